// Round 1
// 345.116 us; speedup vs baseline: 1.1923x; 1.1923x over previous
//
#include <hip/hip_runtime.h>
#include <hip/hip_bf16.h>

#define B_ 4
#define S_ 2048
#define D_ 768
#define H_ 12
#define HD 64

typedef __attribute__((ext_vector_type(8))) short short8;
typedef __attribute__((ext_vector_type(4))) float f32x4;

__device__ __forceinline__ float fmapf(float x) { return x > 0.f ? x + 1.f : __expf(x); }

// fp32 -> bf16 round-to-nearest-even (finite inputs only)
__device__ __forceinline__ unsigned short f2bu(float f) {
    unsigned u = __float_as_uint(f);
    u += 0x7FFFu + ((u >> 16) & 1u);
    return (unsigned short)(u >> 16);
}
__device__ __forceinline__ float bu2f(unsigned short v) {
    return __uint_as_float((unsigned)v << 16);
}

// ---------------------------------------------------------------------------
// Kernel 0: fp32 -> bf16 bulk convert (n % 4 == 0).
// ---------------------------------------------------------------------------
__global__ __launch_bounds__(256) void convert_bf16(const float* __restrict__ src,
                                                    unsigned short* __restrict__ dst,
                                                    int n) {
    int i = (blockIdx.x * 256 + threadIdx.x) * 4;
    if (i < n) {
        float4 v = *(const float4*)&src[i];
        ushort4 o;
        o.x = f2bu(v.x); o.y = f2bu(v.y); o.z = f2bu(v.z); o.w = f2bu(v.w);
        *(ushort4*)&dst[i] = o;
    }
}

// ---------------------------------------------------------------------------
// Kernel 1: qkv = x @ qkv_w.T via bf16 MFMA (16x16x32), fp32 accumulate.
// ---------------------------------------------------------------------------
__global__ __launch_bounds__(256) void qkv_gemm_mfma(const unsigned short* __restrict__ xb,
                                                     const unsigned short* __restrict__ wb,
                                                     float* __restrict__ qf,
                                                     float* __restrict__ kf,
                                                     float* __restrict__ vv) {
    __shared__ short As[128][40];  // 128 x 32 bf16, +8 pad (80B row stride)
    __shared__ short Bs[128][40];
    const int K = 768;
    int n0 = blockIdx.x * 128, m0 = blockIdx.y * 128;
    int tid = threadIdx.x, lane = tid & 63, wave = tid >> 6;
    int wm = (wave & 1) * 64, wn = (wave >> 1) * 64;
    int quad = lane >> 4, l15 = lane & 15;
    int srow = tid >> 1, scol = (tid & 1) * 16;
    f32x4 acc[4][4];
#pragma unroll
    for (int i = 0; i < 4; i++)
#pragma unroll
        for (int j = 0; j < 4; j++) acc[i][j] = 0.f;

    for (int k0 = 0; k0 < K; k0 += 32) {
        const unsigned short* xp = xb + (size_t)(m0 + srow) * K + k0 + scol;
        const unsigned short* wp = wb + (size_t)(n0 + srow) * K + k0 + scol;
        uint4 xa0 = *(const uint4*)xp;
        uint4 xa1 = *(const uint4*)(xp + 8);
        uint4 wa0 = *(const uint4*)wp;
        uint4 wa1 = *(const uint4*)(wp + 8);
        *(uint4*)&As[srow][scol] = xa0;
        *(uint4*)&As[srow][scol + 8] = xa1;
        *(uint4*)&Bs[srow][scol] = wa0;
        *(uint4*)&Bs[srow][scol + 8] = wa1;
        __syncthreads();
        short8 af[4], bfr[4];
#pragma unroll
        for (int i = 0; i < 4; i++) af[i] = *(short8*)&As[wm + i * 16 + l15][quad * 8];
#pragma unroll
        for (int j = 0; j < 4; j++) bfr[j] = *(short8*)&Bs[wn + j * 16 + l15][quad * 8];
#pragma unroll
        for (int i = 0; i < 4; i++)
#pragma unroll
            for (int j = 0; j < 4; j++)
                acc[i][j] = __builtin_amdgcn_mfma_f32_16x16x32_bf16(af[i], bfr[j], acc[i][j], 0, 0, 0);
        __syncthreads();
    }
#pragma unroll
    for (int j = 0; j < 4; j++) {
        int col = n0 + wn + j * 16 + l15;
        int t3 = col / 768;
        int r = col - t3 * 768;
        int h = r >> 6, d = r & 63;
#pragma unroll
        for (int i = 0; i < 4; i++) {
#pragma unroll
            for (int rr = 0; rr < 4; rr++) {
                int m = m0 + wm + i * 16 + quad * 4 + rr;
                int b = m >> 11, s = m & 2047;
                size_t dst = (((size_t)(b * H_ + h) * S_) + s) * HD + d;
                float val = acc[i][j][rr];
                if (t3 == 0)
                    qf[dst] = fmapf(val);
                else if (t3 == 1)
                    kf[dst] = fmapf(val);
                else
                    vv[dst] = val;
            }
        }
    }
}

// ---------------------------------------------------------------------------
// Kernel 2a: partial kv states. Grid = 48 bh * 8 chunks (256 tokens each).
// ---------------------------------------------------------------------------
__global__ __launch_bounds__(256) void band_partial(const float* __restrict__ kf,
                                                    const float* __restrict__ vv,
                                                    float* __restrict__ pkv,
                                                    float* __restrict__ pks) {
    int bh = blockIdx.x >> 3, chunk = blockIdx.x & 7;
    int sbase = chunk * 256;
    const float* kfp = kf + (size_t)bh * S_ * HD + (size_t)sbase * HD;
    const float* vp = vv + (size_t)bh * S_ * HD + (size_t)sbase * HD;
    __shared__ float kt[16][64];
    __shared__ float vt[16][64];
    int tid = threadIdx.x;
    int d = tid >> 2, eg = tid & 3, e0 = eg * 16;
    float accg[16], accs[16];
#pragma unroll
    for (int i = 0; i < 16; i++) { accg[i] = 0.f; accs[i] = 0.f; }
    float ksg = 0.f, kss = 0.f;
    for (int s0 = 0; s0 < 256; s0 += 16) {
        for (int i = tid; i < 1024; i += 256) {
            kt[i >> 6][i & 63] = kfp[(size_t)s0 * HD + i];
            vt[i >> 6][i & 63] = vp[(size_t)s0 * HD + i];
        }
        __syncthreads();
#pragma unroll 4
        for (int ss = 0; ss < 16; ss++) {
            float kd = kt[ss][d];
            bool str = ((sbase + s0 + ss) % 3) == 0;  // block-uniform
            ksg += kd;
            if (str) kss += kd;
#pragma unroll
            for (int i = 0; i < 16; i++) {
                float ve = vt[ss][e0 + i];
                accg[i] += kd * ve;
                if (str) accs[i] += kd * ve;
            }
        }
        __syncthreads();
    }
    float* pg = pkv + (size_t)blockIdx.x * 2 * 4096;
#pragma unroll
    for (int i = 0; i < 16; i++) pg[d * 64 + e0 + i] = accg[i];
#pragma unroll
    for (int i = 0; i < 16; i++) pg[4096 + d * 64 + e0 + i] = accs[i];
    if (eg == 0) {
        pks[blockIdx.x * 128 + d] = ksg;
        pks[blockIdx.x * 128 + 64 + d] = kss;
    }
}

// ---------------------------------------------------------------------------
// Kernel 2b: reduce partials + anchor outputs. Grid = 48 bh * 4 e-blocks.
// ---------------------------------------------------------------------------
__global__ __launch_bounds__(256) void band_reduce(const float* __restrict__ pkv,
                                                   const float* __restrict__ pks,
                                                   const float* __restrict__ aq,
                                                   float* __restrict__ kvs,
                                                   float* __restrict__ ksums,
                                                   float* __restrict__ aout) {
    int bh = blockIdx.x >> 2, eb = blockIdx.x & 3, e0 = eb * 16;
    int h = bh % H_;
    __shared__ float kvgL[64][17];
    __shared__ float ksgL[64];
    __shared__ float anorm[12];
    int tid = threadIdx.x;
    for (int idx = tid; idx < 1024; idx += 256) {
        int d = idx >> 4, j = idx & 15;
        float sg = 0.f, ss = 0.f;
        const float* p = pkv + (size_t)(bh * 8) * 2 * 4096 + d * 64 + e0 + j;
#pragma unroll 4
        for (int c = 0; c < 8; c++) {
            sg += p[0];
            ss += p[4096];
            p += 2 * 4096;
        }
        kvgL[d][j] = sg;
        kvs[(size_t)bh * 4096 + d * 64 + e0 + j] = ss;
    }
    if (tid < 64) {
        float sg = 0.f, ss = 0.f;
#pragma unroll 4
        for (int c = 0; c < 8; c++) {
            sg += pks[(bh * 8 + c) * 128 + tid];
            ss += pks[(bh * 8 + c) * 128 + 64 + tid];
        }
        ksgL[tid] = sg;
        if (eb == 0) ksums[bh * 64 + tid] = ss;
    }
    __syncthreads();
    if (tid < 12) {
        float nrm = 0.f;
        for (int dd = 0; dd < 64; dd++)
            nrm += fmapf(aq[h * 768 + tid * 64 + dd]) * ksgL[dd];
        anorm[tid] = fmaxf(nrm, 1e-6f);
    }
    __syncthreads();
    if (tid < 192) {
        int a = tid >> 4, j = tid & 15;
        float acc = 0.f;
        for (int dd = 0; dd < 64; dd++)
            acc += fmapf(aq[h * 768 + a * 64 + dd]) * kvgL[dd][j];
        aout[(size_t)bh * 768 + a * 64 + e0 + j] = acc / anorm[a];
    }
}

// ---------------------------------------------------------------------------
// Kernel 3: combine, all-MFMA version.
//  Per 64-token tile, wave w owns output rows w*16..w*16+15:
//   phase A (MFMA): dense qk_local rows (5 tiles) -> masked bf16 P in LDS;
//                   qkg rows (1 tile) -> bf16 in LDS (col 12 = ns).
//   norms: lanes 0-15 of each wave compute reciprocal weights for own rows.
//   phase B (MFMA): out = P@V^T (3 K-steps) + qkg@aout^T (1) + qf@kvs (2),
//                   epilogue = 3 FMAs per element.
//  plb/qkgb/nrm are wave-private (phase A tiles ti == wave), so only ONE
//  __syncthreads (after staging) is needed; within-wave LDS ordering is
//  handled by lgkmcnt. LDS ~68.3 KB -> 2 blocks/CU.
// ---------------------------------------------------------------------------
__global__ __launch_bounds__(256) void combine(const float* __restrict__ qf,
                                               const float* __restrict__ kf,
                                               const float* __restrict__ vv,
                                               const float* __restrict__ aq,
                                               const float* __restrict__ kvs,
                                               const float* __restrict__ ksums,
                                               const float* __restrict__ aout,
                                               const float* __restrict__ wlp,
                                               const float* __restrict__ wsp,
                                               const float* __restrict__ wgp,
                                               unsigned short* __restrict__ attnb) {
    __shared__ __attribute__((aligned(16))) unsigned short qftb[64][72];   // [token][d]
    __shared__ __attribute__((aligned(16))) unsigned short kftb[80][72];   // [band k][d]
    __shared__ __attribute__((aligned(16))) unsigned short kvsbT[64][72];  // [e][d]
    __shared__ __attribute__((aligned(16))) unsigned short aqfb[16][72];   // anchors + ksum
    __shared__ __attribute__((aligned(16))) unsigned short vtbT[64][104];  // [e][band k], k<96
    __shared__ __attribute__((aligned(16))) unsigned short plb[64][104];   // masked P, [token][band k]
    __shared__ __attribute__((aligned(16))) unsigned short qkgb[64][40];   // [token][anchor k], k<32
    __shared__ __attribute__((aligned(16))) unsigned short aoutT[64][40];  // [e][anchor k], k<32
    __shared__ float nrm[4][3][16];  // per-wave reciprocal weights: wl/nl, wg/ng, ws/ns
    int bh = blockIdx.x >> 5, stile = blockIdx.x & 31;
    int b = bh / H_, h = bh % H_;
    int s0 = stile * 64;
    int tid = threadIdx.x, lane = tid & 63, wave = tid >> 6;
    int quad = lane >> 4, l15 = lane & 15;
    const float* qfp = qf + (size_t)bh * S_ * HD;
    const float* kfp = kf + (size_t)bh * S_ * HD;
    const float* vp = vv + (size_t)bh * S_ * HD;
    float a0 = wlp[0], a1 = wsp[0], a2 = wgp[0];
    float mx = fmaxf(a0, fmaxf(a1, a2));
    float ew0 = __expf(a0 - mx), ew1 = __expf(a1 - mx), ew2 = __expf(a2 - mx);
    float inv = 1.f / (ew0 + ew1 + ew2);
    float wl = ew0 * inv, wsb = ew1 * inv, wg = ew2 * inv;
    // ---- stage bf16 tiles ----
    for (int i = tid; i < 4096; i += 256) {
        int r = i >> 6, c = i & 63;
        qftb[r][c] = f2bu(qfp[(size_t)(s0 + r) * HD + c]);
        kvsbT[c][r] = f2bu(kvs[(size_t)bh * 4096 + i]);  // transpose -> [e][d]
    }
    for (int i = tid; i < 80 * 64; i += 256) {
        int row = i >> 6, c = i & 63;
        int gs = s0 + row - 6;
        float kv_ = (row < 75 && gs >= 0 && gs < S_) ? kfp[(size_t)gs * HD + c] : 1.0f;
        kftb[row][c] = f2bu(kv_);
    }
    for (int i = tid; i < 96 * 64; i += 256) {
        int k = i >> 6, e = i & 63;
        int gs = s0 + k - 6;
        float v_ = (k < 75 && gs >= 0 && gs < S_) ? vp[(size_t)gs * HD + e] : 0.f;
        vtbT[e][k] = f2bu(v_);  // transpose -> [e][band k]; rows k>=75 zero
    }
    for (int i = tid; i < 1024; i += 256) {
        int a = i >> 6, dd = i & 63;
        float v_;
        if (a < 12) v_ = fmapf(aq[h * 768 + a * 64 + dd]);
        else if (a == 12) v_ = ksums[bh * 64 + dd];
        else v_ = 0.f;
        aqfb[a][dd] = f2bu(v_);
    }
    for (int i = tid; i < 2048; i += 256) {
        int e = i >> 5, a = i & 31;
        aoutT[e][a] = (a < 12) ? f2bu(aout[(size_t)bh * 768 + a * 64 + e]) : (unsigned short)0;
    }
    for (int i = tid; i < 1024; i += 256) {
        plb[i >> 4][80 + (i & 15)] = 0;   // K-pad cols 80..95
        qkgb[i >> 4][16 + (i & 15)] = 0;  // K-pad cols 16..31
    }
    __syncthreads();
    // ---- phase A: wave w computes P rows w*16..w*16+15 (wave-private) ----
#pragma unroll
    for (int tj = 0; tj < 5; tj++) {
        f32x4 c = {0.f, 0.f, 0.f, 0.f};
#pragma unroll
        for (int kk = 0; kk < 2; kk++) {
            short8 afr = *(short8*)&qftb[wave * 16 + l15][kk * 32 + quad * 8];
            short8 bfr = *(short8*)&kftb[tj * 16 + l15][kk * 32 + quad * 8];
            c = __builtin_amdgcn_mfma_f32_16x16x32_bf16(afr, bfr, c, 0, 0, 0);
        }
        int col = tj * 16 + l15;
#pragma unroll
        for (int rr = 0; rr < 4; rr++) {
            int tok = wave * 16 + quad * 4 + rr;
            int which = col - tok;
            plb[tok][col] = (which >= 0 && which < 12) ? f2bu(c[rr]) : (unsigned short)0;
        }
    }
    {
        f32x4 c = {0.f, 0.f, 0.f, 0.f};
#pragma unroll
        for (int kk = 0; kk < 2; kk++) {
            short8 afr = *(short8*)&qftb[wave * 16 + l15][kk * 32 + quad * 8];
            short8 bfr = *(short8*)&aqfb[l15][kk * 32 + quad * 8];
            c = __builtin_amdgcn_mfma_f32_16x16x32_bf16(afr, bfr, c, 0, 0, 0);
        }
#pragma unroll
        for (int rr = 0; rr < 4; rr++) qkgb[wave * 16 + quad * 4 + rr][l15] = f2bu(c[rr]);
    }
    // ---- per-wave norms -> reciprocal combine weights (lanes 0-15) ----
    if (lane < 16) {
        int t = wave * 16 + lane;
        float sl = 0.f;
#pragma unroll
        for (int j = 0; j < 12; j++) sl += bu2f(plb[t][t + j]);
        float sg = 0.f;
#pragma unroll
        for (int a = 0; a < 12; a++) sg += bu2f(qkgb[t][a]);
        nrm[wave][0][lane] = wl / fmaxf(sl, 1e-6f);
        nrm[wave][1][lane] = wg / fmaxf(sg, 1e-6f);
        nrm[wave][2][lane] = wsb / fmaxf(bu2f(qkgb[t][12]), 1e-6f);
    }
    // ---- phase B: fused MFMA for all three bands ----
#pragma unroll
    for (int j2 = 0; j2 < 4; j2++) {
        f32x4 cL = {0.f, 0.f, 0.f, 0.f};
        f32x4 cG = {0.f, 0.f, 0.f, 0.f};
        f32x4 cS = {0.f, 0.f, 0.f, 0.f};
#pragma unroll
        for (int kk = 0; kk < 3; kk++) {
            short8 afr = *(short8*)&plb[wave * 16 + l15][kk * 32 + quad * 8];
            short8 bfr = *(short8*)&vtbT[j2 * 16 + l15][kk * 32 + quad * 8];
            cL = __builtin_amdgcn_mfma_f32_16x16x32_bf16(afr, bfr, cL, 0, 0, 0);
        }
        {
            short8 afr = *(short8*)&qkgb[wave * 16 + l15][quad * 8];
            short8 bfr = *(short8*)&aoutT[j2 * 16 + l15][quad * 8];
            cG = __builtin_amdgcn_mfma_f32_16x16x32_bf16(afr, bfr, cG, 0, 0, 0);
        }
#pragma unroll
        for (int kk = 0; kk < 2; kk++) {
            short8 afr = *(short8*)&qftb[wave * 16 + l15][kk * 32 + quad * 8];
            short8 bfr = *(short8*)&kvsbT[j2 * 16 + l15][kk * 32 + quad * 8];
            cS = __builtin_amdgcn_mfma_f32_16x16x32_bf16(afr, bfr, cS, 0, 0, 0);
        }
        int e = j2 * 16 + l15;
#pragma unroll
        for (int rr = 0; rr < 4; rr++) {
            int tq = quad * 4 + rr;
            int tok = wave * 16 + tq;
            float res = cL[rr] * nrm[wave][0][tq] + cS[rr] * nrm[wave][2][tq] +
                        cG[rr] * nrm[wave][1][tq];
            attnb[((size_t)(b * S_ + s0 + tok)) * 768 + h * 64 + e] = f2bu(res);
        }
    }
}

// ---------------------------------------------------------------------------
// Kernel 4: out = attn(bf16) @ out_w.T via bf16 MFMA -> fp32 out.
// ---------------------------------------------------------------------------
__global__ __launch_bounds__(256) void out_gemm_mfma(const unsigned short* __restrict__ attnb,
                                                     const unsigned short* __restrict__ wb,
                                                     float* __restrict__ out) {
    __shared__ short As[128][40];
    __shared__ short Bs[128][40];
    const int K = 768;
    int n0 = blockIdx.x * 128, m0 = blockIdx.y * 128;
    int tid = threadIdx.x, lane = tid & 63, wave = tid >> 6;
    int wm = (wave & 1) * 64, wn = (wave >> 1) * 64;
    int quad = lane >> 4, l15 = lane & 15;
    int srow = tid >> 1, scol = (tid & 1) * 16;
    f32x4 acc[4][4];
#pragma unroll
    for (int i = 0; i < 4; i++)
#pragma unroll
        for (int j = 0; j < 4; j++) acc[i][j] = 0.f;

    for (int k0 = 0; k0 < K; k0 += 32) {
        const unsigned short* ap = attnb + (size_t)(m0 + srow) * K + k0 + scol;
        const unsigned short* wp = wb + (size_t)(n0 + srow) * K + k0 + scol;
        uint4 a0 = *(const uint4*)ap;
        uint4 a1 = *(const uint4*)(ap + 8);
        uint4 w0 = *(const uint4*)wp;
        uint4 w1 = *(const uint4*)(wp + 8);
        *(uint4*)&As[srow][scol] = a0;
        *(uint4*)&As[srow][scol + 8] = a1;
        *(uint4*)&Bs[srow][scol] = w0;
        *(uint4*)&Bs[srow][scol + 8] = w1;
        __syncthreads();
        short8 af[4], bfr[4];
#pragma unroll
        for (int i = 0; i < 4; i++) af[i] = *(short8*)&As[wm + i * 16 + l15][quad * 8];
#pragma unroll
        for (int j = 0; j < 4; j++) bfr[j] = *(short8*)&Bs[wn + j * 16 + l15][quad * 8];
#pragma unroll
        for (int i = 0; i < 4; i++)
#pragma unroll
            for (int j = 0; j < 4; j++)
                acc[i][j] = __builtin_amdgcn_mfma_f32_16x16x32_bf16(af[i], bfr[j], acc[i][j], 0, 0, 0);
        __syncthreads();
    }
#pragma unroll
    for (int j = 0; j < 4; j++) {
        int col = n0 + wn + j * 16 + l15;
#pragma unroll
        for (int i = 0; i < 4; i++) {
#pragma unroll
            for (int rr = 0; rr < 4; rr++) {
                int m = m0 + wm + i * 16 + quad * 4 + rr;
                out[(size_t)m * 768 + col] = acc[i][j][rr];
            }
        }
    }
}

extern "C" void kernel_launch(void* const* d_in, const int* in_sizes, int n_in,
                              void* d_out, int out_size, void* d_ws, size_t ws_size,
                              hipStream_t stream) {
    const float* x = (const float*)d_in[0];
    const float* qkvw = (const float*)d_in[1];
    const float* outw = (const float*)d_in[2];
    const float* aq = (const float*)d_in[3];
    const float* wlp = (const float*)d_in[4];
    const float* wsp = (const float*)d_in[5];
    const float* wgp = (const float*)d_in[6];

    float* ws = (float*)d_ws;
    const size_t NBH = (size_t)B_ * H_ * S_ * HD;  // 6,291,456
    float* qf = ws;
    float* kf = qf + NBH;
    float* vv = kf + NBH;
    float* attn_region = vv + NBH;       // NBH floats; multi-use scratch
    float* kvs = attn_region + NBH;      // 48*4096
    float* ksums = kvs + 48 * 4096;      // 48*64
    float* aout = ksums + 48 * 64;       // 48*768
    // Lifetimes inside attn_region (NBH floats):
    //  [0, 3145728)           xb (bf16 x)      : convert .. qkv_gemm
    //  [3145728, 4030464)     wb (bf16 qkv_w)  : convert .. qkv_gemm
    //  [4030464, 4325376)     outwb (bf16)     : convert .. out_gemm
    //  [0, 3145728)           pkv              : band_partial .. band_reduce
    //  [3145728, 3194880)     pks              : band_partial .. band_reduce
    //  [0, 3145728)           attnb (bf16 attn): combine .. out_gemm
    unsigned short* xb = (unsigned short*)attn_region;
    unsigned short* wb = (unsigned short*)(attn_region + 3145728);
    unsigned short* outwb = (unsigned short*)(attn_region + 3145728 + 884736);
    float* pkv = attn_region;
    float* pks = attn_region + 3145728;
    unsigned short* attnb = (unsigned short*)attn_region;

    convert_bf16<<<6144, 256, 0, stream>>>(x, xb, 6291456);
    convert_bf16<<<1728, 256, 0, stream>>>(qkvw, wb, 1769472);
    convert_bf16<<<576, 256, 0, stream>>>(outw, outwb, 589824);
    qkv_gemm_mfma<<<dim3(18, 64), 256, 0, stream>>>(xb, wb, qf, kf, vv);
    band_partial<<<48 * 8, 256, 0, stream>>>(kf, vv, pkv, pks);
    band_reduce<<<48 * 4, 256, 0, stream>>>(pkv, pks, aq, kvs, ksums, aout);
    combine<<<48 * 32, 256, 0, stream>>>(qf, kf, vv, aq, kvs, ksums, aout, wlp, wsp, wgp, attnb);
    out_gemm_mfma<<<dim3(6, 64), 256, 0, stream>>>(attnb, outwb, (float*)d_out);
}

// Round 2
// 325.028 us; speedup vs baseline: 1.2660x; 1.0618x over previous
//
#include <hip/hip_runtime.h>
#include <hip/hip_bf16.h>

#define B_ 4
#define S_ 2048
#define D_ 768
#define H_ 12
#define HD 64

typedef __attribute__((ext_vector_type(8))) short short8;
typedef __attribute__((ext_vector_type(4))) float f32x4;

__device__ __forceinline__ float fmapf(float x) { return x > 0.f ? x + 1.f : __expf(x); }

// fp32 -> bf16 round-to-nearest-even (finite inputs only)
__device__ __forceinline__ unsigned short f2bu(float f) {
    unsigned u = __float_as_uint(f);
    u += 0x7FFFu + ((u >> 16) & 1u);
    return (unsigned short)(u >> 16);
}
__device__ __forceinline__ float bu2f(unsigned short v) {
    return __uint_as_float((unsigned)v << 16);
}

// ---------------------------------------------------------------------------
// Kernel 0: fp32 -> bf16 bulk convert (n % 4 == 0).
// ---------------------------------------------------------------------------
__global__ __launch_bounds__(256) void convert_bf16(const float* __restrict__ src,
                                                    unsigned short* __restrict__ dst,
                                                    int n) {
    int i = (blockIdx.x * 256 + threadIdx.x) * 4;
    if (i < n) {
        float4 v = *(const float4*)&src[i];
        ushort4 o;
        o.x = f2bu(v.x); o.y = f2bu(v.y); o.z = f2bu(v.z); o.w = f2bu(v.w);
        *(ushort4*)&dst[i] = o;
    }
}

// ---------------------------------------------------------------------------
// Kernel 1: qkv = x @ qkv_w.T via bf16 MFMA (16x16x32), fp32 accumulate.
// ---------------------------------------------------------------------------
__global__ __launch_bounds__(256) void qkv_gemm_mfma(const unsigned short* __restrict__ xb,
                                                     const unsigned short* __restrict__ wb,
                                                     float* __restrict__ qf,
                                                     float* __restrict__ kf,
                                                     float* __restrict__ vv) {
    __shared__ short As[128][40];  // 128 x 32 bf16, +8 pad (80B row stride)
    __shared__ short Bs[128][40];
    const int K = 768;
    int n0 = blockIdx.x * 128, m0 = blockIdx.y * 128;
    int tid = threadIdx.x, lane = tid & 63, wave = tid >> 6;
    int wm = (wave & 1) * 64, wn = (wave >> 1) * 64;
    int quad = lane >> 4, l15 = lane & 15;
    int srow = tid >> 1, scol = (tid & 1) * 16;
    f32x4 acc[4][4];
#pragma unroll
    for (int i = 0; i < 4; i++)
#pragma unroll
        for (int j = 0; j < 4; j++) acc[i][j] = 0.f;

    for (int k0 = 0; k0 < K; k0 += 32) {
        const unsigned short* xp = xb + (size_t)(m0 + srow) * K + k0 + scol;
        const unsigned short* wp = wb + (size_t)(n0 + srow) * K + k0 + scol;
        uint4 xa0 = *(const uint4*)xp;
        uint4 xa1 = *(const uint4*)(xp + 8);
        uint4 wa0 = *(const uint4*)wp;
        uint4 wa1 = *(const uint4*)(wp + 8);
        *(uint4*)&As[srow][scol] = xa0;
        *(uint4*)&As[srow][scol + 8] = xa1;
        *(uint4*)&Bs[srow][scol] = wa0;
        *(uint4*)&Bs[srow][scol + 8] = wa1;
        __syncthreads();
        short8 af[4], bfr[4];
#pragma unroll
        for (int i = 0; i < 4; i++) af[i] = *(short8*)&As[wm + i * 16 + l15][quad * 8];
#pragma unroll
        for (int j = 0; j < 4; j++) bfr[j] = *(short8*)&Bs[wn + j * 16 + l15][quad * 8];
#pragma unroll
        for (int i = 0; i < 4; i++)
#pragma unroll
            for (int j = 0; j < 4; j++)
                acc[i][j] = __builtin_amdgcn_mfma_f32_16x16x32_bf16(af[i], bfr[j], acc[i][j], 0, 0, 0);
        __syncthreads();
    }
#pragma unroll
    for (int j = 0; j < 4; j++) {
        int col = n0 + wn + j * 16 + l15;
        int t3 = col / 768;
        int r = col - t3 * 768;
        int h = r >> 6, d = r & 63;
#pragma unroll
        for (int i = 0; i < 4; i++) {
#pragma unroll
            for (int rr = 0; rr < 4; rr++) {
                int m = m0 + wm + i * 16 + quad * 4 + rr;
                int b = m >> 11, s = m & 2047;
                size_t dst = (((size_t)(b * H_ + h) * S_) + s) * HD + d;
                float val = acc[i][j][rr];
                if (t3 == 0)
                    qf[dst] = fmapf(val);
                else if (t3 == 1)
                    kf[dst] = fmapf(val);
                else
                    vv[dst] = val;
            }
        }
    }
}

// ---------------------------------------------------------------------------
// Kernel 2a: partial kv states. Grid = 48 bh * 16 chunks (128 tokens each).
// Vectorized LDS: v reads as float4 (b128), staging as float4 both sides.
// ---------------------------------------------------------------------------
__global__ __launch_bounds__(256) void band_partial(const float* __restrict__ kf,
                                                    const float* __restrict__ vv,
                                                    float* __restrict__ pkv,
                                                    float* __restrict__ pks) {
    int bh = blockIdx.x >> 4, chunk = blockIdx.x & 15;
    int sbase = chunk * 128;
    const float* kfp = kf + (size_t)bh * S_ * HD + (size_t)sbase * HD;
    const float* vp = vv + (size_t)bh * S_ * HD + (size_t)sbase * HD;
    __shared__ float kt[16][64];
    __shared__ float vt[16][64];
    int tid = threadIdx.x;
    int d = tid >> 2, eg = tid & 3, e0 = eg * 16;
    int srow = tid >> 4, scol = (tid & 15) * 4;
    float accg[16], accs[16];
#pragma unroll
    for (int i = 0; i < 16; i++) { accg[i] = 0.f; accs[i] = 0.f; }
    float ksg = 0.f, kss = 0.f;
    for (int s0 = 0; s0 < 128; s0 += 16) {
        *(float4*)&kt[srow][scol] = *(const float4*)&kfp[(size_t)(s0 + srow) * HD + scol];
        *(float4*)&vt[srow][scol] = *(const float4*)&vp[(size_t)(s0 + srow) * HD + scol];
        __syncthreads();
        int m3 = (sbase + s0) % 3;  // block-uniform stride phase
#pragma unroll
        for (int ss = 0; ss < 16; ss++) {
            float kd = kt[ss][d];
            bool str = ((m3 + ss) % 3) == 0;
            ksg += kd;
            float4 v0 = *(float4*)&vt[ss][e0];
            float4 v1 = *(float4*)&vt[ss][e0 + 4];
            float4 v2 = *(float4*)&vt[ss][e0 + 8];
            float4 v3 = *(float4*)&vt[ss][e0 + 12];
            accg[0] += kd * v0.x;  accg[1] += kd * v0.y;
            accg[2] += kd * v0.z;  accg[3] += kd * v0.w;
            accg[4] += kd * v1.x;  accg[5] += kd * v1.y;
            accg[6] += kd * v1.z;  accg[7] += kd * v1.w;
            accg[8] += kd * v2.x;  accg[9] += kd * v2.y;
            accg[10] += kd * v2.z; accg[11] += kd * v2.w;
            accg[12] += kd * v3.x; accg[13] += kd * v3.y;
            accg[14] += kd * v3.z; accg[15] += kd * v3.w;
            if (str) {
                kss += kd;
                accs[0] += kd * v0.x;  accs[1] += kd * v0.y;
                accs[2] += kd * v0.z;  accs[3] += kd * v0.w;
                accs[4] += kd * v1.x;  accs[5] += kd * v1.y;
                accs[6] += kd * v1.z;  accs[7] += kd * v1.w;
                accs[8] += kd * v2.x;  accs[9] += kd * v2.y;
                accs[10] += kd * v2.z; accs[11] += kd * v2.w;
                accs[12] += kd * v3.x; accs[13] += kd * v3.y;
                accs[14] += kd * v3.z; accs[15] += kd * v3.w;
            }
        }
        __syncthreads();
    }
    float* pg = pkv + (size_t)blockIdx.x * 2 * 4096;
#pragma unroll
    for (int i = 0; i < 16; i++) pg[d * 64 + e0 + i] = accg[i];
#pragma unroll
    for (int i = 0; i < 16; i++) pg[4096 + d * 64 + e0 + i] = accs[i];
    if (eg == 0) {
        pks[blockIdx.x * 128 + d] = ksg;
        pks[blockIdx.x * 128 + 64 + d] = kss;
    }
}

// ---------------------------------------------------------------------------
// Kernel 2b: reduce partials + anchor outputs. Grid = 48 bh * 4 e-blocks.
// ---------------------------------------------------------------------------
__global__ __launch_bounds__(256) void band_reduce(const float* __restrict__ pkv,
                                                   const float* __restrict__ pks,
                                                   const float* __restrict__ aq,
                                                   float* __restrict__ kvs,
                                                   float* __restrict__ ksums,
                                                   float* __restrict__ aout) {
    int bh = blockIdx.x >> 2, eb = blockIdx.x & 3, e0 = eb * 16;
    int h = bh % H_;
    __shared__ float kvgL[64][17];
    __shared__ float ksgL[64];
    __shared__ float anorm[12];
    int tid = threadIdx.x;
    for (int idx = tid; idx < 1024; idx += 256) {
        int d = idx >> 4, j = idx & 15;
        float sg = 0.f, ss = 0.f;
        const float* p = pkv + (size_t)(bh * 16) * 2 * 4096 + d * 64 + e0 + j;
#pragma unroll 4
        for (int c = 0; c < 16; c++) {
            sg += p[0];
            ss += p[4096];
            p += 2 * 4096;
        }
        kvgL[d][j] = sg;
        kvs[(size_t)bh * 4096 + d * 64 + e0 + j] = ss;
    }
    if (tid < 64) {
        float sg = 0.f, ss = 0.f;
#pragma unroll 4
        for (int c = 0; c < 16; c++) {
            sg += pks[(bh * 16 + c) * 128 + tid];
            ss += pks[(bh * 16 + c) * 128 + 64 + tid];
        }
        ksgL[tid] = sg;
        if (eb == 0) ksums[bh * 64 + tid] = ss;
    }
    __syncthreads();
    if (tid < 12) {
        float nrm = 0.f;
        for (int dd = 0; dd < 64; dd++)
            nrm += fmapf(aq[h * 768 + tid * 64 + dd]) * ksgL[dd];
        anorm[tid] = fmaxf(nrm, 1e-6f);
    }
    __syncthreads();
    if (tid < 192) {
        int a = tid >> 4, j = tid & 15;
        float acc = 0.f;
        for (int dd = 0; dd < 64; dd++)
            acc += fmapf(aq[h * 768 + a * 64 + dd]) * kvgL[dd][j];
        aout[(size_t)bh * 768 + a * 64 + e0 + j] = acc / anorm[a];
    }
}

// ---------------------------------------------------------------------------
// Kernel 3: combine, all-MFMA version.
//  Per 64-token tile, wave w owns output rows w*16..w*16+15:
//   phase A (MFMA): dense qk_local rows (5 tiles) -> masked bf16 P in LDS;
//                   qkg rows (1 tile) -> bf16 in LDS (col 12 = ns).
//   norms: lanes 0-15 of each wave compute reciprocal weights for own rows.
//   phase B (MFMA): out = P@V^T (3 K-steps) + qkg@aout^T (1) + qf@kvs (2),
//                   epilogue = 3 FMAs per element.
//  plb/qkgb/nrm are wave-private (phase A tiles ti == wave), so only ONE
//  __syncthreads (after staging) is needed; within-wave LDS ordering is
//  handled by lgkmcnt. LDS ~68.3 KB -> 2 blocks/CU.
// ---------------------------------------------------------------------------
__global__ __launch_bounds__(256) void combine(const float* __restrict__ qf,
                                               const float* __restrict__ kf,
                                               const float* __restrict__ vv,
                                               const float* __restrict__ aq,
                                               const float* __restrict__ kvs,
                                               const float* __restrict__ ksums,
                                               const float* __restrict__ aout,
                                               const float* __restrict__ wlp,
                                               const float* __restrict__ wsp,
                                               const float* __restrict__ wgp,
                                               unsigned short* __restrict__ attnb) {
    __shared__ __attribute__((aligned(16))) unsigned short qftb[64][72];   // [token][d]
    __shared__ __attribute__((aligned(16))) unsigned short kftb[80][72];   // [band k][d]
    __shared__ __attribute__((aligned(16))) unsigned short kvsbT[64][72];  // [e][d]
    __shared__ __attribute__((aligned(16))) unsigned short aqfb[16][72];   // anchors + ksum
    __shared__ __attribute__((aligned(16))) unsigned short vtbT[64][104];  // [e][band k], k<96
    __shared__ __attribute__((aligned(16))) unsigned short plb[64][104];   // masked P, [token][band k]
    __shared__ __attribute__((aligned(16))) unsigned short qkgb[64][40];   // [token][anchor k], k<32
    __shared__ __attribute__((aligned(16))) unsigned short aoutT[64][40];  // [e][anchor k], k<32
    __shared__ float nrm[4][3][16];  // per-wave reciprocal weights: wl/nl, wg/ng, ws/ns
    int bh = blockIdx.x >> 5, stile = blockIdx.x & 31;
    int b = bh / H_, h = bh % H_;
    int s0 = stile * 64;
    int tid = threadIdx.x, lane = tid & 63, wave = tid >> 6;
    int quad = lane >> 4, l15 = lane & 15;
    const float* qfp = qf + (size_t)bh * S_ * HD;
    const float* kfp = kf + (size_t)bh * S_ * HD;
    const float* vp = vv + (size_t)bh * S_ * HD;
    float a0 = wlp[0], a1 = wsp[0], a2 = wgp[0];
    float mx = fmaxf(a0, fmaxf(a1, a2));
    float ew0 = __expf(a0 - mx), ew1 = __expf(a1 - mx), ew2 = __expf(a2 - mx);
    float inv = 1.f / (ew0 + ew1 + ew2);
    float wl = ew0 * inv, wsb = ew1 * inv, wg = ew2 * inv;
    // ---- stage bf16 tiles ----
    for (int i = tid; i < 4096; i += 256) {
        int r = i >> 6, c = i & 63;
        qftb[r][c] = f2bu(qfp[(size_t)(s0 + r) * HD + c]);
        kvsbT[c][r] = f2bu(kvs[(size_t)bh * 4096 + i]);  // transpose -> [e][d]
    }
    for (int i = tid; i < 80 * 64; i += 256) {
        int row = i >> 6, c = i & 63;
        int gs = s0 + row - 6;
        float kv_ = (row < 75 && gs >= 0 && gs < S_) ? kfp[(size_t)gs * HD + c] : 1.0f;
        kftb[row][c] = f2bu(kv_);
    }
    for (int i = tid; i < 96 * 64; i += 256) {
        int k = i >> 6, e = i & 63;
        int gs = s0 + k - 6;
        float v_ = (k < 75 && gs >= 0 && gs < S_) ? vp[(size_t)gs * HD + e] : 0.f;
        vtbT[e][k] = f2bu(v_);  // transpose -> [e][band k]; rows k>=75 zero
    }
    for (int i = tid; i < 1024; i += 256) {
        int a = i >> 6, dd = i & 63;
        float v_;
        if (a < 12) v_ = fmapf(aq[h * 768 + a * 64 + dd]);
        else if (a == 12) v_ = ksums[bh * 64 + dd];
        else v_ = 0.f;
        aqfb[a][dd] = f2bu(v_);
    }
    for (int i = tid; i < 2048; i += 256) {
        int e = i >> 5, a = i & 31;
        aoutT[e][a] = (a < 12) ? f2bu(aout[(size_t)bh * 768 + a * 64 + e]) : (unsigned short)0;
    }
    for (int i = tid; i < 1024; i += 256) {
        plb[i >> 4][80 + (i & 15)] = 0;   // K-pad cols 80..95
        qkgb[i >> 4][16 + (i & 15)] = 0;  // K-pad cols 16..31
    }
    __syncthreads();
    // ---- phase A: wave w computes P rows w*16..w*16+15 (wave-private) ----
#pragma unroll
    for (int tj = 0; tj < 5; tj++) {
        f32x4 c = {0.f, 0.f, 0.f, 0.f};
#pragma unroll
        for (int kk = 0; kk < 2; kk++) {
            short8 afr = *(short8*)&qftb[wave * 16 + l15][kk * 32 + quad * 8];
            short8 bfr = *(short8*)&kftb[tj * 16 + l15][kk * 32 + quad * 8];
            c = __builtin_amdgcn_mfma_f32_16x16x32_bf16(afr, bfr, c, 0, 0, 0);
        }
        int col = tj * 16 + l15;
#pragma unroll
        for (int rr = 0; rr < 4; rr++) {
            int tok = wave * 16 + quad * 4 + rr;
            int which = col - tok;
            plb[tok][col] = (which >= 0 && which < 12) ? f2bu(c[rr]) : (unsigned short)0;
        }
    }
    {
        f32x4 c = {0.f, 0.f, 0.f, 0.f};
#pragma unroll
        for (int kk = 0; kk < 2; kk++) {
            short8 afr = *(short8*)&qftb[wave * 16 + l15][kk * 32 + quad * 8];
            short8 bfr = *(short8*)&aqfb[l15][kk * 32 + quad * 8];
            c = __builtin_amdgcn_mfma_f32_16x16x32_bf16(afr, bfr, c, 0, 0, 0);
        }
#pragma unroll
        for (int rr = 0; rr < 4; rr++) qkgb[wave * 16 + quad * 4 + rr][l15] = f2bu(c[rr]);
    }
    // ---- per-wave norms -> reciprocal combine weights (lanes 0-15) ----
    if (lane < 16) {
        int t = wave * 16 + lane;
        float sl = 0.f;
#pragma unroll
        for (int j = 0; j < 12; j++) sl += bu2f(plb[t][t + j]);
        float sg = 0.f;
#pragma unroll
        for (int a = 0; a < 12; a++) sg += bu2f(qkgb[t][a]);
        nrm[wave][0][lane] = wl / fmaxf(sl, 1e-6f);
        nrm[wave][1][lane] = wg / fmaxf(sg, 1e-6f);
        nrm[wave][2][lane] = wsb / fmaxf(bu2f(qkgb[t][12]), 1e-6f);
    }
    // ---- phase B: fused MFMA for all three bands ----
#pragma unroll
    for (int j2 = 0; j2 < 4; j2++) {
        f32x4 cL = {0.f, 0.f, 0.f, 0.f};
        f32x4 cG = {0.f, 0.f, 0.f, 0.f};
        f32x4 cS = {0.f, 0.f, 0.f, 0.f};
#pragma unroll
        for (int kk = 0; kk < 3; kk++) {
            short8 afr = *(short8*)&plb[wave * 16 + l15][kk * 32 + quad * 8];
            short8 bfr = *(short8*)&vtbT[j2 * 16 + l15][kk * 32 + quad * 8];
            cL = __builtin_amdgcn_mfma_f32_16x16x32_bf16(afr, bfr, cL, 0, 0, 0);
        }
        {
            short8 afr = *(short8*)&qkgb[wave * 16 + l15][quad * 8];
            short8 bfr = *(short8*)&aoutT[j2 * 16 + l15][quad * 8];
            cG = __builtin_amdgcn_mfma_f32_16x16x32_bf16(afr, bfr, cG, 0, 0, 0);
        }
#pragma unroll
        for (int kk = 0; kk < 2; kk++) {
            short8 afr = *(short8*)&qftb[wave * 16 + l15][kk * 32 + quad * 8];
            short8 bfr = *(short8*)&kvsbT[j2 * 16 + l15][kk * 32 + quad * 8];
            cS = __builtin_amdgcn_mfma_f32_16x16x32_bf16(afr, bfr, cS, 0, 0, 0);
        }
        int e = j2 * 16 + l15;
#pragma unroll
        for (int rr = 0; rr < 4; rr++) {
            int tq = quad * 4 + rr;
            int tok = wave * 16 + tq;
            float res = cL[rr] * nrm[wave][0][tq] + cS[rr] * nrm[wave][2][tq] +
                        cG[rr] * nrm[wave][1][tq];
            attnb[((size_t)(b * S_ + s0 + tok)) * 768 + h * 64 + e] = f2bu(res);
        }
    }
}

// ---------------------------------------------------------------------------
// Kernel 4: out = attn(bf16) @ out_w.T via bf16 MFMA -> fp32 out.
// ---------------------------------------------------------------------------
__global__ __launch_bounds__(256) void out_gemm_mfma(const unsigned short* __restrict__ attnb,
                                                     const unsigned short* __restrict__ wb,
                                                     float* __restrict__ out) {
    __shared__ short As[128][40];
    __shared__ short Bs[128][40];
    const int K = 768;
    int n0 = blockIdx.x * 128, m0 = blockIdx.y * 128;
    int tid = threadIdx.x, lane = tid & 63, wave = tid >> 6;
    int wm = (wave & 1) * 64, wn = (wave >> 1) * 64;
    int quad = lane >> 4, l15 = lane & 15;
    int srow = tid >> 1, scol = (tid & 1) * 16;
    f32x4 acc[4][4];
#pragma unroll
    for (int i = 0; i < 4; i++)
#pragma unroll
        for (int j = 0; j < 4; j++) acc[i][j] = 0.f;

    for (int k0 = 0; k0 < K; k0 += 32) {
        const unsigned short* ap = attnb + (size_t)(m0 + srow) * K + k0 + scol;
        const unsigned short* wp = wb + (size_t)(n0 + srow) * K + k0 + scol;
        uint4 a0 = *(const uint4*)ap;
        uint4 a1 = *(const uint4*)(ap + 8);
        uint4 w0 = *(const uint4*)wp;
        uint4 w1 = *(const uint4*)(wp + 8);
        *(uint4*)&As[srow][scol] = a0;
        *(uint4*)&As[srow][scol + 8] = a1;
        *(uint4*)&Bs[srow][scol] = w0;
        *(uint4*)&Bs[srow][scol + 8] = w1;
        __syncthreads();
        short8 af[4], bfr[4];
#pragma unroll
        for (int i = 0; i < 4; i++) af[i] = *(short8*)&As[wm + i * 16 + l15][quad * 8];
#pragma unroll
        for (int j = 0; j < 4; j++) bfr[j] = *(short8*)&Bs[wn + j * 16 + l15][quad * 8];
#pragma unroll
        for (int i = 0; i < 4; i++)
#pragma unroll
            for (int j = 0; j < 4; j++)
                acc[i][j] = __builtin_amdgcn_mfma_f32_16x16x32_bf16(af[i], bfr[j], acc[i][j], 0, 0, 0);
        __syncthreads();
    }
#pragma unroll
    for (int j = 0; j < 4; j++) {
        int col = n0 + wn + j * 16 + l15;
#pragma unroll
        for (int i = 0; i < 4; i++) {
#pragma unroll
            for (int rr = 0; rr < 4; rr++) {
                int m = m0 + wm + i * 16 + quad * 4 + rr;
                out[(size_t)m * 768 + col] = acc[i][j][rr];
            }
        }
    }
}

extern "C" void kernel_launch(void* const* d_in, const int* in_sizes, int n_in,
                              void* d_out, int out_size, void* d_ws, size_t ws_size,
                              hipStream_t stream) {
    const float* x = (const float*)d_in[0];
    const float* qkvw = (const float*)d_in[1];
    const float* outw = (const float*)d_in[2];
    const float* aq = (const float*)d_in[3];
    const float* wlp = (const float*)d_in[4];
    const float* wsp = (const float*)d_in[5];
    const float* wgp = (const float*)d_in[6];

    float* ws = (float*)d_ws;
    const size_t NBH = (size_t)B_ * H_ * S_ * HD;  // 6,291,456
    float* qf = ws;
    float* kf = qf + NBH;
    float* vv = kf + NBH;
    float* attn_region = vv + NBH;       // NBH floats; multi-use scratch
    float* kvs = attn_region + NBH;      // 48*4096
    float* ksums = kvs + 48 * 4096;      // 48*64
    float* aout = ksums + 48 * 64;       // 48*768
    float* pks = aout + 48 * 768;        // 768*128 floats (outside attn_region!)
    // Lifetimes inside attn_region (NBH floats):
    //  [0, 3145728)           xb (bf16 x)      : convert .. qkv_gemm
    //  [3145728, 4030464)     wb (bf16 qkv_w)  : convert .. qkv_gemm
    //  [0, NBH)               pkv              : band_partial .. band_reduce
    //  [0, 3145728)           attnb (bf16 attn): combine .. out_gemm
    // outwb moved past pks (pkv now fills all of attn_region).
    unsigned short* xb = (unsigned short*)attn_region;
    unsigned short* wb = (unsigned short*)(attn_region + 3145728);
    unsigned short* outwb = (unsigned short*)(pks + 768 * 128);
    float* pkv = attn_region;
    unsigned short* attnb = (unsigned short*)attn_region;

    convert_bf16<<<6144, 256, 0, stream>>>(x, xb, 6291456);
    convert_bf16<<<1728, 256, 0, stream>>>(qkvw, wb, 1769472);
    convert_bf16<<<576, 256, 0, stream>>>(outw, outwb, 589824);
    qkv_gemm_mfma<<<dim3(18, 64), 256, 0, stream>>>(xb, wb, qf, kf, vv);
    band_partial<<<48 * 16, 256, 0, stream>>>(kf, vv, pkv, pks);
    band_reduce<<<48 * 4, 256, 0, stream>>>(pkv, pks, aq, kvs, ksums, aout);
    combine<<<48 * 32, 256, 0, stream>>>(qf, kf, vv, aq, kvs, ksums, aout, wlp, wsp, wgp, attnb);
    out_gemm_mfma<<<dim3(6, 64), 256, 0, stream>>>(attnb, outwb, (float*)d_out);
}

// Round 3
// 315.496 us; speedup vs baseline: 1.3042x; 1.0302x over previous
//
#include <hip/hip_runtime.h>
#include <hip/hip_bf16.h>

#define B_ 4
#define S_ 2048
#define D_ 768
#define H_ 12
#define HD 64

typedef __attribute__((ext_vector_type(8))) short short8;
typedef __attribute__((ext_vector_type(4))) float f32x4;

__device__ __forceinline__ float fmapf(float x) { return x > 0.f ? x + 1.f : __expf(x); }

// fp32 -> bf16 round-to-nearest-even (finite inputs only)
__device__ __forceinline__ unsigned short f2bu(float f) {
    unsigned u = __float_as_uint(f);
    u += 0x7FFFu + ((u >> 16) & 1u);
    return (unsigned short)(u >> 16);
}
__device__ __forceinline__ float bu2f(unsigned short v) {
    return __uint_as_float((unsigned)v << 16);
}

// async global->LDS direct copy, 16B per lane. lds ptr must be wave-uniform;
// HW writes lane l to ldsbase + l*16 (m97 pattern: linear LDS dest).
__device__ __forceinline__ void gload16(const void* g, void* l) {
    __builtin_amdgcn_global_load_lds((__attribute__((address_space(1))) void*)(size_t)g,
                                     (__attribute__((address_space(3))) void*)l, 16, 0, 0);
}

// ---------------------------------------------------------------------------
// Kernel 0: fp32 -> bf16 bulk convert (n % 4 == 0).
// ---------------------------------------------------------------------------
__global__ __launch_bounds__(256) void convert_bf16(const float* __restrict__ src,
                                                    unsigned short* __restrict__ dst,
                                                    int n) {
    int i = (blockIdx.x * 256 + threadIdx.x) * 4;
    if (i < n) {
        float4 v = *(const float4*)&src[i];
        ushort4 o;
        o.x = f2bu(v.x); o.y = f2bu(v.y); o.z = f2bu(v.z); o.w = f2bu(v.w);
        *(ushort4*)&dst[i] = o;
    }
}

// ---------------------------------------------------------------------------
// Kernel 1: qkv = x @ qkv_w.T via bf16 MFMA (16x16x32), fp32 accumulate.
// m97 structure: linear LDS [128][32], global_load_lds width=16 staging.
// ---------------------------------------------------------------------------
__global__ __launch_bounds__(256) void qkv_gemm_mfma(const unsigned short* __restrict__ xb,
                                                     const unsigned short* __restrict__ wb,
                                                     float* __restrict__ qf,
                                                     float* __restrict__ kf,
                                                     float* __restrict__ vv) {
    __shared__ __attribute__((aligned(16))) unsigned short As[128 * 32];
    __shared__ __attribute__((aligned(16))) unsigned short Bs[128 * 32];
    const int K = 768;
    int n0 = blockIdx.x * 128, m0 = blockIdx.y * 128;
    int tid = threadIdx.x, lane = tid & 63, wave = tid >> 6;
    int wm = (wave & 1) * 64, wn = (wave >> 1) * 64;
    int quad = lane >> 4, l15 = lane & 15;
    f32x4 acc[4][4];
#pragma unroll
    for (int i = 0; i < 4; i++)
#pragma unroll
        for (int j = 0; j < 4; j++) acc[i][j] = 0.f;

    // staging: chunk c (16B) -> LDS linear offset c*8 shorts; row=c>>2, col8=c&3.
    // issue 0: chunks [0,256) (rows 0..63), issue 1: chunks [256,512) (rows 64..127)
    const unsigned short* ga0 = xb + (size_t)(m0 + (tid >> 2)) * K + (tid & 3) * 8;
    const unsigned short* ga1 = xb + (size_t)(m0 + 64 + (tid >> 2)) * K + (tid & 3) * 8;
    const unsigned short* gb0 = wb + (size_t)(n0 + (tid >> 2)) * K + (tid & 3) * 8;
    const unsigned short* gb1 = wb + (size_t)(n0 + 64 + (tid >> 2)) * K + (tid & 3) * 8;
    unsigned short* lA0 = As + wave * 512;
    unsigned short* lA1 = As + 2048 + wave * 512;
    unsigned short* lB0 = Bs + wave * 512;
    unsigned short* lB1 = Bs + 2048 + wave * 512;

    for (int k0 = 0; k0 < K; k0 += 32) {
        gload16(ga0 + k0, lA0);
        gload16(ga1 + k0, lA1);
        gload16(gb0 + k0, lB0);
        gload16(gb1 + k0, lB1);
        __syncthreads();
        short8 af[4], bfr[4];
#pragma unroll
        for (int i = 0; i < 4; i++) af[i] = *(short8*)&As[(wm + i * 16 + l15) * 32 + quad * 8];
#pragma unroll
        for (int j = 0; j < 4; j++) bfr[j] = *(short8*)&Bs[(wn + j * 16 + l15) * 32 + quad * 8];
#pragma unroll
        for (int i = 0; i < 4; i++)
#pragma unroll
            for (int j = 0; j < 4; j++)
                acc[i][j] = __builtin_amdgcn_mfma_f32_16x16x32_bf16(af[i], bfr[j], acc[i][j], 0, 0, 0);
        __syncthreads();
    }
#pragma unroll
    for (int j = 0; j < 4; j++) {
        int col = n0 + wn + j * 16 + l15;
        int t3 = col / 768;
        int r = col - t3 * 768;
        int h = r >> 6, d = r & 63;
#pragma unroll
        for (int i = 0; i < 4; i++) {
#pragma unroll
            for (int rr = 0; rr < 4; rr++) {
                int m = m0 + wm + i * 16 + quad * 4 + rr;
                int b = m >> 11, s = m & 2047;
                size_t dst = (((size_t)(b * H_ + h) * S_) + s) * HD + d;
                float val = acc[i][j][rr];
                if (t3 == 0)
                    qf[dst] = fmapf(val);
                else if (t3 == 1)
                    kf[dst] = fmapf(val);
                else
                    vv[dst] = val;
            }
        }
    }
}

// ---------------------------------------------------------------------------
// Kernel 2a: partial kv states. Grid = 48 bh * 16 chunks (128 tokens each).
// Vectorized LDS: v reads as float4 (b128), staging as float4 both sides.
// ---------------------------------------------------------------------------
__global__ __launch_bounds__(256) void band_partial(const float* __restrict__ kf,
                                                    const float* __restrict__ vv,
                                                    float* __restrict__ pkv,
                                                    float* __restrict__ pks) {
    int bh = blockIdx.x >> 4, chunk = blockIdx.x & 15;
    int sbase = chunk * 128;
    const float* kfp = kf + (size_t)bh * S_ * HD + (size_t)sbase * HD;
    const float* vp = vv + (size_t)bh * S_ * HD + (size_t)sbase * HD;
    __shared__ float kt[16][64];
    __shared__ float vt[16][64];
    int tid = threadIdx.x;
    int d = tid >> 2, eg = tid & 3, e0 = eg * 16;
    int srow = tid >> 4, scol = (tid & 15) * 4;
    float accg[16], accs[16];
#pragma unroll
    for (int i = 0; i < 16; i++) { accg[i] = 0.f; accs[i] = 0.f; }
    float ksg = 0.f, kss = 0.f;
    for (int s0 = 0; s0 < 128; s0 += 16) {
        *(float4*)&kt[srow][scol] = *(const float4*)&kfp[(size_t)(s0 + srow) * HD + scol];
        *(float4*)&vt[srow][scol] = *(const float4*)&vp[(size_t)(s0 + srow) * HD + scol];
        __syncthreads();
        int m3 = (sbase + s0) % 3;  // block-uniform stride phase
#pragma unroll
        for (int ss = 0; ss < 16; ss++) {
            float kd = kt[ss][d];
            bool str = ((m3 + ss) % 3) == 0;
            ksg += kd;
            float4 v0 = *(float4*)&vt[ss][e0];
            float4 v1 = *(float4*)&vt[ss][e0 + 4];
            float4 v2 = *(float4*)&vt[ss][e0 + 8];
            float4 v3 = *(float4*)&vt[ss][e0 + 12];
            accg[0] += kd * v0.x;  accg[1] += kd * v0.y;
            accg[2] += kd * v0.z;  accg[3] += kd * v0.w;
            accg[4] += kd * v1.x;  accg[5] += kd * v1.y;
            accg[6] += kd * v1.z;  accg[7] += kd * v1.w;
            accg[8] += kd * v2.x;  accg[9] += kd * v2.y;
            accg[10] += kd * v2.z; accg[11] += kd * v2.w;
            accg[12] += kd * v3.x; accg[13] += kd * v3.y;
            accg[14] += kd * v3.z; accg[15] += kd * v3.w;
            if (str) {
                kss += kd;
                accs[0] += kd * v0.x;  accs[1] += kd * v0.y;
                accs[2] += kd * v0.z;  accs[3] += kd * v0.w;
                accs[4] += kd * v1.x;  accs[5] += kd * v1.y;
                accs[6] += kd * v1.z;  accs[7] += kd * v1.w;
                accs[8] += kd * v2.x;  accs[9] += kd * v2.y;
                accs[10] += kd * v2.z; accs[11] += kd * v2.w;
                accs[12] += kd * v3.x; accs[13] += kd * v3.y;
                accs[14] += kd * v3.z; accs[15] += kd * v3.w;
            }
        }
        __syncthreads();
    }
    float* pg = pkv + (size_t)blockIdx.x * 2 * 4096;
#pragma unroll
    for (int i = 0; i < 16; i++) pg[d * 64 + e0 + i] = accg[i];
#pragma unroll
    for (int i = 0; i < 16; i++) pg[4096 + d * 64 + e0 + i] = accs[i];
    if (eg == 0) {
        pks[blockIdx.x * 128 + d] = ksg;
        pks[blockIdx.x * 128 + 64 + d] = kss;
    }
}

// ---------------------------------------------------------------------------
// Kernel 2b: reduce partials + anchor outputs. Grid = 48 bh * 4 e-blocks.
// ---------------------------------------------------------------------------
__global__ __launch_bounds__(256) void band_reduce(const float* __restrict__ pkv,
                                                   const float* __restrict__ pks,
                                                   const float* __restrict__ aq,
                                                   float* __restrict__ kvs,
                                                   float* __restrict__ ksums,
                                                   float* __restrict__ aout) {
    int bh = blockIdx.x >> 2, eb = blockIdx.x & 3, e0 = eb * 16;
    int h = bh % H_;
    __shared__ float kvgL[64][17];
    __shared__ float ksgL[64];
    __shared__ float anorm[12];
    int tid = threadIdx.x;
    for (int idx = tid; idx < 1024; idx += 256) {
        int d = idx >> 4, j = idx & 15;
        float sg = 0.f, ss = 0.f;
        const float* p = pkv + (size_t)(bh * 16) * 2 * 4096 + d * 64 + e0 + j;
#pragma unroll 4
        for (int c = 0; c < 16; c++) {
            sg += p[0];
            ss += p[4096];
            p += 2 * 4096;
        }
        kvgL[d][j] = sg;
        kvs[(size_t)bh * 4096 + d * 64 + e0 + j] = ss;
    }
    if (tid < 64) {
        float sg = 0.f, ss = 0.f;
#pragma unroll 4
        for (int c = 0; c < 16; c++) {
            sg += pks[(bh * 16 + c) * 128 + tid];
            ss += pks[(bh * 16 + c) * 128 + 64 + tid];
        }
        ksgL[tid] = sg;
        if (eb == 0) ksums[bh * 64 + tid] = ss;
    }
    __syncthreads();
    if (tid < 12) {
        float nrm = 0.f;
        for (int dd = 0; dd < 64; dd++)
            nrm += fmapf(aq[h * 768 + tid * 64 + dd]) * ksgL[dd];
        anorm[tid] = fmaxf(nrm, 1e-6f);
    }
    __syncthreads();
    if (tid < 192) {
        int a = tid >> 4, j = tid & 15;
        float acc = 0.f;
        for (int dd = 0; dd < 64; dd++)
            acc += fmapf(aq[h * 768 + a * 64 + dd]) * kvgL[dd][j];
        aout[(size_t)bh * 768 + a * 64 + e0 + j] = acc / anorm[a];
    }
}

// ---------------------------------------------------------------------------
// Kernel 3: combine, all-MFMA version.
//  Per 64-token tile, wave w owns output rows w*16..w*16+15:
//   phase A (MFMA): dense qk_local rows (5 tiles) -> masked bf16 P in LDS;
//                   qkg rows (1 tile) -> bf16 in LDS (col 12 = ns).
//   norms: lanes 0-15 of each wave compute reciprocal weights for own rows.
//   phase B (MFMA): out = P@V^T (3 K-steps) + qkg@aout^T (1) + qf@kvs (2),
//                   epilogue = 3 FMAs per element.
//  plb/qkgb/nrm are wave-private (phase A tiles ti == wave), so only ONE
//  __syncthreads (after staging) is needed; within-wave LDS ordering is
//  handled by lgkmcnt. LDS ~68.3 KB -> 2 blocks/CU.
// ---------------------------------------------------------------------------
__global__ __launch_bounds__(256) void combine(const float* __restrict__ qf,
                                               const float* __restrict__ kf,
                                               const float* __restrict__ vv,
                                               const float* __restrict__ aq,
                                               const float* __restrict__ kvs,
                                               const float* __restrict__ ksums,
                                               const float* __restrict__ aout,
                                               const float* __restrict__ wlp,
                                               const float* __restrict__ wsp,
                                               const float* __restrict__ wgp,
                                               unsigned short* __restrict__ attnb) {
    __shared__ __attribute__((aligned(16))) unsigned short qftb[64][72];   // [token][d]
    __shared__ __attribute__((aligned(16))) unsigned short kftb[80][72];   // [band k][d]
    __shared__ __attribute__((aligned(16))) unsigned short kvsbT[64][72];  // [e][d]
    __shared__ __attribute__((aligned(16))) unsigned short aqfb[16][72];   // anchors + ksum
    __shared__ __attribute__((aligned(16))) unsigned short vtbT[64][104];  // [e][band k], k<96
    __shared__ __attribute__((aligned(16))) unsigned short plb[64][104];   // masked P, [token][band k]
    __shared__ __attribute__((aligned(16))) unsigned short qkgb[64][40];   // [token][anchor k], k<32
    __shared__ __attribute__((aligned(16))) unsigned short aoutT[64][40];  // [e][anchor k], k<32
    __shared__ float nrm[4][3][16];  // per-wave reciprocal weights: wl/nl, wg/ng, ws/ns
    int bh = blockIdx.x >> 5, stile = blockIdx.x & 31;
    int b = bh / H_, h = bh % H_;
    int s0 = stile * 64;
    int tid = threadIdx.x, lane = tid & 63, wave = tid >> 6;
    int quad = lane >> 4, l15 = lane & 15;
    const float* qfp = qf + (size_t)bh * S_ * HD;
    const float* kfp = kf + (size_t)bh * S_ * HD;
    const float* vp = vv + (size_t)bh * S_ * HD;
    float a0 = wlp[0], a1 = wsp[0], a2 = wgp[0];
    float mx = fmaxf(a0, fmaxf(a1, a2));
    float ew0 = __expf(a0 - mx), ew1 = __expf(a1 - mx), ew2 = __expf(a2 - mx);
    float inv = 1.f / (ew0 + ew1 + ew2);
    float wl = ew0 * inv, wsb = ew1 * inv, wg = ew2 * inv;
    // ---- stage bf16 tiles ----
    for (int i = tid; i < 4096; i += 256) {
        int r = i >> 6, c = i & 63;
        qftb[r][c] = f2bu(qfp[(size_t)(s0 + r) * HD + c]);
        kvsbT[c][r] = f2bu(kvs[(size_t)bh * 4096 + i]);  // transpose -> [e][d]
    }
    for (int i = tid; i < 80 * 64; i += 256) {
        int row = i >> 6, c = i & 63;
        int gs = s0 + row - 6;
        float kv_ = (row < 75 && gs >= 0 && gs < S_) ? kfp[(size_t)gs * HD + c] : 1.0f;
        kftb[row][c] = f2bu(kv_);
    }
    for (int i = tid; i < 96 * 64; i += 256) {
        int k = i >> 6, e = i & 63;
        int gs = s0 + k - 6;
        float v_ = (k < 75 && gs >= 0 && gs < S_) ? vp[(size_t)gs * HD + e] : 0.f;
        vtbT[e][k] = f2bu(v_);  // transpose -> [e][band k]; rows k>=75 zero
    }
    for (int i = tid; i < 1024; i += 256) {
        int a = i >> 6, dd = i & 63;
        float v_;
        if (a < 12) v_ = fmapf(aq[h * 768 + a * 64 + dd]);
        else if (a == 12) v_ = ksums[bh * 64 + dd];
        else v_ = 0.f;
        aqfb[a][dd] = f2bu(v_);
    }
    for (int i = tid; i < 2048; i += 256) {
        int e = i >> 5, a = i & 31;
        aoutT[e][a] = (a < 12) ? f2bu(aout[(size_t)bh * 768 + a * 64 + e]) : (unsigned short)0;
    }
    for (int i = tid; i < 1024; i += 256) {
        plb[i >> 4][80 + (i & 15)] = 0;   // K-pad cols 80..95
        qkgb[i >> 4][16 + (i & 15)] = 0;  // K-pad cols 16..31
    }
    __syncthreads();
    // ---- phase A: wave w computes P rows w*16..w*16+15 (wave-private) ----
#pragma unroll
    for (int tj = 0; tj < 5; tj++) {
        f32x4 c = {0.f, 0.f, 0.f, 0.f};
#pragma unroll
        for (int kk = 0; kk < 2; kk++) {
            short8 afr = *(short8*)&qftb[wave * 16 + l15][kk * 32 + quad * 8];
            short8 bfr = *(short8*)&kftb[tj * 16 + l15][kk * 32 + quad * 8];
            c = __builtin_amdgcn_mfma_f32_16x16x32_bf16(afr, bfr, c, 0, 0, 0);
        }
        int col = tj * 16 + l15;
#pragma unroll
        for (int rr = 0; rr < 4; rr++) {
            int tok = wave * 16 + quad * 4 + rr;
            int which = col - tok;
            plb[tok][col] = (which >= 0 && which < 12) ? f2bu(c[rr]) : (unsigned short)0;
        }
    }
    {
        f32x4 c = {0.f, 0.f, 0.f, 0.f};
#pragma unroll
        for (int kk = 0; kk < 2; kk++) {
            short8 afr = *(short8*)&qftb[wave * 16 + l15][kk * 32 + quad * 8];
            short8 bfr = *(short8*)&aqfb[l15][kk * 32 + quad * 8];
            c = __builtin_amdgcn_mfma_f32_16x16x32_bf16(afr, bfr, c, 0, 0, 0);
        }
#pragma unroll
        for (int rr = 0; rr < 4; rr++) qkgb[wave * 16 + quad * 4 + rr][l15] = f2bu(c[rr]);
    }
    // ---- per-wave norms -> reciprocal combine weights (lanes 0-15) ----
    if (lane < 16) {
        int t = wave * 16 + lane;
        float sl = 0.f;
#pragma unroll
        for (int j = 0; j < 12; j++) sl += bu2f(plb[t][t + j]);
        float sg = 0.f;
#pragma unroll
        for (int a = 0; a < 12; a++) sg += bu2f(qkgb[t][a]);
        nrm[wave][0][lane] = wl / fmaxf(sl, 1e-6f);
        nrm[wave][1][lane] = wg / fmaxf(sg, 1e-6f);
        nrm[wave][2][lane] = wsb / fmaxf(bu2f(qkgb[t][12]), 1e-6f);
    }
    // ---- phase B: fused MFMA for all three bands ----
#pragma unroll
    for (int j2 = 0; j2 < 4; j2++) {
        f32x4 cL = {0.f, 0.f, 0.f, 0.f};
        f32x4 cG = {0.f, 0.f, 0.f, 0.f};
        f32x4 cS = {0.f, 0.f, 0.f, 0.f};
#pragma unroll
        for (int kk = 0; kk < 3; kk++) {
            short8 afr = *(short8*)&plb[wave * 16 + l15][kk * 32 + quad * 8];
            short8 bfr = *(short8*)&vtbT[j2 * 16 + l15][kk * 32 + quad * 8];
            cL = __builtin_amdgcn_mfma_f32_16x16x32_bf16(afr, bfr, cL, 0, 0, 0);
        }
        {
            short8 afr = *(short8*)&qkgb[wave * 16 + l15][quad * 8];
            short8 bfr = *(short8*)&aoutT[j2 * 16 + l15][quad * 8];
            cG = __builtin_amdgcn_mfma_f32_16x16x32_bf16(afr, bfr, cG, 0, 0, 0);
        }
#pragma unroll
        for (int kk = 0; kk < 2; kk++) {
            short8 afr = *(short8*)&qftb[wave * 16 + l15][kk * 32 + quad * 8];
            short8 bfr = *(short8*)&kvsbT[j2 * 16 + l15][kk * 32 + quad * 8];
            cS = __builtin_amdgcn_mfma_f32_16x16x32_bf16(afr, bfr, cS, 0, 0, 0);
        }
        int e = j2 * 16 + l15;
#pragma unroll
        for (int rr = 0; rr < 4; rr++) {
            int tq = quad * 4 + rr;
            int tok = wave * 16 + tq;
            float res = cL[rr] * nrm[wave][0][tq] + cS[rr] * nrm[wave][2][tq] +
                        cG[rr] * nrm[wave][1][tq];
            attnb[((size_t)(b * S_ + s0 + tok)) * 768 + h * 64 + e] = f2bu(res);
        }
    }
}

// ---------------------------------------------------------------------------
// Kernel 4: out = attn(bf16) @ out_w.T via bf16 MFMA -> fp32 out.
// m97 structure: linear LDS, global_load_lds width=16 staging.
// ---------------------------------------------------------------------------
__global__ __launch_bounds__(256) void out_gemm_mfma(const unsigned short* __restrict__ attnb,
                                                     const unsigned short* __restrict__ wb,
                                                     float* __restrict__ out) {
    __shared__ __attribute__((aligned(16))) unsigned short As[128 * 32];
    __shared__ __attribute__((aligned(16))) unsigned short Bs[128 * 32];
    const int K = 768;
    int n0 = blockIdx.x * 128, m0 = blockIdx.y * 128;
    int tid = threadIdx.x, lane = tid & 63, wave = tid >> 6;
    int wm = (wave & 1) * 64, wn = (wave >> 1) * 64;
    int quad = lane >> 4, l15 = lane & 15;
    f32x4 acc[4][4];
#pragma unroll
    for (int i = 0; i < 4; i++)
#pragma unroll
        for (int j = 0; j < 4; j++) acc[i][j] = 0.f;

    const unsigned short* ga0 = attnb + (size_t)(m0 + (tid >> 2)) * K + (tid & 3) * 8;
    const unsigned short* ga1 = attnb + (size_t)(m0 + 64 + (tid >> 2)) * K + (tid & 3) * 8;
    const unsigned short* gb0 = wb + (size_t)(n0 + (tid >> 2)) * K + (tid & 3) * 8;
    const unsigned short* gb1 = wb + (size_t)(n0 + 64 + (tid >> 2)) * K + (tid & 3) * 8;
    unsigned short* lA0 = As + wave * 512;
    unsigned short* lA1 = As + 2048 + wave * 512;
    unsigned short* lB0 = Bs + wave * 512;
    unsigned short* lB1 = Bs + 2048 + wave * 512;

    for (int k0 = 0; k0 < K; k0 += 32) {
        gload16(ga0 + k0, lA0);
        gload16(ga1 + k0, lA1);
        gload16(gb0 + k0, lB0);
        gload16(gb1 + k0, lB1);
        __syncthreads();
        short8 af[4], bfr[4];
#pragma unroll
        for (int i = 0; i < 4; i++) af[i] = *(short8*)&As[(wm + i * 16 + l15) * 32 + quad * 8];
#pragma unroll
        for (int j = 0; j < 4; j++) bfr[j] = *(short8*)&Bs[(wn + j * 16 + l15) * 32 + quad * 8];
#pragma unroll
        for (int i = 0; i < 4; i++)
#pragma unroll
            for (int j = 0; j < 4; j++)
                acc[i][j] = __builtin_amdgcn_mfma_f32_16x16x32_bf16(af[i], bfr[j], acc[i][j], 0, 0, 0);
        __syncthreads();
    }
#pragma unroll
    for (int j = 0; j < 4; j++) {
        int col = n0 + wn + j * 16 + l15;
#pragma unroll
        for (int i = 0; i < 4; i++) {
#pragma unroll
            for (int rr = 0; rr < 4; rr++) {
                int m = m0 + wm + i * 16 + quad * 4 + rr;
                out[(size_t)m * 768 + col] = acc[i][j][rr];
            }
        }
    }
}

extern "C" void kernel_launch(void* const* d_in, const int* in_sizes, int n_in,
                              void* d_out, int out_size, void* d_ws, size_t ws_size,
                              hipStream_t stream) {
    const float* x = (const float*)d_in[0];
    const float* qkvw = (const float*)d_in[1];
    const float* outw = (const float*)d_in[2];
    const float* aq = (const float*)d_in[3];
    const float* wlp = (const float*)d_in[4];
    const float* wsp = (const float*)d_in[5];
    const float* wgp = (const float*)d_in[6];

    float* ws = (float*)d_ws;
    const size_t NBH = (size_t)B_ * H_ * S_ * HD;  // 6,291,456
    float* qf = ws;
    float* kf = qf + NBH;
    float* vv = kf + NBH;
    float* attn_region = vv + NBH;       // NBH floats; multi-use scratch
    float* kvs = attn_region + NBH;      // 48*4096
    float* ksums = kvs + 48 * 4096;      // 48*64
    float* aout = ksums + 48 * 64;       // 48*768
    float* pks = aout + 48 * 768;        // 768*128 floats (outside attn_region!)
    // Lifetimes inside attn_region (NBH floats):
    //  [0, 3145728)           xb (bf16 x)      : convert .. qkv_gemm
    //  [3145728, 4030464)     wb (bf16 qkv_w)  : convert .. qkv_gemm
    //  [0, NBH)               pkv              : band_partial .. band_reduce
    //  [0, 3145728)           attnb (bf16 attn): combine .. out_gemm
    // outwb moved past pks (pkv now fills all of attn_region).
    unsigned short* xb = (unsigned short*)attn_region;
    unsigned short* wb = (unsigned short*)(attn_region + 3145728);
    unsigned short* outwb = (unsigned short*)(pks + 768 * 128);
    float* pkv = attn_region;
    unsigned short* attnb = (unsigned short*)attn_region;

    convert_bf16<<<6144, 256, 0, stream>>>(x, xb, 6291456);
    convert_bf16<<<1728, 256, 0, stream>>>(qkvw, wb, 1769472);
    convert_bf16<<<576, 256, 0, stream>>>(outw, outwb, 589824);
    qkv_gemm_mfma<<<dim3(18, 64), 256, 0, stream>>>(xb, wb, qf, kf, vv);
    band_partial<<<48 * 16, 256, 0, stream>>>(kf, vv, pkv, pks);
    band_reduce<<<48 * 4, 256, 0, stream>>>(pkv, pks, aq, kvs, ksums, aout);
    combine<<<48 * 32, 256, 0, stream>>>(qf, kf, vv, aq, kvs, ksums, aout, wlp, wsp, wgp, attnb);
    out_gemm_mfma<<<dim3(6, 64), 256, 0, stream>>>(attnb, outwb, (float*)d_out);
}

// Round 4
// 301.578 us; speedup vs baseline: 1.3644x; 1.0462x over previous
//
#include <hip/hip_runtime.h>
#include <hip/hip_bf16.h>

#define B_ 4
#define S_ 2048
#define D_ 768
#define H_ 12
#define HD 64

typedef __attribute__((ext_vector_type(8))) short short8;
typedef __attribute__((ext_vector_type(4))) float f32x4;

__device__ __forceinline__ float fmapf(float x) { return x > 0.f ? x + 1.f : __expf(x); }

// fp32 -> bf16 round-to-nearest-even (finite inputs only)
__device__ __forceinline__ unsigned short f2bu(float f) {
    unsigned u = __float_as_uint(f);
    u += 0x7FFFu + ((u >> 16) & 1u);
    return (unsigned short)(u >> 16);
}
__device__ __forceinline__ float bu2f(unsigned short v) {
    return __uint_as_float((unsigned)v << 16);
}

// async global->LDS direct copy, 16B per lane. lds ptr must be wave-uniform;
// HW writes lane l to ldsbase + l*16 (m97 pattern: linear LDS dest).
__device__ __forceinline__ void gload16(const void* g, void* l) {
    __builtin_amdgcn_global_load_lds((__attribute__((address_space(1))) void*)(size_t)g,
                                     (__attribute__((address_space(3))) void*)l, 16, 0, 0);
}

// ---------------------------------------------------------------------------
// Kernel 0: fp32 -> bf16 bulk convert (n % 4 == 0).
// ---------------------------------------------------------------------------
__global__ __launch_bounds__(256) void convert_bf16(const float* __restrict__ src,
                                                    unsigned short* __restrict__ dst,
                                                    int n) {
    int i = (blockIdx.x * 256 + threadIdx.x) * 4;
    if (i < n) {
        float4 v = *(const float4*)&src[i];
        ushort4 o;
        o.x = f2bu(v.x); o.y = f2bu(v.y); o.z = f2bu(v.z); o.w = f2bu(v.w);
        *(ushort4*)&dst[i] = o;
    }
}

// ---------------------------------------------------------------------------
// Kernel 1: qkv = x @ qkv_w.T via bf16 MFMA (16x16x32), fp32 accumulate.
// m97 structure + double-buffered LDS (stage t+1 before compute t, one
// barrier per K-step) + bijective XCD swizzle (1152 blocks, 144/XCD chunk
// = 8 m-rows sharing the full w-panel in one XCD's L2).
// ---------------------------------------------------------------------------
__global__ __launch_bounds__(256) void qkv_gemm_mfma(const unsigned short* __restrict__ xb,
                                                     const unsigned short* __restrict__ wb,
                                                     float* __restrict__ qf,
                                                     float* __restrict__ kf,
                                                     float* __restrict__ vv) {
    __shared__ __attribute__((aligned(16))) unsigned short As[2][128 * 32];
    __shared__ __attribute__((aligned(16))) unsigned short Bs[2][128 * 32];
    const int K = 768;
    // XCD-aware bijective swizzle: nwg=1152, 1152%8==0, chunk=144.
    int orig = blockIdx.x;
    int swz = (orig & 7) * 144 + (orig >> 3);
    int mt = swz / 18, nt = swz - mt * 18;
    int n0 = nt * 128, m0 = mt * 128;
    int tid = threadIdx.x, lane = tid & 63, wave = tid >> 6;
    int wm = (wave & 1) * 64, wn = (wave >> 1) * 64;
    int quad = lane >> 4, l15 = lane & 15;
    f32x4 acc[4][4];
#pragma unroll
    for (int i = 0; i < 4; i++)
#pragma unroll
        for (int j = 0; j < 4; j++) acc[i][j] = 0.f;

    const unsigned short* ga0 = xb + (size_t)(m0 + (tid >> 2)) * K + (tid & 3) * 8;
    const unsigned short* ga1 = xb + (size_t)(m0 + 64 + (tid >> 2)) * K + (tid & 3) * 8;
    const unsigned short* gb0 = wb + (size_t)(n0 + (tid >> 2)) * K + (tid & 3) * 8;
    const unsigned short* gb1 = wb + (size_t)(n0 + 64 + (tid >> 2)) * K + (tid & 3) * 8;

    // prologue: stage K-step 0 into buf 0
    gload16(ga0, &As[0][wave * 512]);
    gload16(ga1, &As[0][2048 + wave * 512]);
    gload16(gb0, &Bs[0][wave * 512]);
    gload16(gb1, &Bs[0][2048 + wave * 512]);
    __syncthreads();

    int buf = 0;
    for (int k0 = 0; k0 < K; k0 += 32) {
        int nb = buf ^ 1;
        if (k0 + 32 < K) {  // stage next K-step while computing this one
            gload16(ga0 + k0 + 32, &As[nb][wave * 512]);
            gload16(ga1 + k0 + 32, &As[nb][2048 + wave * 512]);
            gload16(gb0 + k0 + 32, &Bs[nb][wave * 512]);
            gload16(gb1 + k0 + 32, &Bs[nb][2048 + wave * 512]);
        }
        short8 af[4], bfr[4];
#pragma unroll
        for (int i = 0; i < 4; i++)
            af[i] = *(short8*)&As[buf][(wm + i * 16 + l15) * 32 + quad * 8];
#pragma unroll
        for (int j = 0; j < 4; j++)
            bfr[j] = *(short8*)&Bs[buf][(wn + j * 16 + l15) * 32 + quad * 8];
#pragma unroll
        for (int i = 0; i < 4; i++)
#pragma unroll
            for (int j = 0; j < 4; j++)
                acc[i][j] = __builtin_amdgcn_mfma_f32_16x16x32_bf16(af[i], bfr[j], acc[i][j], 0, 0, 0);
        __syncthreads();  // drains next-step loads (had full compute phase in flight)
        buf = nb;
    }
#pragma unroll
    for (int j = 0; j < 4; j++) {
        int col = n0 + wn + j * 16 + l15;
        int t3 = col / 768;
        int r = col - t3 * 768;
        int h = r >> 6, d = r & 63;
#pragma unroll
        for (int i = 0; i < 4; i++) {
#pragma unroll
            for (int rr = 0; rr < 4; rr++) {
                int m = m0 + wm + i * 16 + quad * 4 + rr;
                int b = m >> 11, s = m & 2047;
                size_t dst = (((size_t)(b * H_ + h) * S_) + s) * HD + d;
                float val = acc[i][j][rr];
                if (t3 == 0)
                    qf[dst] = fmapf(val);
                else if (t3 == 1)
                    kf[dst] = fmapf(val);
                else
                    vv[dst] = val;
            }
        }
    }
}

// ---------------------------------------------------------------------------
// Kernel 2a: partial kv states. Grid = 48 bh * 16 chunks (128 tokens each).
// Vectorized LDS: v reads as float4 (b128), staging as float4 both sides.
// ---------------------------------------------------------------------------
__global__ __launch_bounds__(256) void band_partial(const float* __restrict__ kf,
                                                    const float* __restrict__ vv,
                                                    float* __restrict__ pkv,
                                                    float* __restrict__ pks) {
    int bh = blockIdx.x >> 4, chunk = blockIdx.x & 15;
    int sbase = chunk * 128;
    const float* kfp = kf + (size_t)bh * S_ * HD + (size_t)sbase * HD;
    const float* vp = vv + (size_t)bh * S_ * HD + (size_t)sbase * HD;
    __shared__ float kt[16][64];
    __shared__ float vt[16][64];
    int tid = threadIdx.x;
    int d = tid >> 2, eg = tid & 3, e0 = eg * 16;
    int srow = tid >> 4, scol = (tid & 15) * 4;
    float accg[16], accs[16];
#pragma unroll
    for (int i = 0; i < 16; i++) { accg[i] = 0.f; accs[i] = 0.f; }
    float ksg = 0.f, kss = 0.f;
    for (int s0 = 0; s0 < 128; s0 += 16) {
        *(float4*)&kt[srow][scol] = *(const float4*)&kfp[(size_t)(s0 + srow) * HD + scol];
        *(float4*)&vt[srow][scol] = *(const float4*)&vp[(size_t)(s0 + srow) * HD + scol];
        __syncthreads();
        int m3 = (sbase + s0) % 3;  // block-uniform stride phase
#pragma unroll
        for (int ss = 0; ss < 16; ss++) {
            float kd = kt[ss][d];
            bool str = ((m3 + ss) % 3) == 0;
            ksg += kd;
            float4 v0 = *(float4*)&vt[ss][e0];
            float4 v1 = *(float4*)&vt[ss][e0 + 4];
            float4 v2 = *(float4*)&vt[ss][e0 + 8];
            float4 v3 = *(float4*)&vt[ss][e0 + 12];
            accg[0] += kd * v0.x;  accg[1] += kd * v0.y;
            accg[2] += kd * v0.z;  accg[3] += kd * v0.w;
            accg[4] += kd * v1.x;  accg[5] += kd * v1.y;
            accg[6] += kd * v1.z;  accg[7] += kd * v1.w;
            accg[8] += kd * v2.x;  accg[9] += kd * v2.y;
            accg[10] += kd * v2.z; accg[11] += kd * v2.w;
            accg[12] += kd * v3.x; accg[13] += kd * v3.y;
            accg[14] += kd * v3.z; accg[15] += kd * v3.w;
            if (str) {
                kss += kd;
                accs[0] += kd * v0.x;  accs[1] += kd * v0.y;
                accs[2] += kd * v0.z;  accs[3] += kd * v0.w;
                accs[4] += kd * v1.x;  accs[5] += kd * v1.y;
                accs[6] += kd * v1.z;  accs[7] += kd * v1.w;
                accs[8] += kd * v2.x;  accs[9] += kd * v2.y;
                accs[10] += kd * v2.z; accs[11] += kd * v2.w;
                accs[12] += kd * v3.x; accs[13] += kd * v3.y;
                accs[14] += kd * v3.z; accs[15] += kd * v3.w;
            }
        }
        __syncthreads();
    }
    float* pg = pkv + (size_t)blockIdx.x * 2 * 4096;
#pragma unroll
    for (int i = 0; i < 16; i++) pg[d * 64 + e0 + i] = accg[i];
#pragma unroll
    for (int i = 0; i < 16; i++) pg[4096 + d * 64 + e0 + i] = accs[i];
    if (eg == 0) {
        pks[blockIdx.x * 128 + d] = ksg;
        pks[blockIdx.x * 128 + 64 + d] = kss;
    }
}

// ---------------------------------------------------------------------------
// Kernel 2b: reduce partials + anchor outputs. Grid = 48 bh * 4 e-blocks.
// ---------------------------------------------------------------------------
__global__ __launch_bounds__(256) void band_reduce(const float* __restrict__ pkv,
                                                   const float* __restrict__ pks,
                                                   const float* __restrict__ aq,
                                                   float* __restrict__ kvs,
                                                   float* __restrict__ ksums,
                                                   float* __restrict__ aout) {
    int bh = blockIdx.x >> 2, eb = blockIdx.x & 3, e0 = eb * 16;
    int h = bh % H_;
    __shared__ float kvgL[64][17];
    __shared__ float ksgL[64];
    __shared__ float anorm[12];
    int tid = threadIdx.x;
    for (int idx = tid; idx < 1024; idx += 256) {
        int d = idx >> 4, j = idx & 15;
        float sg = 0.f, ss = 0.f;
        const float* p = pkv + (size_t)(bh * 16) * 2 * 4096 + d * 64 + e0 + j;
#pragma unroll 4
        for (int c = 0; c < 16; c++) {
            sg += p[0];
            ss += p[4096];
            p += 2 * 4096;
        }
        kvgL[d][j] = sg;
        kvs[(size_t)bh * 4096 + d * 64 + e0 + j] = ss;
    }
    if (tid < 64) {
        float sg = 0.f, ss = 0.f;
#pragma unroll 4
        for (int c = 0; c < 16; c++) {
            sg += pks[(bh * 16 + c) * 128 + tid];
            ss += pks[(bh * 16 + c) * 128 + 64 + tid];
        }
        ksgL[tid] = sg;
        if (eb == 0) ksums[bh * 64 + tid] = ss;
    }
    __syncthreads();
    if (tid < 12) {
        float nrm = 0.f;
        for (int dd = 0; dd < 64; dd++)
            nrm += fmapf(aq[h * 768 + tid * 64 + dd]) * ksgL[dd];
        anorm[tid] = fmaxf(nrm, 1e-6f);
    }
    __syncthreads();
    if (tid < 192) {
        int a = tid >> 4, j = tid & 15;
        float acc = 0.f;
        for (int dd = 0; dd < 64; dd++)
            acc += fmapf(aq[h * 768 + a * 64 + dd]) * kvgL[dd][j];
        aout[(size_t)bh * 768 + a * 64 + e0 + j] = acc / anorm[a];
    }
}

// ---------------------------------------------------------------------------
// Kernel 3: combine, all-MFMA version (unchanged from round 2).
// ---------------------------------------------------------------------------
__global__ __launch_bounds__(256) void combine(const float* __restrict__ qf,
                                               const float* __restrict__ kf,
                                               const float* __restrict__ vv,
                                               const float* __restrict__ aq,
                                               const float* __restrict__ kvs,
                                               const float* __restrict__ ksums,
                                               const float* __restrict__ aout,
                                               const float* __restrict__ wlp,
                                               const float* __restrict__ wsp,
                                               const float* __restrict__ wgp,
                                               unsigned short* __restrict__ attnb) {
    __shared__ __attribute__((aligned(16))) unsigned short qftb[64][72];   // [token][d]
    __shared__ __attribute__((aligned(16))) unsigned short kftb[80][72];   // [band k][d]
    __shared__ __attribute__((aligned(16))) unsigned short kvsbT[64][72];  // [e][d]
    __shared__ __attribute__((aligned(16))) unsigned short aqfb[16][72];   // anchors + ksum
    __shared__ __attribute__((aligned(16))) unsigned short vtbT[64][104];  // [e][band k], k<96
    __shared__ __attribute__((aligned(16))) unsigned short plb[64][104];   // masked P, [token][band k]
    __shared__ __attribute__((aligned(16))) unsigned short qkgb[64][40];   // [token][anchor k], k<32
    __shared__ __attribute__((aligned(16))) unsigned short aoutT[64][40];  // [e][anchor k], k<32
    __shared__ float nrm[4][3][16];  // per-wave reciprocal weights: wl/nl, wg/ng, ws/ns
    int bh = blockIdx.x >> 5, stile = blockIdx.x & 31;
    int b = bh / H_, h = bh % H_;
    int s0 = stile * 64;
    int tid = threadIdx.x, lane = tid & 63, wave = tid >> 6;
    int quad = lane >> 4, l15 = lane & 15;
    const float* qfp = qf + (size_t)bh * S_ * HD;
    const float* kfp = kf + (size_t)bh * S_ * HD;
    const float* vp = vv + (size_t)bh * S_ * HD;
    float a0 = wlp[0], a1 = wsp[0], a2 = wgp[0];
    float mx = fmaxf(a0, fmaxf(a1, a2));
    float ew0 = __expf(a0 - mx), ew1 = __expf(a1 - mx), ew2 = __expf(a2 - mx);
    float inv = 1.f / (ew0 + ew1 + ew2);
    float wl = ew0 * inv, wsb = ew1 * inv, wg = ew2 * inv;
    // ---- stage bf16 tiles ----
    for (int i = tid; i < 4096; i += 256) {
        int r = i >> 6, c = i & 63;
        qftb[r][c] = f2bu(qfp[(size_t)(s0 + r) * HD + c]);
        kvsbT[c][r] = f2bu(kvs[(size_t)bh * 4096 + i]);  // transpose -> [e][d]
    }
    for (int i = tid; i < 80 * 64; i += 256) {
        int row = i >> 6, c = i & 63;
        int gs = s0 + row - 6;
        float kv_ = (row < 75 && gs >= 0 && gs < S_) ? kfp[(size_t)gs * HD + c] : 1.0f;
        kftb[row][c] = f2bu(kv_);
    }
    for (int i = tid; i < 96 * 64; i += 256) {
        int k = i >> 6, e = i & 63;
        int gs = s0 + k - 6;
        float v_ = (k < 75 && gs >= 0 && gs < S_) ? vp[(size_t)gs * HD + e] : 0.f;
        vtbT[e][k] = f2bu(v_);  // transpose -> [e][band k]; rows k>=75 zero
    }
    for (int i = tid; i < 1024; i += 256) {
        int a = i >> 6, dd = i & 63;
        float v_;
        if (a < 12) v_ = fmapf(aq[h * 768 + a * 64 + dd]);
        else if (a == 12) v_ = ksums[bh * 64 + dd];
        else v_ = 0.f;
        aqfb[a][dd] = f2bu(v_);
    }
    for (int i = tid; i < 2048; i += 256) {
        int e = i >> 5, a = i & 31;
        aoutT[e][a] = (a < 12) ? f2bu(aout[(size_t)bh * 768 + a * 64 + e]) : (unsigned short)0;
    }
    for (int i = tid; i < 1024; i += 256) {
        plb[i >> 4][80 + (i & 15)] = 0;   // K-pad cols 80..95
        qkgb[i >> 4][16 + (i & 15)] = 0;  // K-pad cols 16..31
    }
    __syncthreads();
    // ---- phase A: wave w computes P rows w*16..w*16+15 (wave-private) ----
#pragma unroll
    for (int tj = 0; tj < 5; tj++) {
        f32x4 c = {0.f, 0.f, 0.f, 0.f};
#pragma unroll
        for (int kk = 0; kk < 2; kk++) {
            short8 afr = *(short8*)&qftb[wave * 16 + l15][kk * 32 + quad * 8];
            short8 bfr = *(short8*)&kftb[tj * 16 + l15][kk * 32 + quad * 8];
            c = __builtin_amdgcn_mfma_f32_16x16x32_bf16(afr, bfr, c, 0, 0, 0);
        }
        int col = tj * 16 + l15;
#pragma unroll
        for (int rr = 0; rr < 4; rr++) {
            int tok = wave * 16 + quad * 4 + rr;
            int which = col - tok;
            plb[tok][col] = (which >= 0 && which < 12) ? f2bu(c[rr]) : (unsigned short)0;
        }
    }
    {
        f32x4 c = {0.f, 0.f, 0.f, 0.f};
#pragma unroll
        for (int kk = 0; kk < 2; kk++) {
            short8 afr = *(short8*)&qftb[wave * 16 + l15][kk * 32 + quad * 8];
            short8 bfr = *(short8*)&aqfb[l15][kk * 32 + quad * 8];
            c = __builtin_amdgcn_mfma_f32_16x16x32_bf16(afr, bfr, c, 0, 0, 0);
        }
#pragma unroll
        for (int rr = 0; rr < 4; rr++) qkgb[wave * 16 + quad * 4 + rr][l15] = f2bu(c[rr]);
    }
    // ---- per-wave norms -> reciprocal combine weights (lanes 0-15) ----
    if (lane < 16) {
        int t = wave * 16 + lane;
        float sl = 0.f;
#pragma unroll
        for (int j = 0; j < 12; j++) sl += bu2f(plb[t][t + j]);
        float sg = 0.f;
#pragma unroll
        for (int a = 0; a < 12; a++) sg += bu2f(qkgb[t][a]);
        nrm[wave][0][lane] = wl / fmaxf(sl, 1e-6f);
        nrm[wave][1][lane] = wg / fmaxf(sg, 1e-6f);
        nrm[wave][2][lane] = wsb / fmaxf(bu2f(qkgb[t][12]), 1e-6f);
    }
    // ---- phase B: fused MFMA for all three bands ----
#pragma unroll
    for (int j2 = 0; j2 < 4; j2++) {
        f32x4 cL = {0.f, 0.f, 0.f, 0.f};
        f32x4 cG = {0.f, 0.f, 0.f, 0.f};
        f32x4 cS = {0.f, 0.f, 0.f, 0.f};
#pragma unroll
        for (int kk = 0; kk < 3; kk++) {
            short8 afr = *(short8*)&plb[wave * 16 + l15][kk * 32 + quad * 8];
            short8 bfr = *(short8*)&vtbT[j2 * 16 + l15][kk * 32 + quad * 8];
            cL = __builtin_amdgcn_mfma_f32_16x16x32_bf16(afr, bfr, cL, 0, 0, 0);
        }
        {
            short8 afr = *(short8*)&qkgb[wave * 16 + l15][quad * 8];
            short8 bfr = *(short8*)&aoutT[j2 * 16 + l15][quad * 8];
            cG = __builtin_amdgcn_mfma_f32_16x16x32_bf16(afr, bfr, cG, 0, 0, 0);
        }
#pragma unroll
        for (int kk = 0; kk < 2; kk++) {
            short8 afr = *(short8*)&qftb[wave * 16 + l15][kk * 32 + quad * 8];
            short8 bfr = *(short8*)&kvsbT[j2 * 16 + l15][kk * 32 + quad * 8];
            cS = __builtin_amdgcn_mfma_f32_16x16x32_bf16(afr, bfr, cS, 0, 0, 0);
        }
        int e = j2 * 16 + l15;
#pragma unroll
        for (int rr = 0; rr < 4; rr++) {
            int tq = quad * 4 + rr;
            int tok = wave * 16 + tq;
            float res = cL[rr] * nrm[wave][0][tq] + cS[rr] * nrm[wave][2][tq] +
                        cG[rr] * nrm[wave][1][tq];
            attnb[((size_t)(b * S_ + s0 + tok)) * 768 + h * 64 + e] = f2bu(res);
        }
    }
}

// ---------------------------------------------------------------------------
// Kernel 4: out = attn(bf16) @ out_w.T, dbuf + XCD swizzle (384 blocks).
// ---------------------------------------------------------------------------
__global__ __launch_bounds__(256) void out_gemm_mfma(const unsigned short* __restrict__ attnb,
                                                     const unsigned short* __restrict__ wb,
                                                     float* __restrict__ out) {
    __shared__ __attribute__((aligned(16))) unsigned short As[2][128 * 32];
    __shared__ __attribute__((aligned(16))) unsigned short Bs[2][128 * 32];
    const int K = 768;
    // XCD-aware bijective swizzle: nwg=384, chunk=48 (8 m-rows x 6 n-tiles).
    int orig = blockIdx.x;
    int swz = (orig & 7) * 48 + (orig >> 3);
    int mt = swz / 6, nt = swz - mt * 6;
    int n0 = nt * 128, m0 = mt * 128;
    int tid = threadIdx.x, lane = tid & 63, wave = tid >> 6;
    int wm = (wave & 1) * 64, wn = (wave >> 1) * 64;
    int quad = lane >> 4, l15 = lane & 15;
    f32x4 acc[4][4];
#pragma unroll
    for (int i = 0; i < 4; i++)
#pragma unroll
        for (int j = 0; j < 4; j++) acc[i][j] = 0.f;

    const unsigned short* ga0 = attnb + (size_t)(m0 + (tid >> 2)) * K + (tid & 3) * 8;
    const unsigned short* ga1 = attnb + (size_t)(m0 + 64 + (tid >> 2)) * K + (tid & 3) * 8;
    const unsigned short* gb0 = wb + (size_t)(n0 + (tid >> 2)) * K + (tid & 3) * 8;
    const unsigned short* gb1 = wb + (size_t)(n0 + 64 + (tid >> 2)) * K + (tid & 3) * 8;

    gload16(ga0, &As[0][wave * 512]);
    gload16(ga1, &As[0][2048 + wave * 512]);
    gload16(gb0, &Bs[0][wave * 512]);
    gload16(gb1, &Bs[0][2048 + wave * 512]);
    __syncthreads();

    int buf = 0;
    for (int k0 = 0; k0 < K; k0 += 32) {
        int nb = buf ^ 1;
        if (k0 + 32 < K) {
            gload16(ga0 + k0 + 32, &As[nb][wave * 512]);
            gload16(ga1 + k0 + 32, &As[nb][2048 + wave * 512]);
            gload16(gb0 + k0 + 32, &Bs[nb][wave * 512]);
            gload16(gb1 + k0 + 32, &Bs[nb][2048 + wave * 512]);
        }
        short8 af[4], bfr[4];
#pragma unroll
        for (int i = 0; i < 4; i++)
            af[i] = *(short8*)&As[buf][(wm + i * 16 + l15) * 32 + quad * 8];
#pragma unroll
        for (int j = 0; j < 4; j++)
            bfr[j] = *(short8*)&Bs[buf][(wn + j * 16 + l15) * 32 + quad * 8];
#pragma unroll
        for (int i = 0; i < 4; i++)
#pragma unroll
            for (int j = 0; j < 4; j++)
                acc[i][j] = __builtin_amdgcn_mfma_f32_16x16x32_bf16(af[i], bfr[j], acc[i][j], 0, 0, 0);
        __syncthreads();
        buf = nb;
    }
#pragma unroll
    for (int j = 0; j < 4; j++) {
        int col = n0 + wn + j * 16 + l15;
#pragma unroll
        for (int i = 0; i < 4; i++) {
#pragma unroll
            for (int rr = 0; rr < 4; rr++) {
                int m = m0 + wm + i * 16 + quad * 4 + rr;
                out[(size_t)m * 768 + col] = acc[i][j][rr];
            }
        }
    }
}

extern "C" void kernel_launch(void* const* d_in, const int* in_sizes, int n_in,
                              void* d_out, int out_size, void* d_ws, size_t ws_size,
                              hipStream_t stream) {
    const float* x = (const float*)d_in[0];
    const float* qkvw = (const float*)d_in[1];
    const float* outw = (const float*)d_in[2];
    const float* aq = (const float*)d_in[3];
    const float* wlp = (const float*)d_in[4];
    const float* wsp = (const float*)d_in[5];
    const float* wgp = (const float*)d_in[6];

    float* ws = (float*)d_ws;
    const size_t NBH = (size_t)B_ * H_ * S_ * HD;  // 6,291,456
    float* qf = ws;
    float* kf = qf + NBH;
    float* vv = kf + NBH;
    float* attn_region = vv + NBH;       // NBH floats; multi-use scratch
    float* kvs = attn_region + NBH;      // 48*4096
    float* ksums = kvs + 48 * 4096;      // 48*64
    float* aout = ksums + 48 * 64;       // 48*768
    float* pks = aout + 48 * 768;        // 768*128 floats (outside attn_region!)
    // Lifetimes inside attn_region (NBH floats):
    //  [0, 3145728)           xb (bf16 x)      : convert .. qkv_gemm
    //  [3145728, 4030464)     wb (bf16 qkv_w)  : convert .. qkv_gemm
    //  [0, NBH)               pkv              : band_partial .. band_reduce
    //  [0, 3145728)           attnb (bf16 attn): combine .. out_gemm
    // outwb moved past pks (pkv now fills all of attn_region).
    unsigned short* xb = (unsigned short*)attn_region;
    unsigned short* wb = (unsigned short*)(attn_region + 3145728);
    unsigned short* outwb = (unsigned short*)(pks + 768 * 128);
    float* pkv = attn_region;
    unsigned short* attnb = (unsigned short*)attn_region;

    convert_bf16<<<6144, 256, 0, stream>>>(x, xb, 6291456);
    convert_bf16<<<1728, 256, 0, stream>>>(qkvw, wb, 1769472);
    convert_bf16<<<576, 256, 0, stream>>>(outw, outwb, 589824);
    qkv_gemm_mfma<<<1152, 256, 0, stream>>>(xb, wb, qf, kf, vv);
    band_partial<<<48 * 16, 256, 0, stream>>>(kf, vv, pkv, pks);
    band_reduce<<<48 * 4, 256, 0, stream>>>(pkv, pks, aq, kvs, ksums, aout);
    combine<<<48 * 32, 256, 0, stream>>>(qf, kf, vv, aq, kvs, ksums, aout, wlp, wsp, wgp, attnb);
    out_gemm_mfma<<<384, 256, 0, stream>>>(attnb, outwb, (float*)d_out);
}

// Round 5
// 284.873 us; speedup vs baseline: 1.4444x; 1.0586x over previous
//
#include <hip/hip_runtime.h>
#include <hip/hip_bf16.h>

#define B_ 4
#define S_ 2048
#define D_ 768
#define H_ 12
#define HD 64

typedef __attribute__((ext_vector_type(8))) short short8;
typedef __attribute__((ext_vector_type(4))) float f32x4;

__device__ __forceinline__ float fmapf(float x) { return x > 0.f ? x + 1.f : __expf(x); }

// fp32 -> bf16 round-to-nearest-even (finite inputs only)
__device__ __forceinline__ unsigned short f2bu(float f) {
    unsigned u = __float_as_uint(f);
    u += 0x7FFFu + ((u >> 16) & 1u);
    return (unsigned short)(u >> 16);
}
__device__ __forceinline__ float bu2f(unsigned short v) {
    return __uint_as_float((unsigned)v << 16);
}

// async global->LDS direct copy, 16B per lane. lds ptr must be wave-uniform;
// HW writes lane l to ldsbase + l*16 (m97 pattern: linear LDS dest).
__device__ __forceinline__ void gload16(const void* g, void* l) {
    __builtin_amdgcn_global_load_lds((__attribute__((address_space(1))) void*)(size_t)g,
                                     (__attribute__((address_space(3))) void*)l, 16, 0, 0);
}

// ---------------------------------------------------------------------------
// Kernel 0: fp32 -> bf16 bulk convert (n % 4 == 0).
// ---------------------------------------------------------------------------
__global__ __launch_bounds__(256) void convert_bf16(const float* __restrict__ src,
                                                    unsigned short* __restrict__ dst,
                                                    int n) {
    int i = (blockIdx.x * 256 + threadIdx.x) * 4;
    if (i < n) {
        float4 v = *(const float4*)&src[i];
        ushort4 o;
        o.x = f2bu(v.x); o.y = f2bu(v.y); o.z = f2bu(v.z); o.w = f2bu(v.w);
        *(ushort4*)&dst[i] = o;
    }
}

// ---------------------------------------------------------------------------
// Kernel 0b: precompute fmap(anchor_q) as bf16 (9216 elems).
// ---------------------------------------------------------------------------
__global__ __launch_bounds__(256) void prep_aqf(const float* __restrict__ aq,
                                                unsigned short* __restrict__ aqfb_g) {
    int i = blockIdx.x * 256 + threadIdx.x;
    if (i < 9216) aqfb_g[i] = f2bu(fmapf(aq[i]));
}

// ---------------------------------------------------------------------------
// Kernel 1: qkv = x @ qkv_w.T via bf16 MFMA. m97 structure + dbuf + XCD
// swizzle. Epilogue: q -> bf16 only (qfb); k -> fp32 (kf, for band_partial)
// AND bf16 (kfb, for combine); v -> fp32 (vv).
// ---------------------------------------------------------------------------
__global__ __launch_bounds__(256) void qkv_gemm_mfma(const unsigned short* __restrict__ xb,
                                                     const unsigned short* __restrict__ wb,
                                                     unsigned short* __restrict__ qfb,
                                                     float* __restrict__ kf,
                                                     unsigned short* __restrict__ kfb,
                                                     float* __restrict__ vv) {
    __shared__ __attribute__((aligned(16))) unsigned short As[2][128 * 32];
    __shared__ __attribute__((aligned(16))) unsigned short Bs[2][128 * 32];
    const int K = 768;
    // XCD-aware bijective swizzle: nwg=1152, 1152%8==0, chunk=144.
    int orig = blockIdx.x;
    int swz = (orig & 7) * 144 + (orig >> 3);
    int mt = swz / 18, nt = swz - mt * 18;
    int n0 = nt * 128, m0 = mt * 128;
    int tid = threadIdx.x, lane = tid & 63, wave = tid >> 6;
    int wm = (wave & 1) * 64, wn = (wave >> 1) * 64;
    int quad = lane >> 4, l15 = lane & 15;
    f32x4 acc[4][4];
#pragma unroll
    for (int i = 0; i < 4; i++)
#pragma unroll
        for (int j = 0; j < 4; j++) acc[i][j] = 0.f;

    const unsigned short* ga0 = xb + (size_t)(m0 + (tid >> 2)) * K + (tid & 3) * 8;
    const unsigned short* ga1 = xb + (size_t)(m0 + 64 + (tid >> 2)) * K + (tid & 3) * 8;
    const unsigned short* gb0 = wb + (size_t)(n0 + (tid >> 2)) * K + (tid & 3) * 8;
    const unsigned short* gb1 = wb + (size_t)(n0 + 64 + (tid >> 2)) * K + (tid & 3) * 8;

    gload16(ga0, &As[0][wave * 512]);
    gload16(ga1, &As[0][2048 + wave * 512]);
    gload16(gb0, &Bs[0][wave * 512]);
    gload16(gb1, &Bs[0][2048 + wave * 512]);
    __syncthreads();

    int buf = 0;
    for (int k0 = 0; k0 < K; k0 += 32) {
        int nb = buf ^ 1;
        if (k0 + 32 < K) {
            gload16(ga0 + k0 + 32, &As[nb][wave * 512]);
            gload16(ga1 + k0 + 32, &As[nb][2048 + wave * 512]);
            gload16(gb0 + k0 + 32, &Bs[nb][wave * 512]);
            gload16(gb1 + k0 + 32, &Bs[nb][2048 + wave * 512]);
        }
        short8 af[4], bfr[4];
#pragma unroll
        for (int i = 0; i < 4; i++)
            af[i] = *(short8*)&As[buf][(wm + i * 16 + l15) * 32 + quad * 8];
#pragma unroll
        for (int j = 0; j < 4; j++)
            bfr[j] = *(short8*)&Bs[buf][(wn + j * 16 + l15) * 32 + quad * 8];
#pragma unroll
        for (int i = 0; i < 4; i++)
#pragma unroll
            for (int j = 0; j < 4; j++)
                acc[i][j] = __builtin_amdgcn_mfma_f32_16x16x32_bf16(af[i], bfr[j], acc[i][j], 0, 0, 0);
        __syncthreads();
        buf = nb;
    }
#pragma unroll
    for (int j = 0; j < 4; j++) {
        int col = n0 + wn + j * 16 + l15;
        int t3 = col / 768;
        int r = col - t3 * 768;
        int h = r >> 6, d = r & 63;
#pragma unroll
        for (int i = 0; i < 4; i++) {
#pragma unroll
            for (int rr = 0; rr < 4; rr++) {
                int m = m0 + wm + i * 16 + quad * 4 + rr;
                int b = m >> 11, s = m & 2047;
                size_t dst = (((size_t)(b * H_ + h) * S_) + s) * HD + d;
                float val = acc[i][j][rr];
                if (t3 == 0) {
                    qfb[dst] = f2bu(fmapf(val));
                } else if (t3 == 1) {
                    float fv = fmapf(val);
                    kf[dst] = fv;
                    kfb[dst] = f2bu(fv);
                } else {
                    vv[dst] = val;
                }
            }
        }
    }
}

// ---------------------------------------------------------------------------
// Kernel 2a: partial kv states. Grid = 48 bh * 16 chunks (128 tokens each).
// ---------------------------------------------------------------------------
__global__ __launch_bounds__(256) void band_partial(const float* __restrict__ kf,
                                                    const float* __restrict__ vv,
                                                    float* __restrict__ pkv,
                                                    float* __restrict__ pks) {
    int bh = blockIdx.x >> 4, chunk = blockIdx.x & 15;
    int sbase = chunk * 128;
    const float* kfp = kf + (size_t)bh * S_ * HD + (size_t)sbase * HD;
    const float* vp = vv + (size_t)bh * S_ * HD + (size_t)sbase * HD;
    __shared__ float kt[16][64];
    __shared__ float vt[16][64];
    int tid = threadIdx.x;
    int d = tid >> 2, eg = tid & 3, e0 = eg * 16;
    int srow = tid >> 4, scol = (tid & 15) * 4;
    float accg[16], accs[16];
#pragma unroll
    for (int i = 0; i < 16; i++) { accg[i] = 0.f; accs[i] = 0.f; }
    float ksg = 0.f, kss = 0.f;
    for (int s0 = 0; s0 < 128; s0 += 16) {
        *(float4*)&kt[srow][scol] = *(const float4*)&kfp[(size_t)(s0 + srow) * HD + scol];
        *(float4*)&vt[srow][scol] = *(const float4*)&vp[(size_t)(s0 + srow) * HD + scol];
        __syncthreads();
        int m3 = (sbase + s0) % 3;  // block-uniform stride phase
#pragma unroll
        for (int ss = 0; ss < 16; ss++) {
            float kd = kt[ss][d];
            bool str = ((m3 + ss) % 3) == 0;
            ksg += kd;
            float4 v0 = *(float4*)&vt[ss][e0];
            float4 v1 = *(float4*)&vt[ss][e0 + 4];
            float4 v2 = *(float4*)&vt[ss][e0 + 8];
            float4 v3 = *(float4*)&vt[ss][e0 + 12];
            accg[0] += kd * v0.x;  accg[1] += kd * v0.y;
            accg[2] += kd * v0.z;  accg[3] += kd * v0.w;
            accg[4] += kd * v1.x;  accg[5] += kd * v1.y;
            accg[6] += kd * v1.z;  accg[7] += kd * v1.w;
            accg[8] += kd * v2.x;  accg[9] += kd * v2.y;
            accg[10] += kd * v2.z; accg[11] += kd * v2.w;
            accg[12] += kd * v3.x; accg[13] += kd * v3.y;
            accg[14] += kd * v3.z; accg[15] += kd * v3.w;
            if (str) {
                kss += kd;
                accs[0] += kd * v0.x;  accs[1] += kd * v0.y;
                accs[2] += kd * v0.z;  accs[3] += kd * v0.w;
                accs[4] += kd * v1.x;  accs[5] += kd * v1.y;
                accs[6] += kd * v1.z;  accs[7] += kd * v1.w;
                accs[8] += kd * v2.x;  accs[9] += kd * v2.y;
                accs[10] += kd * v2.z; accs[11] += kd * v2.w;
                accs[12] += kd * v3.x; accs[13] += kd * v3.y;
                accs[14] += kd * v3.z; accs[15] += kd * v3.w;
            }
        }
        __syncthreads();
    }
    float* pg = pkv + (size_t)blockIdx.x * 2 * 4096;
#pragma unroll
    for (int i = 0; i < 16; i++) pg[d * 64 + e0 + i] = accg[i];
#pragma unroll
    for (int i = 0; i < 16; i++) pg[4096 + d * 64 + e0 + i] = accs[i];
    if (eg == 0) {
        pks[blockIdx.x * 128 + d] = ksg;
        pks[blockIdx.x * 128 + 64 + d] = kss;
    }
}

// ---------------------------------------------------------------------------
// Kernel 2b: reduce partials + anchor outputs. Grid = 48 bh * 4 e-blocks.
// Outputs pre-transposed, pre-converted bf16 for combine: kvsTb[e][d],
// aoutTb[e][a], ksumsb (all f2bu of the fp32 combine used to convert).
// ---------------------------------------------------------------------------
__global__ __launch_bounds__(256) void band_reduce(const float* __restrict__ pkv,
                                                   const float* __restrict__ pks,
                                                   const float* __restrict__ aq,
                                                   unsigned short* __restrict__ kvsTb,
                                                   unsigned short* __restrict__ ksumsb,
                                                   unsigned short* __restrict__ aoutTb) {
    int bh = blockIdx.x >> 2, eb = blockIdx.x & 3, e0 = eb * 16;
    int h = bh % H_;
    __shared__ float kvgL[64][17];
    __shared__ float ksgL[64];
    __shared__ float anorm[12];
    int tid = threadIdx.x;
    for (int idx = tid; idx < 1024; idx += 256) {
        int d = idx >> 4, j = idx & 15;
        float sg = 0.f, ss = 0.f;
        const float* p = pkv + (size_t)(bh * 16) * 2 * 4096 + d * 64 + e0 + j;
#pragma unroll 4
        for (int c = 0; c < 16; c++) {
            sg += p[0];
            ss += p[4096];
            p += 2 * 4096;
        }
        kvgL[d][j] = sg;
        kvsTb[(size_t)bh * 4096 + (e0 + j) * 64 + d] = f2bu(ss);
    }
    if (tid < 64) {
        float sg = 0.f, ss = 0.f;
#pragma unroll 4
        for (int c = 0; c < 16; c++) {
            sg += pks[(bh * 16 + c) * 128 + tid];
            ss += pks[(bh * 16 + c) * 128 + 64 + tid];
        }
        ksgL[tid] = sg;
        if (eb == 0) ksumsb[bh * 64 + tid] = f2bu(ss);
    }
    __syncthreads();
    if (tid < 12) {
        float nrm = 0.f;
        for (int dd = 0; dd < 64; dd++)
            nrm += fmapf(aq[h * 768 + tid * 64 + dd]) * ksgL[dd];
        anorm[tid] = fmaxf(nrm, 1e-6f);
    }
    __syncthreads();
    if (tid < 192) {
        int a = tid >> 4, j = tid & 15;
        float acc = 0.f;
        for (int dd = 0; dd < 64; dd++)
            acc += fmapf(aq[h * 768 + a * 64 + dd]) * kvgL[dd][j];
        aoutTb[(size_t)bh * 768 + (e0 + j) * 12 + a] = f2bu(acc / anorm[a]);
    }
}

// ---------------------------------------------------------------------------
// Kernel 3: combine, all-MFMA. Staging now mostly short8 copies from bf16
// sources (qfb/kfb/kvsTb/aqfb_g/aoutTb); only vtbT keeps the fp32 scalar
// transpose. Values bit-identical to previous round.
// ---------------------------------------------------------------------------
__global__ __launch_bounds__(256) void combine(const unsigned short* __restrict__ qfb,
                                               const unsigned short* __restrict__ kfb,
                                               const float* __restrict__ vv,
                                               const unsigned short* __restrict__ aqfb_g,
                                               const unsigned short* __restrict__ kvsTb,
                                               const unsigned short* __restrict__ ksumsb,
                                               const unsigned short* __restrict__ aoutTb,
                                               const float* __restrict__ wlp,
                                               const float* __restrict__ wsp,
                                               const float* __restrict__ wgp,
                                               unsigned short* __restrict__ attnb) {
    __shared__ __attribute__((aligned(16))) unsigned short qftb[64][72];   // [token][d]
    __shared__ __attribute__((aligned(16))) unsigned short kftb[80][72];   // [band k][d]
    __shared__ __attribute__((aligned(16))) unsigned short kvsbT[64][72];  // [e][d]
    __shared__ __attribute__((aligned(16))) unsigned short aqfb[16][72];   // anchors + ksum
    __shared__ __attribute__((aligned(16))) unsigned short vtbT[64][104];  // [e][band k], k<96
    __shared__ __attribute__((aligned(16))) unsigned short plb[64][104];   // masked P, [token][band k]
    __shared__ __attribute__((aligned(16))) unsigned short qkgb[64][40];   // [token][anchor k], k<32
    __shared__ __attribute__((aligned(16))) unsigned short aoutT[64][40];  // [e][anchor k], k<32
    __shared__ float nrm[4][3][16];  // per-wave reciprocal weights: wl/nl, wg/ng, ws/ns
    int bh = blockIdx.x >> 5, stile = blockIdx.x & 31;
    int b = bh / H_, h = bh % H_;
    int s0 = stile * 64;
    int tid = threadIdx.x, lane = tid & 63, wave = tid >> 6;
    int quad = lane >> 4, l15 = lane & 15;
    const unsigned short* qfp = qfb + (size_t)bh * S_ * HD;
    const unsigned short* kfp = kfb + (size_t)bh * S_ * HD;
    const float* vp = vv + (size_t)bh * S_ * HD;
    float a0 = wlp[0], a1 = wsp[0], a2 = wgp[0];
    float mx = fmaxf(a0, fmaxf(a1, a2));
    float ew0 = __expf(a0 - mx), ew1 = __expf(a1 - mx), ew2 = __expf(a2 - mx);
    float inv = 1.f / (ew0 + ew1 + ew2);
    float wl = ew0 * inv, wsb = ew1 * inv, wg = ew2 * inv;
    // ---- stage bf16 tiles (vector copies) ----
    {
        int r = tid >> 2, c = (tid & 3) * 16;
        *(short8*)&qftb[r][c] = *(const short8*)&qfp[(size_t)(s0 + r) * HD + c];
        *(short8*)&qftb[r][c + 8] = *(const short8*)&qfp[(size_t)(s0 + r) * HD + c + 8];
        const unsigned short* kp = kvsTb + (size_t)bh * 4096 + r * 64 + c;
        *(short8*)&kvsbT[r][c] = *(const short8*)&kp[0];
        *(short8*)&kvsbT[r][c + 8] = *(const short8*)&kp[8];
    }
    for (int row = tid >> 2; row < 80; row += 64) {
        int c = (tid & 3) * 16;
        int gs = s0 + row - 6;
        if (row < 75 && gs >= 0 && gs < S_) {
            *(short8*)&kftb[row][c] = *(const short8*)&kfp[(size_t)gs * HD + c];
            *(short8*)&kftb[row][c + 8] = *(const short8*)&kfp[(size_t)gs * HD + c + 8];
        } else {
            short8 ones = {0x3F80, 0x3F80, 0x3F80, 0x3F80, 0x3F80, 0x3F80, 0x3F80, 0x3F80};
            *(short8*)&kftb[row][c] = ones;
            *(short8*)&kftb[row][c + 8] = ones;
        }
    }
    for (int i = tid; i < 96 * 64; i += 256) {
        int k = i >> 6, e = i & 63;
        int gs = s0 + k - 6;
        float v_ = (k < 75 && gs >= 0 && gs < S_) ? vp[(size_t)gs * HD + e] : 0.f;
        vtbT[e][k] = f2bu(v_);  // transpose -> [e][band k]; rows k>=75 zero
    }
    if (tid < 192) {  // aqfb rows 0-11 from precomputed bf16
        int a = tid >> 4, c = (tid & 15) * 4;
        *(ushort4*)&aqfb[a][c] = *(const ushort4*)&aqfb_g[h * 768 + a * 64 + c];
    }
    if (tid < 64) aqfb[12][tid] = ksumsb[bh * 64 + tid];
    if (tid < 192) aqfb[13 + (tid >> 6)][tid & 63] = 0;
    for (int i = tid; i < 64 * 20; i += 256) {  // aoutT pad cols 12-31
        int e = i / 20, c = 12 + i - e * 20;
        aoutT[e][c] = 0;
    }
    for (int i = tid; i < 768; i += 256) {
        int e = i / 12, a = i - e * 12;
        aoutT[e][a] = aoutTb[(size_t)bh * 768 + i];
    }
    for (int i = tid; i < 1024; i += 256) {
        plb[i >> 4][80 + (i & 15)] = 0;   // K-pad cols 80..95
        qkgb[i >> 4][16 + (i & 15)] = 0;  // K-pad cols 16..31
    }
    __syncthreads();
    // ---- phase A: wave w computes P rows w*16..w*16+15 (wave-private) ----
#pragma unroll
    for (int tj = 0; tj < 5; tj++) {
        f32x4 c = {0.f, 0.f, 0.f, 0.f};
#pragma unroll
        for (int kk = 0; kk < 2; kk++) {
            short8 afr = *(short8*)&qftb[wave * 16 + l15][kk * 32 + quad * 8];
            short8 bfr = *(short8*)&kftb[tj * 16 + l15][kk * 32 + quad * 8];
            c = __builtin_amdgcn_mfma_f32_16x16x32_bf16(afr, bfr, c, 0, 0, 0);
        }
        int col = tj * 16 + l15;
#pragma unroll
        for (int rr = 0; rr < 4; rr++) {
            int tok = wave * 16 + quad * 4 + rr;
            int which = col - tok;
            plb[tok][col] = (which >= 0 && which < 12) ? f2bu(c[rr]) : (unsigned short)0;
        }
    }
    {
        f32x4 c = {0.f, 0.f, 0.f, 0.f};
#pragma unroll
        for (int kk = 0; kk < 2; kk++) {
            short8 afr = *(short8*)&qftb[wave * 16 + l15][kk * 32 + quad * 8];
            short8 bfr = *(short8*)&aqfb[l15][kk * 32 + quad * 8];
            c = __builtin_amdgcn_mfma_f32_16x16x32_bf16(afr, bfr, c, 0, 0, 0);
        }
#pragma unroll
        for (int rr = 0; rr < 4; rr++) qkgb[wave * 16 + quad * 4 + rr][l15] = f2bu(c[rr]);
    }
    // ---- per-wave norms -> reciprocal combine weights (lanes 0-15) ----
    if (lane < 16) {
        int t = wave * 16 + lane;
        float sl = 0.f;
#pragma unroll
        for (int j = 0; j < 12; j++) sl += bu2f(plb[t][t + j]);
        float sg = 0.f;
#pragma unroll
        for (int a = 0; a < 12; a++) sg += bu2f(qkgb[t][a]);
        nrm[wave][0][lane] = wl / fmaxf(sl, 1e-6f);
        nrm[wave][1][lane] = wg / fmaxf(sg, 1e-6f);
        nrm[wave][2][lane] = wsb / fmaxf(bu2f(qkgb[t][12]), 1e-6f);
    }
    // ---- phase B: fused MFMA for all three bands ----
#pragma unroll
    for (int j2 = 0; j2 < 4; j2++) {
        f32x4 cL = {0.f, 0.f, 0.f, 0.f};
        f32x4 cG = {0.f, 0.f, 0.f, 0.f};
        f32x4 cS = {0.f, 0.f, 0.f, 0.f};
#pragma unroll
        for (int kk = 0; kk < 3; kk++) {
            short8 afr = *(short8*)&plb[wave * 16 + l15][kk * 32 + quad * 8];
            short8 bfr = *(short8*)&vtbT[j2 * 16 + l15][kk * 32 + quad * 8];
            cL = __builtin_amdgcn_mfma_f32_16x16x32_bf16(afr, bfr, cL, 0, 0, 0);
        }
        {
            short8 afr = *(short8*)&qkgb[wave * 16 + l15][quad * 8];
            short8 bfr = *(short8*)&aoutT[j2 * 16 + l15][quad * 8];
            cG = __builtin_amdgcn_mfma_f32_16x16x32_bf16(afr, bfr, cG, 0, 0, 0);
        }
#pragma unroll
        for (int kk = 0; kk < 2; kk++) {
            short8 afr = *(short8*)&qftb[wave * 16 + l15][kk * 32 + quad * 8];
            short8 bfr = *(short8*)&kvsbT[j2 * 16 + l15][kk * 32 + quad * 8];
            cS = __builtin_amdgcn_mfma_f32_16x16x32_bf16(afr, bfr, cS, 0, 0, 0);
        }
        int e = j2 * 16 + l15;
#pragma unroll
        for (int rr = 0; rr < 4; rr++) {
            int tq = quad * 4 + rr;
            int tok = wave * 16 + tq;
            float res = cL[rr] * nrm[wave][0][tq] + cS[rr] * nrm[wave][2][tq] +
                        cG[rr] * nrm[wave][1][tq];
            attnb[((size_t)(b * S_ + s0 + tok)) * 768 + h * 64 + e] = f2bu(res);
        }
    }
}

// ---------------------------------------------------------------------------
// Kernel 4: out = attn(bf16) @ out_w.T, dbuf + XCD swizzle (384 blocks).
// ---------------------------------------------------------------------------
__global__ __launch_bounds__(256) void out_gemm_mfma(const unsigned short* __restrict__ attnb,
                                                     const unsigned short* __restrict__ wb,
                                                     float* __restrict__ out) {
    __shared__ __attribute__((aligned(16))) unsigned short As[2][128 * 32];
    __shared__ __attribute__((aligned(16))) unsigned short Bs[2][128 * 32];
    const int K = 768;
    int orig = blockIdx.x;
    int swz = (orig & 7) * 48 + (orig >> 3);
    int mt = swz / 6, nt = swz - mt * 6;
    int n0 = nt * 128, m0 = mt * 128;
    int tid = threadIdx.x, lane = tid & 63, wave = tid >> 6;
    int wm = (wave & 1) * 64, wn = (wave >> 1) * 64;
    int quad = lane >> 4, l15 = lane & 15;
    f32x4 acc[4][4];
#pragma unroll
    for (int i = 0; i < 4; i++)
#pragma unroll
        for (int j = 0; j < 4; j++) acc[i][j] = 0.f;

    const unsigned short* ga0 = attnb + (size_t)(m0 + (tid >> 2)) * K + (tid & 3) * 8;
    const unsigned short* ga1 = attnb + (size_t)(m0 + 64 + (tid >> 2)) * K + (tid & 3) * 8;
    const unsigned short* gb0 = wb + (size_t)(n0 + (tid >> 2)) * K + (tid & 3) * 8;
    const unsigned short* gb1 = wb + (size_t)(n0 + 64 + (tid >> 2)) * K + (tid & 3) * 8;

    gload16(ga0, &As[0][wave * 512]);
    gload16(ga1, &As[0][2048 + wave * 512]);
    gload16(gb0, &Bs[0][wave * 512]);
    gload16(gb1, &Bs[0][2048 + wave * 512]);
    __syncthreads();

    int buf = 0;
    for (int k0 = 0; k0 < K; k0 += 32) {
        int nb = buf ^ 1;
        if (k0 + 32 < K) {
            gload16(ga0 + k0 + 32, &As[nb][wave * 512]);
            gload16(ga1 + k0 + 32, &As[nb][2048 + wave * 512]);
            gload16(gb0 + k0 + 32, &Bs[nb][wave * 512]);
            gload16(gb1 + k0 + 32, &Bs[nb][2048 + wave * 512]);
        }
        short8 af[4], bfr[4];
#pragma unroll
        for (int i = 0; i < 4; i++)
            af[i] = *(short8*)&As[buf][(wm + i * 16 + l15) * 32 + quad * 8];
#pragma unroll
        for (int j = 0; j < 4; j++)
            bfr[j] = *(short8*)&Bs[buf][(wn + j * 16 + l15) * 32 + quad * 8];
#pragma unroll
        for (int i = 0; i < 4; i++)
#pragma unroll
            for (int j = 0; j < 4; j++)
                acc[i][j] = __builtin_amdgcn_mfma_f32_16x16x32_bf16(af[i], bfr[j], acc[i][j], 0, 0, 0);
        __syncthreads();
        buf = nb;
    }
#pragma unroll
    for (int j = 0; j < 4; j++) {
        int col = n0 + wn + j * 16 + l15;
#pragma unroll
        for (int i = 0; i < 4; i++) {
#pragma unroll
            for (int rr = 0; rr < 4; rr++) {
                int m = m0 + wm + i * 16 + quad * 4 + rr;
                out[(size_t)m * 768 + col] = acc[i][j][rr];
            }
        }
    }
}

extern "C" void kernel_launch(void* const* d_in, const int* in_sizes, int n_in,
                              void* d_out, int out_size, void* d_ws, size_t ws_size,
                              hipStream_t stream) {
    const float* x = (const float*)d_in[0];
    const float* qkvw = (const float*)d_in[1];
    const float* outw = (const float*)d_in[2];
    const float* aq = (const float*)d_in[3];
    const float* wlp = (const float*)d_in[4];
    const float* wsp = (const float*)d_in[5];
    const float* wgp = (const float*)d_in[6];

    float* ws = (float*)d_ws;
    const size_t NBH = (size_t)B_ * H_ * S_ * HD;  // 6,291,456
    // Region 0 [0, NBH): bf16 qfb (NBH ushorts) + bf16 kfb (NBH ushorts)
    unsigned short* qfb = (unsigned short*)ws;
    unsigned short* kfb = (unsigned short*)(ws + NBH / 2);
    float* kf = ws + NBH;                 // fp32 k (band_partial)
    float* vv = ws + 2 * NBH;             // fp32 v
    float* attn_region = ws + 3 * NBH;    // NBH floats; multi-use scratch
    //  [0, 3145728)  xb (bf16 x)      : convert .. qkv_gemm
    //  [3145728, 4030464) wb (bf16 qkv_w): convert .. qkv_gemm
    //  [0, NBH)      pkv              : band_partial .. band_reduce
    //  [0, 3145728)  attnb (bf16 attn): combine .. out_gemm
    unsigned short* xb = (unsigned short*)attn_region;
    unsigned short* wb = (unsigned short*)(attn_region + 3145728);
    float* pkv = attn_region;
    unsigned short* attnb = (unsigned short*)attn_region;
    // Post-region small buffers (all bf16 except pks):
    unsigned short* kvsTb = (unsigned short*)(attn_region + NBH);   // 48*4096
    unsigned short* ksumsb = kvsTb + 48 * 4096;                     // 48*64
    unsigned short* aoutTb = ksumsb + 48 * 64;                      // 48*768
    unsigned short* aqfb_g = aoutTb + 48 * 768;                     // 9216
    // total ushorts above = 196608+3072+36864+9216 = 245760 -> 122880 floats
    float* pks = attn_region + NBH + 122880;                        // 768*128 floats
    unsigned short* outwb = (unsigned short*)(pks + 768 * 128);

    convert_bf16<<<6144, 256, 0, stream>>>(x, xb, 6291456);
    convert_bf16<<<1728, 256, 0, stream>>>(qkvw, wb, 1769472);
    convert_bf16<<<576, 256, 0, stream>>>(outw, outwb, 589824);
    prep_aqf<<<36, 256, 0, stream>>>(aq, aqfb_g);
    qkv_gemm_mfma<<<1152, 256, 0, stream>>>(xb, wb, qfb, kf, kfb, vv);
    band_partial<<<48 * 16, 256, 0, stream>>>(kf, vv, pkv, pks);
    band_reduce<<<48 * 4, 256, 0, stream>>>(pkv, pks, aq, kvsTb, ksumsb, aoutTb);
    combine<<<48 * 32, 256, 0, stream>>>(qfb, kfb, vv, aqfb_g, kvsTb, ksumsb, aoutTb,
                                         wlp, wsp, wgp, attnb);
    out_gemm_mfma<<<384, 256, 0, stream>>>(attnb, outwb, (float*)d_out);
}

// Round 6
// 284.008 us; speedup vs baseline: 1.4488x; 1.0030x over previous
//
#include <hip/hip_runtime.h>
#include <hip/hip_bf16.h>

#define B_ 4
#define S_ 2048
#define D_ 768
#define H_ 12
#define HD 64

typedef __attribute__((ext_vector_type(8))) short short8;
typedef __attribute__((ext_vector_type(4))) float f32x4;

__device__ __forceinline__ float fmapf(float x) { return x > 0.f ? x + 1.f : __expf(x); }

// fp32 -> bf16 round-to-nearest-even (finite inputs only)
__device__ __forceinline__ unsigned short f2bu(float f) {
    unsigned u = __float_as_uint(f);
    u += 0x7FFFu + ((u >> 16) & 1u);
    return (unsigned short)(u >> 16);
}
__device__ __forceinline__ float bu2f(unsigned short v) {
    return __uint_as_float((unsigned)v << 16);
}

// async global->LDS direct copy, 16B per lane. lds ptr must be wave-uniform;
// HW writes lane l to ldsbase + l*16 (m97 pattern: linear LDS dest).
__device__ __forceinline__ void gload16(const void* g, void* l) {
    __builtin_amdgcn_global_load_lds((__attribute__((address_space(1))) void*)(size_t)g,
                                     (__attribute__((address_space(3))) void*)l, 16, 0, 0);
}

// ---------------------------------------------------------------------------
// Kernel 0: fp32 -> bf16 bulk convert (n % 4 == 0).
// ---------------------------------------------------------------------------
__global__ __launch_bounds__(256) void convert_bf16(const float* __restrict__ src,
                                                    unsigned short* __restrict__ dst,
                                                    int n) {
    int i = (blockIdx.x * 256 + threadIdx.x) * 4;
    if (i < n) {
        float4 v = *(const float4*)&src[i];
        ushort4 o;
        o.x = f2bu(v.x); o.y = f2bu(v.y); o.z = f2bu(v.z); o.w = f2bu(v.w);
        *(ushort4*)&dst[i] = o;
    }
}

// ---------------------------------------------------------------------------
// Kernel 0b: precompute fmap(anchor_q) as bf16 (9216 elems).
// ---------------------------------------------------------------------------
__global__ __launch_bounds__(256) void prep_aqf(const float* __restrict__ aq,
                                                unsigned short* __restrict__ aqfb_g) {
    int i = blockIdx.x * 256 + threadIdx.x;
    if (i < 9216) aqfb_g[i] = f2bu(fmapf(aq[i]));
}

// ---------------------------------------------------------------------------
// Kernel 1: qkv = x @ qkv_w.T via bf16 MFMA. dbuf + XCD swizzle +
// COUNTED vmcnt (T4): never drain vmcnt(0) in the main loop. Two raw
// s_barriers per K-step; tile t's loads get a full iteration in flight.
// ---------------------------------------------------------------------------
__global__ __launch_bounds__(256) void qkv_gemm_mfma(const unsigned short* __restrict__ xb,
                                                     const unsigned short* __restrict__ wb,
                                                     unsigned short* __restrict__ qfb,
                                                     float* __restrict__ kf,
                                                     unsigned short* __restrict__ kfb,
                                                     float* __restrict__ vv) {
    __shared__ __attribute__((aligned(16))) unsigned short As[2][128 * 32];
    __shared__ __attribute__((aligned(16))) unsigned short Bs[2][128 * 32];
    const int K = 768;
    // XCD-aware bijective swizzle: nwg=1152, 1152%8==0, chunk=144.
    int orig = blockIdx.x;
    int swz = (orig & 7) * 144 + (orig >> 3);
    int mt = swz / 18, nt = swz - mt * 18;
    int n0 = nt * 128, m0 = mt * 128;
    int tid = threadIdx.x, lane = tid & 63, wave = tid >> 6;
    int wm = (wave & 1) * 64, wn = (wave >> 1) * 64;
    int quad = lane >> 4, l15 = lane & 15;
    f32x4 acc[4][4];
#pragma unroll
    for (int i = 0; i < 4; i++)
#pragma unroll
        for (int j = 0; j < 4; j++) acc[i][j] = 0.f;

    const unsigned short* ga0 = xb + (size_t)(m0 + (tid >> 2)) * K + (tid & 3) * 8;
    const unsigned short* ga1 = xb + (size_t)(m0 + 64 + (tid >> 2)) * K + (tid & 3) * 8;
    const unsigned short* gb0 = wb + (size_t)(n0 + (tid >> 2)) * K + (tid & 3) * 8;
    const unsigned short* gb1 = wb + (size_t)(n0 + 64 + (tid >> 2)) * K + (tid & 3) * 8;

    auto stage = [&](int bufi, int kk) {
        gload16(ga0 + kk, &As[bufi][wave * 512]);
        gload16(ga1 + kk, &As[bufi][2048 + wave * 512]);
        gload16(gb0 + kk, &Bs[bufi][wave * 512]);
        gload16(gb1 + kk, &Bs[bufi][2048 + wave * 512]);
    };
    auto compute = [&](int bufi) {
        short8 af[4], bfr[4];
#pragma unroll
        for (int i = 0; i < 4; i++)
            af[i] = *(short8*)&As[bufi][(wm + i * 16 + l15) * 32 + quad * 8];
#pragma unroll
        for (int j = 0; j < 4; j++)
            bfr[j] = *(short8*)&Bs[bufi][(wn + j * 16 + l15) * 32 + quad * 8];
#pragma unroll
        for (int i = 0; i < 4; i++)
#pragma unroll
            for (int j = 0; j < 4; j++)
                acc[i][j] = __builtin_amdgcn_mfma_f32_16x16x32_bf16(af[i], bfr[j], acc[i][j], 0, 0, 0);
    };

    stage(0, 0);  // prologue: tile 0 in flight
    int buf = 0;
    for (int t = 0; t < 23; t++) {
        stage(buf ^ 1, (t + 1) * 32);                 // tile t+1 in flight (8 outstanding)
        asm volatile("s_waitcnt vmcnt(4)" ::: "memory");  // my tile-t loads landed
        __builtin_amdgcn_s_barrier();                 // => ALL waves' tile-t loads landed
        __builtin_amdgcn_sched_barrier(0);
        compute(buf);
        asm volatile("" ::: "memory");
        __builtin_amdgcn_s_barrier();                 // all reads of buf done -> next iter may overwrite
        buf ^= 1;
    }
    asm volatile("s_waitcnt vmcnt(0)" ::: "memory");  // last tile
    __builtin_amdgcn_s_barrier();
    __builtin_amdgcn_sched_barrier(0);
    compute(buf);

#pragma unroll
    for (int j = 0; j < 4; j++) {
        int col = n0 + wn + j * 16 + l15;
        int t3 = col / 768;
        int r = col - t3 * 768;
        int h = r >> 6, d = r & 63;
#pragma unroll
        for (int i = 0; i < 4; i++) {
#pragma unroll
            for (int rr = 0; rr < 4; rr++) {
                int m = m0 + wm + i * 16 + quad * 4 + rr;
                int b = m >> 11, s = m & 2047;
                size_t dst = (((size_t)(b * H_ + h) * S_) + s) * HD + d;
                float val = acc[i][j][rr];
                if (t3 == 0) {
                    qfb[dst] = f2bu(fmapf(val));
                } else if (t3 == 1) {
                    float fv = fmapf(val);
                    kf[dst] = fv;
                    kfb[dst] = f2bu(fv);
                } else {
                    vv[dst] = val;
                }
            }
        }
    }
}

// ---------------------------------------------------------------------------
// Kernel 2a: partial kv states. Grid = 48 bh * 16 chunks (128 tokens each).
// ---------------------------------------------------------------------------
__global__ __launch_bounds__(256) void band_partial(const float* __restrict__ kf,
                                                    const float* __restrict__ vv,
                                                    float* __restrict__ pkv,
                                                    float* __restrict__ pks) {
    int bh = blockIdx.x >> 4, chunk = blockIdx.x & 15;
    int sbase = chunk * 128;
    const float* kfp = kf + (size_t)bh * S_ * HD + (size_t)sbase * HD;
    const float* vp = vv + (size_t)bh * S_ * HD + (size_t)sbase * HD;
    __shared__ float kt[16][64];
    __shared__ float vt[16][64];
    int tid = threadIdx.x;
    int d = tid >> 2, eg = tid & 3, e0 = eg * 16;
    int srow = tid >> 4, scol = (tid & 15) * 4;
    float accg[16], accs[16];
#pragma unroll
    for (int i = 0; i < 16; i++) { accg[i] = 0.f; accs[i] = 0.f; }
    float ksg = 0.f, kss = 0.f;
    for (int s0 = 0; s0 < 128; s0 += 16) {
        *(float4*)&kt[srow][scol] = *(const float4*)&kfp[(size_t)(s0 + srow) * HD + scol];
        *(float4*)&vt[srow][scol] = *(const float4*)&vp[(size_t)(s0 + srow) * HD + scol];
        __syncthreads();
        int m3 = (sbase + s0) % 3;  // block-uniform stride phase
#pragma unroll
        for (int ss = 0; ss < 16; ss++) {
            float kd = kt[ss][d];
            bool str = ((m3 + ss) % 3) == 0;
            ksg += kd;
            float4 v0 = *(float4*)&vt[ss][e0];
            float4 v1 = *(float4*)&vt[ss][e0 + 4];
            float4 v2 = *(float4*)&vt[ss][e0 + 8];
            float4 v3 = *(float4*)&vt[ss][e0 + 12];
            accg[0] += kd * v0.x;  accg[1] += kd * v0.y;
            accg[2] += kd * v0.z;  accg[3] += kd * v0.w;
            accg[4] += kd * v1.x;  accg[5] += kd * v1.y;
            accg[6] += kd * v1.z;  accg[7] += kd * v1.w;
            accg[8] += kd * v2.x;  accg[9] += kd * v2.y;
            accg[10] += kd * v2.z; accg[11] += kd * v2.w;
            accg[12] += kd * v3.x; accg[13] += kd * v3.y;
            accg[14] += kd * v3.z; accg[15] += kd * v3.w;
            if (str) {
                kss += kd;
                accs[0] += kd * v0.x;  accs[1] += kd * v0.y;
                accs[2] += kd * v0.z;  accs[3] += kd * v0.w;
                accs[4] += kd * v1.x;  accs[5] += kd * v1.y;
                accs[6] += kd * v1.z;  accs[7] += kd * v1.w;
                accs[8] += kd * v2.x;  accs[9] += kd * v2.y;
                accs[10] += kd * v2.z; accs[11] += kd * v2.w;
                accs[12] += kd * v3.x; accs[13] += kd * v3.y;
                accs[14] += kd * v3.z; accs[15] += kd * v3.w;
            }
        }
        __syncthreads();
    }
    float* pg = pkv + (size_t)blockIdx.x * 2 * 4096;
#pragma unroll
    for (int i = 0; i < 16; i++) pg[d * 64 + e0 + i] = accg[i];
#pragma unroll
    for (int i = 0; i < 16; i++) pg[4096 + d * 64 + e0 + i] = accs[i];
    if (eg == 0) {
        pks[blockIdx.x * 128 + d] = ksg;
        pks[blockIdx.x * 128 + 64 + d] = kss;
    }
}

// ---------------------------------------------------------------------------
// Kernel 2b: reduce partials + anchor outputs. Grid = 48 bh * 4 e-blocks.
// ---------------------------------------------------------------------------
__global__ __launch_bounds__(256) void band_reduce(const float* __restrict__ pkv,
                                                   const float* __restrict__ pks,
                                                   const float* __restrict__ aq,
                                                   unsigned short* __restrict__ kvsTb,
                                                   unsigned short* __restrict__ ksumsb,
                                                   unsigned short* __restrict__ aoutTb) {
    int bh = blockIdx.x >> 2, eb = blockIdx.x & 3, e0 = eb * 16;
    int h = bh % H_;
    __shared__ float kvgL[64][17];
    __shared__ float ksgL[64];
    __shared__ float anorm[12];
    int tid = threadIdx.x;
    for (int idx = tid; idx < 1024; idx += 256) {
        int d = idx >> 4, j = idx & 15;
        float sg = 0.f, ss = 0.f;
        const float* p = pkv + (size_t)(bh * 16) * 2 * 4096 + d * 64 + e0 + j;
#pragma unroll 4
        for (int c = 0; c < 16; c++) {
            sg += p[0];
            ss += p[4096];
            p += 2 * 4096;
        }
        kvgL[d][j] = sg;
        kvsTb[(size_t)bh * 4096 + (e0 + j) * 64 + d] = f2bu(ss);
    }
    if (tid < 64) {
        float sg = 0.f, ss = 0.f;
#pragma unroll 4
        for (int c = 0; c < 16; c++) {
            sg += pks[(bh * 16 + c) * 128 + tid];
            ss += pks[(bh * 16 + c) * 128 + 64 + tid];
        }
        ksgL[tid] = sg;
        if (eb == 0) ksumsb[bh * 64 + tid] = f2bu(ss);
    }
    __syncthreads();
    if (tid < 12) {
        float nrm = 0.f;
        for (int dd = 0; dd < 64; dd++)
            nrm += fmapf(aq[h * 768 + tid * 64 + dd]) * ksgL[dd];
        anorm[tid] = fmaxf(nrm, 1e-6f);
    }
    __syncthreads();
    if (tid < 192) {
        int a = tid >> 4, j = tid & 15;
        float acc = 0.f;
        for (int dd = 0; dd < 64; dd++)
            acc += fmapf(aq[h * 768 + a * 64 + dd]) * kvgL[dd][j];
        aoutTb[(size_t)bh * 768 + (e0 + j) * 12 + a] = f2bu(acc / anorm[a]);
    }
}

// ---------------------------------------------------------------------------
// Kernel 3: combine, all-MFMA (unchanged from round 5).
// ---------------------------------------------------------------------------
__global__ __launch_bounds__(256) void combine(const unsigned short* __restrict__ qfb,
                                               const unsigned short* __restrict__ kfb,
                                               const float* __restrict__ vv,
                                               const unsigned short* __restrict__ aqfb_g,
                                               const unsigned short* __restrict__ kvsTb,
                                               const unsigned short* __restrict__ ksumsb,
                                               const unsigned short* __restrict__ aoutTb,
                                               const float* __restrict__ wlp,
                                               const float* __restrict__ wsp,
                                               const float* __restrict__ wgp,
                                               unsigned short* __restrict__ attnb) {
    __shared__ __attribute__((aligned(16))) unsigned short qftb[64][72];   // [token][d]
    __shared__ __attribute__((aligned(16))) unsigned short kftb[80][72];   // [band k][d]
    __shared__ __attribute__((aligned(16))) unsigned short kvsbT[64][72];  // [e][d]
    __shared__ __attribute__((aligned(16))) unsigned short aqfb[16][72];   // anchors + ksum
    __shared__ __attribute__((aligned(16))) unsigned short vtbT[64][104];  // [e][band k], k<96
    __shared__ __attribute__((aligned(16))) unsigned short plb[64][104];   // masked P, [token][band k]
    __shared__ __attribute__((aligned(16))) unsigned short qkgb[64][40];   // [token][anchor k], k<32
    __shared__ __attribute__((aligned(16))) unsigned short aoutT[64][40];  // [e][anchor k], k<32
    __shared__ float nrm[4][3][16];  // per-wave reciprocal weights: wl/nl, wg/ng, ws/ns
    int bh = blockIdx.x >> 5, stile = blockIdx.x & 31;
    int b = bh / H_, h = bh % H_;
    int s0 = stile * 64;
    int tid = threadIdx.x, lane = tid & 63, wave = tid >> 6;
    int quad = lane >> 4, l15 = lane & 15;
    const unsigned short* qfp = qfb + (size_t)bh * S_ * HD;
    const unsigned short* kfp = kfb + (size_t)bh * S_ * HD;
    const float* vp = vv + (size_t)bh * S_ * HD;
    float a0 = wlp[0], a1 = wsp[0], a2 = wgp[0];
    float mx = fmaxf(a0, fmaxf(a1, a2));
    float ew0 = __expf(a0 - mx), ew1 = __expf(a1 - mx), ew2 = __expf(a2 - mx);
    float inv = 1.f / (ew0 + ew1 + ew2);
    float wl = ew0 * inv, wsb = ew1 * inv, wg = ew2 * inv;
    // ---- stage bf16 tiles (vector copies) ----
    {
        int r = tid >> 2, c = (tid & 3) * 16;
        *(short8*)&qftb[r][c] = *(const short8*)&qfp[(size_t)(s0 + r) * HD + c];
        *(short8*)&qftb[r][c + 8] = *(const short8*)&qfp[(size_t)(s0 + r) * HD + c + 8];
        const unsigned short* kp = kvsTb + (size_t)bh * 4096 + r * 64 + c;
        *(short8*)&kvsbT[r][c] = *(const short8*)&kp[0];
        *(short8*)&kvsbT[r][c + 8] = *(const short8*)&kp[8];
    }
    for (int row = tid >> 2; row < 80; row += 64) {
        int c = (tid & 3) * 16;
        int gs = s0 + row - 6;
        if (row < 75 && gs >= 0 && gs < S_) {
            *(short8*)&kftb[row][c] = *(const short8*)&kfp[(size_t)gs * HD + c];
            *(short8*)&kftb[row][c + 8] = *(const short8*)&kfp[(size_t)gs * HD + c + 8];
        } else {
            short8 ones = {0x3F80, 0x3F80, 0x3F80, 0x3F80, 0x3F80, 0x3F80, 0x3F80, 0x3F80};
            *(short8*)&kftb[row][c] = ones;
            *(short8*)&kftb[row][c + 8] = ones;
        }
    }
    for (int i = tid; i < 96 * 64; i += 256) {
        int k = i >> 6, e = i & 63;
        int gs = s0 + k - 6;
        float v_ = (k < 75 && gs >= 0 && gs < S_) ? vp[(size_t)gs * HD + e] : 0.f;
        vtbT[e][k] = f2bu(v_);  // transpose -> [e][band k]; rows k>=75 zero
    }
    if (tid < 192) {  // aqfb rows 0-11 from precomputed bf16
        int a = tid >> 4, c = (tid & 15) * 4;
        *(ushort4*)&aqfb[a][c] = *(const ushort4*)&aqfb_g[h * 768 + a * 64 + c];
    }
    if (tid < 64) aqfb[12][tid] = ksumsb[bh * 64 + tid];
    if (tid < 192) aqfb[13 + (tid >> 6)][tid & 63] = 0;
    for (int i = tid; i < 64 * 20; i += 256) {  // aoutT pad cols 12-31
        int e = i / 20, c = 12 + i - e * 20;
        aoutT[e][c] = 0;
    }
    for (int i = tid; i < 768; i += 256) {
        int e = i / 12, a = i - e * 12;
        aoutT[e][a] = aoutTb[(size_t)bh * 768 + i];
    }
    for (int i = tid; i < 1024; i += 256) {
        plb[i >> 4][80 + (i & 15)] = 0;   // K-pad cols 80..95
        qkgb[i >> 4][16 + (i & 15)] = 0;  // K-pad cols 16..31
    }
    __syncthreads();
    // ---- phase A: wave w computes P rows w*16..w*16+15 (wave-private) ----
#pragma unroll
    for (int tj = 0; tj < 5; tj++) {
        f32x4 c = {0.f, 0.f, 0.f, 0.f};
#pragma unroll
        for (int kk = 0; kk < 2; kk++) {
            short8 afr = *(short8*)&qftb[wave * 16 + l15][kk * 32 + quad * 8];
            short8 bfr = *(short8*)&kftb[tj * 16 + l15][kk * 32 + quad * 8];
            c = __builtin_amdgcn_mfma_f32_16x16x32_bf16(afr, bfr, c, 0, 0, 0);
        }
        int col = tj * 16 + l15;
#pragma unroll
        for (int rr = 0; rr < 4; rr++) {
            int tok = wave * 16 + quad * 4 + rr;
            int which = col - tok;
            plb[tok][col] = (which >= 0 && which < 12) ? f2bu(c[rr]) : (unsigned short)0;
        }
    }
    {
        f32x4 c = {0.f, 0.f, 0.f, 0.f};
#pragma unroll
        for (int kk = 0; kk < 2; kk++) {
            short8 afr = *(short8*)&qftb[wave * 16 + l15][kk * 32 + quad * 8];
            short8 bfr = *(short8*)&aqfb[l15][kk * 32 + quad * 8];
            c = __builtin_amdgcn_mfma_f32_16x16x32_bf16(afr, bfr, c, 0, 0, 0);
        }
#pragma unroll
        for (int rr = 0; rr < 4; rr++) qkgb[wave * 16 + quad * 4 + rr][l15] = f2bu(c[rr]);
    }
    // ---- per-wave norms -> reciprocal combine weights (lanes 0-15) ----
    if (lane < 16) {
        int t = wave * 16 + lane;
        float sl = 0.f;
#pragma unroll
        for (int j = 0; j < 12; j++) sl += bu2f(plb[t][t + j]);
        float sg = 0.f;
#pragma unroll
        for (int a = 0; a < 12; a++) sg += bu2f(qkgb[t][a]);
        nrm[wave][0][lane] = wl / fmaxf(sl, 1e-6f);
        nrm[wave][1][lane] = wg / fmaxf(sg, 1e-6f);
        nrm[wave][2][lane] = wsb / fmaxf(bu2f(qkgb[t][12]), 1e-6f);
    }
    // ---- phase B: fused MFMA for all three bands ----
#pragma unroll
    for (int j2 = 0; j2 < 4; j2++) {
        f32x4 cL = {0.f, 0.f, 0.f, 0.f};
        f32x4 cG = {0.f, 0.f, 0.f, 0.f};
        f32x4 cS = {0.f, 0.f, 0.f, 0.f};
#pragma unroll
        for (int kk = 0; kk < 3; kk++) {
            short8 afr = *(short8*)&plb[wave * 16 + l15][kk * 32 + quad * 8];
            short8 bfr = *(short8*)&vtbT[j2 * 16 + l15][kk * 32 + quad * 8];
            cL = __builtin_amdgcn_mfma_f32_16x16x32_bf16(afr, bfr, cL, 0, 0, 0);
        }
        {
            short8 afr = *(short8*)&qkgb[wave * 16 + l15][quad * 8];
            short8 bfr = *(short8*)&aoutT[j2 * 16 + l15][quad * 8];
            cG = __builtin_amdgcn_mfma_f32_16x16x32_bf16(afr, bfr, cG, 0, 0, 0);
        }
#pragma unroll
        for (int kk = 0; kk < 2; kk++) {
            short8 afr = *(short8*)&qftb[wave * 16 + l15][kk * 32 + quad * 8];
            short8 bfr = *(short8*)&kvsbT[j2 * 16 + l15][kk * 32 + quad * 8];
            cS = __builtin_amdgcn_mfma_f32_16x16x32_bf16(afr, bfr, cS, 0, 0, 0);
        }
        int e = j2 * 16 + l15;
#pragma unroll
        for (int rr = 0; rr < 4; rr++) {
            int tq = quad * 4 + rr;
            int tok = wave * 16 + tq;
            float res = cL[rr] * nrm[wave][0][tq] + cS[rr] * nrm[wave][2][tq] +
                        cG[rr] * nrm[wave][1][tq];
            attnb[((size_t)(b * S_ + s0 + tok)) * 768 + h * 64 + e] = f2bu(res);
        }
    }
}

// ---------------------------------------------------------------------------
// Kernel 4: out = attn(bf16) @ out_w.T, counted-vmcnt dbuf + XCD swizzle.
// ---------------------------------------------------------------------------
__global__ __launch_bounds__(256) void out_gemm_mfma(const unsigned short* __restrict__ attnb,
                                                     const unsigned short* __restrict__ wb,
                                                     float* __restrict__ out) {
    __shared__ __attribute__((aligned(16))) unsigned short As[2][128 * 32];
    __shared__ __attribute__((aligned(16))) unsigned short Bs[2][128 * 32];
    const int K = 768;
    int orig = blockIdx.x;
    int swz = (orig & 7) * 48 + (orig >> 3);
    int mt = swz / 6, nt = swz - mt * 6;
    int n0 = nt * 128, m0 = mt * 128;
    int tid = threadIdx.x, lane = tid & 63, wave = tid >> 6;
    int wm = (wave & 1) * 64, wn = (wave >> 1) * 64;
    int quad = lane >> 4, l15 = lane & 15;
    f32x4 acc[4][4];
#pragma unroll
    for (int i = 0; i < 4; i++)
#pragma unroll
        for (int j = 0; j < 4; j++) acc[i][j] = 0.f;

    const unsigned short* ga0 = attnb + (size_t)(m0 + (tid >> 2)) * K + (tid & 3) * 8;
    const unsigned short* ga1 = attnb + (size_t)(m0 + 64 + (tid >> 2)) * K + (tid & 3) * 8;
    const unsigned short* gb0 = wb + (size_t)(n0 + (tid >> 2)) * K + (tid & 3) * 8;
    const unsigned short* gb1 = wb + (size_t)(n0 + 64 + (tid >> 2)) * K + (tid & 3) * 8;

    auto stage = [&](int bufi, int kk) {
        gload16(ga0 + kk, &As[bufi][wave * 512]);
        gload16(ga1 + kk, &As[bufi][2048 + wave * 512]);
        gload16(gb0 + kk, &Bs[bufi][wave * 512]);
        gload16(gb1 + kk, &Bs[bufi][2048 + wave * 512]);
    };
    auto compute = [&](int bufi) {
        short8 af[4], bfr[4];
#pragma unroll
        for (int i = 0; i < 4; i++)
            af[i] = *(short8*)&As[bufi][(wm + i * 16 + l15) * 32 + quad * 8];
#pragma unroll
        for (int j = 0; j < 4; j++)
            bfr[j] = *(short8*)&Bs[bufi][(wn + j * 16 + l15) * 32 + quad * 8];
#pragma unroll
        for (int i = 0; i < 4; i++)
#pragma unroll
            for (int j = 0; j < 4; j++)
                acc[i][j] = __builtin_amdgcn_mfma_f32_16x16x32_bf16(af[i], bfr[j], acc[i][j], 0, 0, 0);
    };

    stage(0, 0);
    int buf = 0;
    for (int t = 0; t < 23; t++) {
        stage(buf ^ 1, (t + 1) * 32);
        asm volatile("s_waitcnt vmcnt(4)" ::: "memory");
        __builtin_amdgcn_s_barrier();
        __builtin_amdgcn_sched_barrier(0);
        compute(buf);
        asm volatile("" ::: "memory");
        __builtin_amdgcn_s_barrier();
        buf ^= 1;
    }
    asm volatile("s_waitcnt vmcnt(0)" ::: "memory");
    __builtin_amdgcn_s_barrier();
    __builtin_amdgcn_sched_barrier(0);
    compute(buf);

#pragma unroll
    for (int j = 0; j < 4; j++) {
        int col = n0 + wn + j * 16 + l15;
#pragma unroll
        for (int i = 0; i < 4; i++) {
#pragma unroll
            for (int rr = 0; rr < 4; rr++) {
                int m = m0 + wm + i * 16 + quad * 4 + rr;
                out[(size_t)m * 768 + col] = acc[i][j][rr];
            }
        }
    }
}

extern "C" void kernel_launch(void* const* d_in, const int* in_sizes, int n_in,
                              void* d_out, int out_size, void* d_ws, size_t ws_size,
                              hipStream_t stream) {
    const float* x = (const float*)d_in[0];
    const float* qkvw = (const float*)d_in[1];
    const float* outw = (const float*)d_in[2];
    const float* aq = (const float*)d_in[3];
    const float* wlp = (const float*)d_in[4];
    const float* wsp = (const float*)d_in[5];
    const float* wgp = (const float*)d_in[6];

    float* ws = (float*)d_ws;
    const size_t NBH = (size_t)B_ * H_ * S_ * HD;  // 6,291,456
    // Region 0 [0, NBH): bf16 qfb (NBH ushorts) + bf16 kfb (NBH ushorts)
    unsigned short* qfb = (unsigned short*)ws;
    unsigned short* kfb = (unsigned short*)(ws + NBH / 2);
    float* kf = ws + NBH;                 // fp32 k (band_partial)
    float* vv = ws + 2 * NBH;             // fp32 v
    float* attn_region = ws + 3 * NBH;    // NBH floats; multi-use scratch
    //  [0, 3145728)  xb (bf16 x)      : convert .. qkv_gemm
    //  [3145728, 4030464) wb (bf16 qkv_w): convert .. qkv_gemm
    //  [0, NBH)      pkv              : band_partial .. band_reduce
    //  [0, 3145728)  attnb (bf16 attn): combine .. out_gemm
    unsigned short* xb = (unsigned short*)attn_region;
    unsigned short* wb = (unsigned short*)(attn_region + 3145728);
    float* pkv = attn_region;
    unsigned short* attnb = (unsigned short*)attn_region;
    // Post-region small buffers (all bf16 except pks):
    unsigned short* kvsTb = (unsigned short*)(attn_region + NBH);   // 48*4096
    unsigned short* ksumsb = kvsTb + 48 * 4096;                     // 48*64
    unsigned short* aoutTb = ksumsb + 48 * 64;                      // 48*768
    unsigned short* aqfb_g = aoutTb + 48 * 768;                     // 9216
    // total ushorts above = 196608+3072+36864+9216 = 245760 -> 122880 floats
    float* pks = attn_region + NBH + 122880;                        // 768*128 floats
    unsigned short* outwb = (unsigned short*)(pks + 768 * 128);

    convert_bf16<<<6144, 256, 0, stream>>>(x, xb, 6291456);
    convert_bf16<<<1728, 256, 0, stream>>>(qkvw, wb, 1769472);
    convert_bf16<<<576, 256, 0, stream>>>(outw, outwb, 589824);
    prep_aqf<<<36, 256, 0, stream>>>(aq, aqfb_g);
    qkv_gemm_mfma<<<1152, 256, 0, stream>>>(xb, wb, qfb, kf, kfb, vv);
    band_partial<<<48 * 16, 256, 0, stream>>>(kf, vv, pkv, pks);
    band_reduce<<<48 * 4, 256, 0, stream>>>(pkv, pks, aq, kvsTb, ksumsb, aoutTb);
    combine<<<48 * 32, 256, 0, stream>>>(qfb, kfb, vv, aqfb_g, kvsTb, ksumsb, aoutTb,
                                         wlp, wsp, wgp, attnb);
    out_gemm_mfma<<<384, 256, 0, stream>>>(attnb, outwb, (float*)d_out);
}

// Round 7
// 280.821 us; speedup vs baseline: 1.4652x; 1.0113x over previous
//
#include <hip/hip_runtime.h>
#include <hip/hip_bf16.h>

#define B_ 4
#define S_ 2048
#define D_ 768
#define H_ 12
#define HD 64

typedef __attribute__((ext_vector_type(8))) short short8;
typedef __attribute__((ext_vector_type(4))) float f32x4;

__device__ __forceinline__ float fmapf(float x) { return x > 0.f ? x + 1.f : __expf(x); }

// fp32 -> bf16 round-to-nearest-even (finite inputs only)
__device__ __forceinline__ unsigned short f2bu(float f) {
    unsigned u = __float_as_uint(f);
    u += 0x7FFFu + ((u >> 16) & 1u);
    return (unsigned short)(u >> 16);
}
__device__ __forceinline__ float bu2f(unsigned short v) {
    return __uint_as_float((unsigned)v << 16);
}

// async global->LDS direct copy, 16B per lane. lds ptr must be wave-uniform;
// HW writes lane l to ldsbase + l*16 (m97 pattern: linear LDS dest).
__device__ __forceinline__ void gload16(const void* g, void* l) {
    __builtin_amdgcn_global_load_lds((__attribute__((address_space(1))) void*)(size_t)g,
                                     (__attribute__((address_space(3))) void*)l, 16, 0, 0);
}

union u16x8 {
    uint4 u;
    short8 s;
};

// ---------------------------------------------------------------------------
// Kernel 0: fp32 -> bf16 bulk convert (n % 4 == 0).
// ---------------------------------------------------------------------------
__global__ __launch_bounds__(256) void convert_bf16(const float* __restrict__ src,
                                                    unsigned short* __restrict__ dst,
                                                    int n) {
    int i = (blockIdx.x * 256 + threadIdx.x) * 4;
    if (i < n) {
        float4 v = *(const float4*)&src[i];
        ushort4 o;
        o.x = f2bu(v.x); o.y = f2bu(v.y); o.z = f2bu(v.z); o.w = f2bu(v.w);
        *(ushort4*)&dst[i] = o;
    }
}

// ---------------------------------------------------------------------------
// Kernel 0b: precompute fmap(anchor_q) as bf16 (9216 elems).
// ---------------------------------------------------------------------------
__global__ __launch_bounds__(256) void prep_aqf(const float* __restrict__ aq,
                                                unsigned short* __restrict__ aqfb_g) {
    int i = blockIdx.x * 256 + threadIdx.x;
    if (i < 9216) aqfb_g[i] = f2bu(fmapf(aq[i]));
}

// ---------------------------------------------------------------------------
// Kernel 1: qkv = x @ qkv_w.T via bf16 MFMA. dbuf + XCD swizzle + counted
// vmcnt (unchanged from round 6).
// ---------------------------------------------------------------------------
__global__ __launch_bounds__(256) void qkv_gemm_mfma(const unsigned short* __restrict__ xb,
                                                     const unsigned short* __restrict__ wb,
                                                     unsigned short* __restrict__ qfb,
                                                     float* __restrict__ kf,
                                                     unsigned short* __restrict__ kfb,
                                                     float* __restrict__ vv) {
    __shared__ __attribute__((aligned(16))) unsigned short As[2][128 * 32];
    __shared__ __attribute__((aligned(16))) unsigned short Bs[2][128 * 32];
    const int K = 768;
    int orig = blockIdx.x;
    int swz = (orig & 7) * 144 + (orig >> 3);
    int mt = swz / 18, nt = swz - mt * 18;
    int n0 = nt * 128, m0 = mt * 128;
    int tid = threadIdx.x, lane = tid & 63, wave = tid >> 6;
    int wm = (wave & 1) * 64, wn = (wave >> 1) * 64;
    int quad = lane >> 4, l15 = lane & 15;
    f32x4 acc[4][4];
#pragma unroll
    for (int i = 0; i < 4; i++)
#pragma unroll
        for (int j = 0; j < 4; j++) acc[i][j] = 0.f;

    const unsigned short* ga0 = xb + (size_t)(m0 + (tid >> 2)) * K + (tid & 3) * 8;
    const unsigned short* ga1 = xb + (size_t)(m0 + 64 + (tid >> 2)) * K + (tid & 3) * 8;
    const unsigned short* gb0 = wb + (size_t)(n0 + (tid >> 2)) * K + (tid & 3) * 8;
    const unsigned short* gb1 = wb + (size_t)(n0 + 64 + (tid >> 2)) * K + (tid & 3) * 8;

    auto stage = [&](int bufi, int kk) {
        gload16(ga0 + kk, &As[bufi][wave * 512]);
        gload16(ga1 + kk, &As[bufi][2048 + wave * 512]);
        gload16(gb0 + kk, &Bs[bufi][wave * 512]);
        gload16(gb1 + kk, &Bs[bufi][2048 + wave * 512]);
    };
    auto compute = [&](int bufi) {
        short8 af[4], bfr[4];
#pragma unroll
        for (int i = 0; i < 4; i++)
            af[i] = *(short8*)&As[bufi][(wm + i * 16 + l15) * 32 + quad * 8];
#pragma unroll
        for (int j = 0; j < 4; j++)
            bfr[j] = *(short8*)&Bs[bufi][(wn + j * 16 + l15) * 32 + quad * 8];
#pragma unroll
        for (int i = 0; i < 4; i++)
#pragma unroll
            for (int j = 0; j < 4; j++)
                acc[i][j] = __builtin_amdgcn_mfma_f32_16x16x32_bf16(af[i], bfr[j], acc[i][j], 0, 0, 0);
    };

    stage(0, 0);
    int buf = 0;
    for (int t = 0; t < 23; t++) {
        stage(buf ^ 1, (t + 1) * 32);
        asm volatile("s_waitcnt vmcnt(4)" ::: "memory");
        __builtin_amdgcn_s_barrier();
        __builtin_amdgcn_sched_barrier(0);
        compute(buf);
        asm volatile("" ::: "memory");
        __builtin_amdgcn_s_barrier();
        buf ^= 1;
    }
    asm volatile("s_waitcnt vmcnt(0)" ::: "memory");
    __builtin_amdgcn_s_barrier();
    __builtin_amdgcn_sched_barrier(0);
    compute(buf);

#pragma unroll
    for (int j = 0; j < 4; j++) {
        int col = n0 + wn + j * 16 + l15;
        int t3 = col / 768;
        int r = col - t3 * 768;
        int h = r >> 6, d = r & 63;
#pragma unroll
        for (int i = 0; i < 4; i++) {
#pragma unroll
            for (int rr = 0; rr < 4; rr++) {
                int m = m0 + wm + i * 16 + quad * 4 + rr;
                int b = m >> 11, s = m & 2047;
                size_t dst = (((size_t)(b * H_ + h) * S_) + s) * HD + d;
                float val = acc[i][j][rr];
                if (t3 == 0) {
                    qfb[dst] = f2bu(fmapf(val));
                } else if (t3 == 1) {
                    float fv = fmapf(val);
                    kf[dst] = fv;
                    kfb[dst] = f2bu(fv);
                } else {
                    vv[dst] = val;
                }
            }
        }
    }
}

// ---------------------------------------------------------------------------
// Kernel 2a: partial kv states. Grid = 48 bh * 16 chunks (128 tokens each).
// ---------------------------------------------------------------------------
__global__ __launch_bounds__(256) void band_partial(const float* __restrict__ kf,
                                                    const float* __restrict__ vv,
                                                    float* __restrict__ pkv,
                                                    float* __restrict__ pks) {
    int bh = blockIdx.x >> 4, chunk = blockIdx.x & 15;
    int sbase = chunk * 128;
    const float* kfp = kf + (size_t)bh * S_ * HD + (size_t)sbase * HD;
    const float* vp = vv + (size_t)bh * S_ * HD + (size_t)sbase * HD;
    __shared__ float kt[16][64];
    __shared__ float vt[16][64];
    int tid = threadIdx.x;
    int d = tid >> 2, eg = tid & 3, e0 = eg * 16;
    int srow = tid >> 4, scol = (tid & 15) * 4;
    float accg[16], accs[16];
#pragma unroll
    for (int i = 0; i < 16; i++) { accg[i] = 0.f; accs[i] = 0.f; }
    float ksg = 0.f, kss = 0.f;
    for (int s0 = 0; s0 < 128; s0 += 16) {
        *(float4*)&kt[srow][scol] = *(const float4*)&kfp[(size_t)(s0 + srow) * HD + scol];
        *(float4*)&vt[srow][scol] = *(const float4*)&vp[(size_t)(s0 + srow) * HD + scol];
        __syncthreads();
        int m3 = (sbase + s0) % 3;  // block-uniform stride phase
#pragma unroll
        for (int ss = 0; ss < 16; ss++) {
            float kd = kt[ss][d];
            bool str = ((m3 + ss) % 3) == 0;
            ksg += kd;
            float4 v0 = *(float4*)&vt[ss][e0];
            float4 v1 = *(float4*)&vt[ss][e0 + 4];
            float4 v2 = *(float4*)&vt[ss][e0 + 8];
            float4 v3 = *(float4*)&vt[ss][e0 + 12];
            accg[0] += kd * v0.x;  accg[1] += kd * v0.y;
            accg[2] += kd * v0.z;  accg[3] += kd * v0.w;
            accg[4] += kd * v1.x;  accg[5] += kd * v1.y;
            accg[6] += kd * v1.z;  accg[7] += kd * v1.w;
            accg[8] += kd * v2.x;  accg[9] += kd * v2.y;
            accg[10] += kd * v2.z; accg[11] += kd * v2.w;
            accg[12] += kd * v3.x; accg[13] += kd * v3.y;
            accg[14] += kd * v3.z; accg[15] += kd * v3.w;
            if (str) {
                kss += kd;
                accs[0] += kd * v0.x;  accs[1] += kd * v0.y;
                accs[2] += kd * v0.z;  accs[3] += kd * v0.w;
                accs[4] += kd * v1.x;  accs[5] += kd * v1.y;
                accs[6] += kd * v1.z;  accs[7] += kd * v1.w;
                accs[8] += kd * v2.x;  accs[9] += kd * v2.y;
                accs[10] += kd * v2.z; accs[11] += kd * v2.w;
                accs[12] += kd * v3.x; accs[13] += kd * v3.y;
                accs[14] += kd * v3.z; accs[15] += kd * v3.w;
            }
        }
        __syncthreads();
    }
    float* pg = pkv + (size_t)blockIdx.x * 2 * 4096;
#pragma unroll
    for (int i = 0; i < 16; i++) pg[d * 64 + e0 + i] = accg[i];
#pragma unroll
    for (int i = 0; i < 16; i++) pg[4096 + d * 64 + e0 + i] = accs[i];
    if (eg == 0) {
        pks[blockIdx.x * 128 + d] = ksg;
        pks[blockIdx.x * 128 + 64 + d] = kss;
    }
}

// ---------------------------------------------------------------------------
// Kernel 2b: reduce partials + anchor outputs. Grid = 48 bh * 4 e-blocks.
// ---------------------------------------------------------------------------
__global__ __launch_bounds__(256) void band_reduce(const float* __restrict__ pkv,
                                                   const float* __restrict__ pks,
                                                   const float* __restrict__ aq,
                                                   unsigned short* __restrict__ kvsTb,
                                                   unsigned short* __restrict__ ksumsb,
                                                   unsigned short* __restrict__ aoutTb) {
    int bh = blockIdx.x >> 2, eb = blockIdx.x & 3, e0 = eb * 16;
    int h = bh % H_;
    __shared__ float kvgL[64][17];
    __shared__ float ksgL[64];
    __shared__ float anorm[12];
    int tid = threadIdx.x;
    for (int idx = tid; idx < 1024; idx += 256) {
        int d = idx >> 4, j = idx & 15;
        float sg = 0.f, ss = 0.f;
        const float* p = pkv + (size_t)(bh * 16) * 2 * 4096 + d * 64 + e0 + j;
#pragma unroll 4
        for (int c = 0; c < 16; c++) {
            sg += p[0];
            ss += p[4096];
            p += 2 * 4096;
        }
        kvgL[d][j] = sg;
        kvsTb[(size_t)bh * 4096 + (e0 + j) * 64 + d] = f2bu(ss);
    }
    if (tid < 64) {
        float sg = 0.f, ss = 0.f;
#pragma unroll 4
        for (int c = 0; c < 16; c++) {
            sg += pks[(bh * 16 + c) * 128 + tid];
            ss += pks[(bh * 16 + c) * 128 + 64 + tid];
        }
        ksgL[tid] = sg;
        if (eb == 0) ksumsb[bh * 64 + tid] = f2bu(ss);
    }
    __syncthreads();
    if (tid < 12) {
        float nrm = 0.f;
        for (int dd = 0; dd < 64; dd++)
            nrm += fmapf(aq[h * 768 + tid * 64 + dd]) * ksgL[dd];
        anorm[tid] = fmaxf(nrm, 1e-6f);
    }
    __syncthreads();
    if (tid < 192) {
        int a = tid >> 4, j = tid & 15;
        float acc = 0.f;
        for (int dd = 0; dd < 64; dd++)
            acc += fmapf(aq[h * 768 + a * 64 + dd]) * kvgL[dd][j];
        aoutTb[(size_t)bh * 768 + (e0 + j) * 12 + a] = f2bu(acc / anorm[a]);
    }
}

// ---------------------------------------------------------------------------
// Kernel 3: combine v2 — register-direct MFMA fragments.
// qftb/kftb/kvsbT/aoutT LDS tiles removed: those operands' fragments are
// per-lane rows loaded straight from global (q: 2 uint4 reused for all
// tiles; k-band: clamped uint4 + select-to-1.0 for OOB = old padding;
// kvsT/aout: direct). LDS keeps only plb/qkgb (P round-trip), vtbT
// (transpose), aqfb, nrm -> 34.8 KB (was ~70). Bit-identical numerics.
// ---------------------------------------------------------------------------
__global__ __launch_bounds__(256) void combine(const unsigned short* __restrict__ qfb,
                                               const unsigned short* __restrict__ kfb,
                                               const float* __restrict__ vv,
                                               const unsigned short* __restrict__ aqfb_g,
                                               const unsigned short* __restrict__ kvsTb,
                                               const unsigned short* __restrict__ ksumsb,
                                               const unsigned short* __restrict__ aoutTb,
                                               const float* __restrict__ wlp,
                                               const float* __restrict__ wsp,
                                               const float* __restrict__ wgp,
                                               unsigned short* __restrict__ attnb) {
    __shared__ __attribute__((aligned(16))) unsigned short aqfb[16][72];   // anchors + ksum
    __shared__ __attribute__((aligned(16))) unsigned short vtbT[64][104];  // [e][band k], k<96
    __shared__ __attribute__((aligned(16))) unsigned short plb[64][104];   // masked P
    __shared__ __attribute__((aligned(16))) unsigned short qkgb[64][40];   // [token][anchor k]
    __shared__ float nrm[4][3][16];
    int bh = blockIdx.x >> 5, stile = blockIdx.x & 31;
    int b = bh / H_, h = bh % H_;
    int s0 = stile * 64;
    int tid = threadIdx.x, lane = tid & 63, wave = tid >> 6;
    int quad = lane >> 4, l15 = lane & 15;
    const unsigned short* qfp = qfb + (size_t)bh * S_ * HD;
    const unsigned short* kfp = kfb + (size_t)bh * S_ * HD;
    const float* vp = vv + (size_t)bh * S_ * HD;
    float a0 = wlp[0], a1 = wsp[0], a2 = wgp[0];
    float mx = fmaxf(a0, fmaxf(a1, a2));
    float ew0 = __expf(a0 - mx), ew1 = __expf(a1 - mx), ew2 = __expf(a2 - mx);
    float inv = 1.f / (ew0 + ew1 + ew2);
    float wl = ew0 * inv, wsb = ew1 * inv, wg = ew2 * inv;
    // ---- stage: vtbT (fp32 v transpose), aqfb, K-pads ----
    for (int i = tid; i < 96 * 64; i += 256) {
        int k = i >> 6, e = i & 63;
        int gs = s0 + k - 6;
        float v_ = (k < 75 && gs >= 0 && gs < S_) ? vp[(size_t)gs * HD + e] : 0.f;
        vtbT[e][k] = f2bu(v_);
    }
    if (tid < 192) {
        int a = tid >> 4, c = (tid & 15) * 4;
        *(ushort4*)&aqfb[a][c] = *(const ushort4*)&aqfb_g[h * 768 + a * 64 + c];
    }
    if (tid < 64) aqfb[12][tid] = ksumsb[bh * 64 + tid];
    if (tid < 192) aqfb[13 + (tid >> 6)][tid & 63] = 0;
    for (int i = tid; i < 1024; i += 256) {
        plb[i >> 4][80 + (i & 15)] = 0;   // K-pad cols 80..95
        qkgb[i >> 4][16 + (i & 15)] = 0;  // K-pad cols 16..31
    }
    __syncthreads();
    // ---- q A-fragments: per-thread rows, loaded once, reused everywhere ----
    u16x8 qa0, qa1;
    {
        const unsigned short* qr = qfp + (size_t)(s0 + wave * 16 + l15) * HD + quad * 8;
        qa0.u = *(const uint4*)qr;
        qa1.u = *(const uint4*)(qr + 32);
    }
    // ---- phase A: wave w computes P rows w*16..w*16+15 (wave-private) ----
#pragma unroll
    for (int tj = 0; tj < 5; tj++) {
        int row = tj * 16 + l15;
        int gs = s0 + row - 6;
        bool valid = (row < 75) && (gs >= 0) && (gs < S_);
        int gsc = gs < 0 ? 0 : (gs > S_ - 1 ? S_ - 1 : gs);
        const unsigned short* kr = kfp + (size_t)gsc * HD + quad * 8;
        u16x8 b0, b1, ones;
        ones.u = make_uint4(0x3F803F80u, 0x3F803F80u, 0x3F803F80u, 0x3F803F80u);
        b0.u = *(const uint4*)kr;
        b1.u = *(const uint4*)(kr + 32);
        if (!valid) { b0 = ones; b1 = ones; }
        f32x4 c = {0.f, 0.f, 0.f, 0.f};
        c = __builtin_amdgcn_mfma_f32_16x16x32_bf16(qa0.s, b0.s, c, 0, 0, 0);
        c = __builtin_amdgcn_mfma_f32_16x16x32_bf16(qa1.s, b1.s, c, 0, 0, 0);
        int col = tj * 16 + l15;
#pragma unroll
        for (int rr = 0; rr < 4; rr++) {
            int tok = wave * 16 + quad * 4 + rr;
            int which = col - tok;
            plb[tok][col] = (which >= 0 && which < 12) ? f2bu(c[rr]) : (unsigned short)0;
        }
    }
    {
        f32x4 c = {0.f, 0.f, 0.f, 0.f};
        short8 bfr0 = *(short8*)&aqfb[l15][quad * 8];
        short8 bfr1 = *(short8*)&aqfb[l15][32 + quad * 8];
        c = __builtin_amdgcn_mfma_f32_16x16x32_bf16(qa0.s, bfr0, c, 0, 0, 0);
        c = __builtin_amdgcn_mfma_f32_16x16x32_bf16(qa1.s, bfr1, c, 0, 0, 0);
#pragma unroll
        for (int rr = 0; rr < 4; rr++) qkgb[wave * 16 + quad * 4 + rr][l15] = f2bu(c[rr]);
    }
    // ---- per-wave norms -> reciprocal combine weights (lanes 0-15) ----
    if (lane < 16) {
        int t = wave * 16 + lane;
        float sl = 0.f;
#pragma unroll
        for (int j = 0; j < 12; j++) sl += bu2f(plb[t][t + j]);
        float sg = 0.f;
#pragma unroll
        for (int a = 0; a < 12; a++) sg += bu2f(qkgb[t][a]);
        nrm[wave][0][lane] = wl / fmaxf(sl, 1e-6f);
        nrm[wave][1][lane] = wg / fmaxf(sg, 1e-6f);
        nrm[wave][2][lane] = wsb / fmaxf(bu2f(qkgb[t][12]), 1e-6f);
    }
    // ---- phase B: fused MFMA; B-frags for stride/global bands direct ----
#pragma unroll
    for (int j2 = 0; j2 < 4; j2++) {
        int e = j2 * 16 + l15;
        f32x4 cL = {0.f, 0.f, 0.f, 0.f};
        f32x4 cG = {0.f, 0.f, 0.f, 0.f};
        f32x4 cS = {0.f, 0.f, 0.f, 0.f};
#pragma unroll
        for (int kk = 0; kk < 3; kk++) {
            short8 afr = *(short8*)&plb[wave * 16 + l15][kk * 32 + quad * 8];
            short8 bfr = *(short8*)&vtbT[e][kk * 32 + quad * 8];
            cL = __builtin_amdgcn_mfma_f32_16x16x32_bf16(afr, bfr, cL, 0, 0, 0);
        }
        {
            short8 afr = *(short8*)&qkgb[wave * 16 + l15][quad * 8];
            u16x8 bo;
            bo.u = make_uint4(0u, 0u, 0u, 0u);
            const unsigned* ap = (const unsigned*)(aoutTb + (size_t)bh * 768 + e * 12);
            if (quad == 0) {
                bo.u.x = ap[0]; bo.u.y = ap[1]; bo.u.z = ap[2]; bo.u.w = ap[3];
            } else if (quad == 1) {
                bo.u.x = ap[4]; bo.u.y = ap[5];
            }
            cG = __builtin_amdgcn_mfma_f32_16x16x32_bf16(afr, bo.s, cG, 0, 0, 0);
        }
        {
            const unsigned short* kvp = kvsTb + (size_t)bh * 4096 + e * 64 + quad * 8;
            u16x8 bk0, bk1;
            bk0.u = *(const uint4*)kvp;
            bk1.u = *(const uint4*)(kvp + 32);
            cS = __builtin_amdgcn_mfma_f32_16x16x32_bf16(qa0.s, bk0.s, cS, 0, 0, 0);
            cS = __builtin_amdgcn_mfma_f32_16x16x32_bf16(qa1.s, bk1.s, cS, 0, 0, 0);
        }
#pragma unroll
        for (int rr = 0; rr < 4; rr++) {
            int tq = quad * 4 + rr;
            int tok = wave * 16 + tq;
            float res = cL[rr] * nrm[wave][0][tq] + cS[rr] * nrm[wave][2][tq] +
                        cG[rr] * nrm[wave][1][tq];
            attnb[((size_t)(b * S_ + s0 + tok)) * 768 + h * 64 + e] = f2bu(res);
        }
    }
}

// ---------------------------------------------------------------------------
// Kernel 4: out = attn(bf16) @ out_w.T, counted-vmcnt dbuf + XCD swizzle.
// ---------------------------------------------------------------------------
__global__ __launch_bounds__(256) void out_gemm_mfma(const unsigned short* __restrict__ attnb,
                                                     const unsigned short* __restrict__ wb,
                                                     float* __restrict__ out) {
    __shared__ __attribute__((aligned(16))) unsigned short As[2][128 * 32];
    __shared__ __attribute__((aligned(16))) unsigned short Bs[2][128 * 32];
    const int K = 768;
    int orig = blockIdx.x;
    int swz = (orig & 7) * 48 + (orig >> 3);
    int mt = swz / 6, nt = swz - mt * 6;
    int n0 = nt * 128, m0 = mt * 128;
    int tid = threadIdx.x, lane = tid & 63, wave = tid >> 6;
    int wm = (wave & 1) * 64, wn = (wave >> 1) * 64;
    int quad = lane >> 4, l15 = lane & 15;
    f32x4 acc[4][4];
#pragma unroll
    for (int i = 0; i < 4; i++)
#pragma unroll
        for (int j = 0; j < 4; j++) acc[i][j] = 0.f;

    const unsigned short* ga0 = attnb + (size_t)(m0 + (tid >> 2)) * K + (tid & 3) * 8;
    const unsigned short* ga1 = attnb + (size_t)(m0 + 64 + (tid >> 2)) * K + (tid & 3) * 8;
    const unsigned short* gb0 = wb + (size_t)(n0 + (tid >> 2)) * K + (tid & 3) * 8;
    const unsigned short* gb1 = wb + (size_t)(n0 + 64 + (tid >> 2)) * K + (tid & 3) * 8;

    auto stage = [&](int bufi, int kk) {
        gload16(ga0 + kk, &As[bufi][wave * 512]);
        gload16(ga1 + kk, &As[bufi][2048 + wave * 512]);
        gload16(gb0 + kk, &Bs[bufi][wave * 512]);
        gload16(gb1 + kk, &Bs[bufi][2048 + wave * 512]);
    };
    auto compute = [&](int bufi) {
        short8 af[4], bfr[4];
#pragma unroll
        for (int i = 0; i < 4; i++)
            af[i] = *(short8*)&As[bufi][(wm + i * 16 + l15) * 32 + quad * 8];
#pragma unroll
        for (int j = 0; j < 4; j++)
            bfr[j] = *(short8*)&Bs[bufi][(wn + j * 16 + l15) * 32 + quad * 8];
#pragma unroll
        for (int i = 0; i < 4; i++)
#pragma unroll
            for (int j = 0; j < 4; j++)
                acc[i][j] = __builtin_amdgcn_mfma_f32_16x16x32_bf16(af[i], bfr[j], acc[i][j], 0, 0, 0);
    };

    stage(0, 0);
    int buf = 0;
    for (int t = 0; t < 23; t++) {
        stage(buf ^ 1, (t + 1) * 32);
        asm volatile("s_waitcnt vmcnt(4)" ::: "memory");
        __builtin_amdgcn_s_barrier();
        __builtin_amdgcn_sched_barrier(0);
        compute(buf);
        asm volatile("" ::: "memory");
        __builtin_amdgcn_s_barrier();
        buf ^= 1;
    }
    asm volatile("s_waitcnt vmcnt(0)" ::: "memory");
    __builtin_amdgcn_s_barrier();
    __builtin_amdgcn_sched_barrier(0);
    compute(buf);

#pragma unroll
    for (int j = 0; j < 4; j++) {
        int col = n0 + wn + j * 16 + l15;
#pragma unroll
        for (int i = 0; i < 4; i++) {
#pragma unroll
            for (int rr = 0; rr < 4; rr++) {
                int m = m0 + wm + i * 16 + quad * 4 + rr;
                out[(size_t)m * 768 + col] = acc[i][j][rr];
            }
        }
    }
}

extern "C" void kernel_launch(void* const* d_in, const int* in_sizes, int n_in,
                              void* d_out, int out_size, void* d_ws, size_t ws_size,
                              hipStream_t stream) {
    const float* x = (const float*)d_in[0];
    const float* qkvw = (const float*)d_in[1];
    const float* outw = (const float*)d_in[2];
    const float* aq = (const float*)d_in[3];
    const float* wlp = (const float*)d_in[4];
    const float* wsp = (const float*)d_in[5];
    const float* wgp = (const float*)d_in[6];

    float* ws = (float*)d_ws;
    const size_t NBH = (size_t)B_ * H_ * S_ * HD;  // 6,291,456
    unsigned short* qfb = (unsigned short*)ws;
    unsigned short* kfb = (unsigned short*)(ws + NBH / 2);
    float* kf = ws + NBH;
    float* vv = ws + 2 * NBH;
    float* attn_region = ws + 3 * NBH;
    unsigned short* xb = (unsigned short*)attn_region;
    unsigned short* wb = (unsigned short*)(attn_region + 3145728);
    float* pkv = attn_region;
    unsigned short* attnb = (unsigned short*)attn_region;
    unsigned short* kvsTb = (unsigned short*)(attn_region + NBH);   // 48*4096
    unsigned short* ksumsb = kvsTb + 48 * 4096;                     // 48*64
    unsigned short* aoutTb = ksumsb + 48 * 64;                      // 48*768
    unsigned short* aqfb_g = aoutTb + 48 * 768;                     // 9216
    float* pks = attn_region + NBH + 122880;                        // 768*128 floats
    unsigned short* outwb = (unsigned short*)(pks + 768 * 128);

    convert_bf16<<<6144, 256, 0, stream>>>(x, xb, 6291456);
    convert_bf16<<<1728, 256, 0, stream>>>(qkvw, wb, 1769472);
    convert_bf16<<<576, 256, 0, stream>>>(outw, outwb, 589824);
    prep_aqf<<<36, 256, 0, stream>>>(aq, aqfb_g);
    qkv_gemm_mfma<<<1152, 256, 0, stream>>>(xb, wb, qfb, kf, kfb, vv);
    band_partial<<<48 * 16, 256, 0, stream>>>(kf, vv, pkv, pks);
    band_reduce<<<48 * 4, 256, 0, stream>>>(pkv, pks, aq, kvsTb, ksumsb, aoutTb);
    combine<<<48 * 32, 256, 0, stream>>>(qfb, kfb, vv, aqfb_g, kvsTb, ksumsb, aoutTb,
                                         wlp, wsp, wgp, attnb);
    out_gemm_mfma<<<384, 256, 0, stream>>>(attnb, outwb, (float*)d_out);
}

// Round 8
// 272.489 us; speedup vs baseline: 1.5101x; 1.0306x over previous
//
#include <hip/hip_runtime.h>
#include <hip/hip_bf16.h>

#define B_ 4
#define S_ 2048
#define D_ 768
#define H_ 12
#define HD 64

typedef __attribute__((ext_vector_type(8))) short short8;
typedef __attribute__((ext_vector_type(4))) float f32x4;

__device__ __forceinline__ float fmapf(float x) { return x > 0.f ? x + 1.f : __expf(x); }

// fp32 -> bf16 round-to-nearest-even (finite inputs only)
__device__ __forceinline__ unsigned short f2bu(float f) {
    unsigned u = __float_as_uint(f);
    u += 0x7FFFu + ((u >> 16) & 1u);
    return (unsigned short)(u >> 16);
}
__device__ __forceinline__ float bu2f(unsigned short v) {
    return __uint_as_float((unsigned)v << 16);
}

// async global->LDS direct copy, 16B per lane. lds ptr must be wave-uniform;
// HW writes lane l to ldsbase + l*16 (m97 pattern: linear LDS dest).
__device__ __forceinline__ void gload16(const void* g, void* l) {
    __builtin_amdgcn_global_load_lds((__attribute__((address_space(1))) void*)(size_t)g,
                                     (__attribute__((address_space(3))) void*)l, 16, 0, 0);
}

union u16x8 {
    uint4 u;
    short8 s;
};

// ---------------------------------------------------------------------------
// Kernel 0: fused fp32->bf16 converts for x, qkv_w, out_w + fmap(anchor_q).
// float4 ranges: x 1572864, qkvw 442368, outw 147456; then 9216 scalar aq.
// Grid = 8484 blocks x 256 (= 2171904 threads exactly).
// ---------------------------------------------------------------------------
__global__ __launch_bounds__(256) void convert_all(const float* __restrict__ x,
                                                   const float* __restrict__ qkvw,
                                                   const float* __restrict__ outw,
                                                   const float* __restrict__ aq,
                                                   unsigned short* __restrict__ xb,
                                                   unsigned short* __restrict__ wb,
                                                   unsigned short* __restrict__ outwb,
                                                   unsigned short* __restrict__ aqfb_g) {
    int gid = blockIdx.x * 256 + threadIdx.x;
    const float* src;
    unsigned short* dst;
    int i4;
    if (gid < 1572864) {
        src = x; dst = xb; i4 = gid;
    } else if (gid < 1572864 + 442368) {
        src = qkvw; dst = wb; i4 = gid - 1572864;
    } else if (gid < 2162688) {
        src = outw; dst = outwb; i4 = gid - (1572864 + 442368);
    } else {
        int i = gid - 2162688;  // < 9216
        aqfb_g[i] = f2bu(fmapf(aq[i]));
        return;
    }
    float4 v = *(const float4*)&src[i4 * 4];
    ushort4 o;
    o.x = f2bu(v.x); o.y = f2bu(v.y); o.z = f2bu(v.z); o.w = f2bu(v.w);
    *(ushort4*)&dst[i4 * 4] = o;
}

// ---------------------------------------------------------------------------
// Kernel 1: qkv = x @ qkv_w.T via bf16 MFMA. dbuf + XCD swizzle + counted
// vmcnt (unchanged).
// ---------------------------------------------------------------------------
__global__ __launch_bounds__(256) void qkv_gemm_mfma(const unsigned short* __restrict__ xb,
                                                     const unsigned short* __restrict__ wb,
                                                     unsigned short* __restrict__ qfb,
                                                     float* __restrict__ kf,
                                                     unsigned short* __restrict__ kfb,
                                                     float* __restrict__ vv) {
    __shared__ __attribute__((aligned(16))) unsigned short As[2][128 * 32];
    __shared__ __attribute__((aligned(16))) unsigned short Bs[2][128 * 32];
    const int K = 768;
    int orig = blockIdx.x;
    int swz = (orig & 7) * 144 + (orig >> 3);
    int mt = swz / 18, nt = swz - mt * 18;
    int n0 = nt * 128, m0 = mt * 128;
    int tid = threadIdx.x, lane = tid & 63, wave = tid >> 6;
    int wm = (wave & 1) * 64, wn = (wave >> 1) * 64;
    int quad = lane >> 4, l15 = lane & 15;
    f32x4 acc[4][4];
#pragma unroll
    for (int i = 0; i < 4; i++)
#pragma unroll
        for (int j = 0; j < 4; j++) acc[i][j] = 0.f;

    const unsigned short* ga0 = xb + (size_t)(m0 + (tid >> 2)) * K + (tid & 3) * 8;
    const unsigned short* ga1 = xb + (size_t)(m0 + 64 + (tid >> 2)) * K + (tid & 3) * 8;
    const unsigned short* gb0 = wb + (size_t)(n0 + (tid >> 2)) * K + (tid & 3) * 8;
    const unsigned short* gb1 = wb + (size_t)(n0 + 64 + (tid >> 2)) * K + (tid & 3) * 8;

    auto stage = [&](int bufi, int kk) {
        gload16(ga0 + kk, &As[bufi][wave * 512]);
        gload16(ga1 + kk, &As[bufi][2048 + wave * 512]);
        gload16(gb0 + kk, &Bs[bufi][wave * 512]);
        gload16(gb1 + kk, &Bs[bufi][2048 + wave * 512]);
    };
    auto compute = [&](int bufi) {
        short8 af[4], bfr[4];
#pragma unroll
        for (int i = 0; i < 4; i++)
            af[i] = *(short8*)&As[bufi][(wm + i * 16 + l15) * 32 + quad * 8];
#pragma unroll
        for (int j = 0; j < 4; j++)
            bfr[j] = *(short8*)&Bs[bufi][(wn + j * 16 + l15) * 32 + quad * 8];
#pragma unroll
        for (int i = 0; i < 4; i++)
#pragma unroll
            for (int j = 0; j < 4; j++)
                acc[i][j] = __builtin_amdgcn_mfma_f32_16x16x32_bf16(af[i], bfr[j], acc[i][j], 0, 0, 0);
    };

    stage(0, 0);
    int buf = 0;
    for (int t = 0; t < 23; t++) {
        stage(buf ^ 1, (t + 1) * 32);
        asm volatile("s_waitcnt vmcnt(4)" ::: "memory");
        __builtin_amdgcn_s_barrier();
        __builtin_amdgcn_sched_barrier(0);
        compute(buf);
        asm volatile("" ::: "memory");
        __builtin_amdgcn_s_barrier();
        buf ^= 1;
    }
    asm volatile("s_waitcnt vmcnt(0)" ::: "memory");
    __builtin_amdgcn_s_barrier();
    __builtin_amdgcn_sched_barrier(0);
    compute(buf);

#pragma unroll
    for (int j = 0; j < 4; j++) {
        int col = n0 + wn + j * 16 + l15;
        int t3 = col / 768;
        int r = col - t3 * 768;
        int h = r >> 6, d = r & 63;
#pragma unroll
        for (int i = 0; i < 4; i++) {
#pragma unroll
            for (int rr = 0; rr < 4; rr++) {
                int m = m0 + wm + i * 16 + quad * 4 + rr;
                int b = m >> 11, s = m & 2047;
                size_t dst = (((size_t)(b * H_ + h) * S_) + s) * HD + d;
                float val = acc[i][j][rr];
                if (t3 == 0) {
                    qfb[dst] = f2bu(fmapf(val));
                } else if (t3 == 1) {
                    float fv = fmapf(val);
                    kf[dst] = fv;
                    kfb[dst] = f2bu(fv);
                } else {
                    vv[dst] = val;
                }
            }
        }
    }
}

// ---------------------------------------------------------------------------
// Kernel 2a: partial kv states v2 — pure streaming, NO LDS, NO barriers.
// Thread map: d = tid&63 (k-reads wave-coalesced), eg = tid>>6 (v-reads
// wave-uniform -> cache broadcast). Same accumulation order as before ->
// bit-identical results. Grid = 48 bh * 16 chunks (128 tokens each).
// ---------------------------------------------------------------------------
__global__ __launch_bounds__(256) void band_partial(const float* __restrict__ kf,
                                                    const float* __restrict__ vv,
                                                    float* __restrict__ pkv,
                                                    float* __restrict__ pks) {
    int bh = blockIdx.x >> 4, chunk = blockIdx.x & 15;
    int sbase = chunk * 128;
    const float* kfp = kf + (size_t)bh * S_ * HD + (size_t)sbase * HD;
    const float* vp = vv + (size_t)bh * S_ * HD + (size_t)sbase * HD;
    int tid = threadIdx.x;
    int d = tid & 63, eg = tid >> 6, e0 = eg * 16;
    float accg[16], accs[16];
#pragma unroll
    for (int i = 0; i < 16; i++) { accg[i] = 0.f; accs[i] = 0.f; }
    float ksg = 0.f, kss = 0.f;
#pragma unroll 4
    for (int s = 0; s < 128; s++) {
        float kd = kfp[(size_t)s * HD + d];
        bool str = ((sbase + s) % 3) == 0;
        ksg += kd;
        float4 v0 = *(const float4*)&vp[(size_t)s * HD + e0];
        float4 v1 = *(const float4*)&vp[(size_t)s * HD + e0 + 4];
        float4 v2 = *(const float4*)&vp[(size_t)s * HD + e0 + 8];
        float4 v3 = *(const float4*)&vp[(size_t)s * HD + e0 + 12];
        accg[0] += kd * v0.x;  accg[1] += kd * v0.y;
        accg[2] += kd * v0.z;  accg[3] += kd * v0.w;
        accg[4] += kd * v1.x;  accg[5] += kd * v1.y;
        accg[6] += kd * v1.z;  accg[7] += kd * v1.w;
        accg[8] += kd * v2.x;  accg[9] += kd * v2.y;
        accg[10] += kd * v2.z; accg[11] += kd * v2.w;
        accg[12] += kd * v3.x; accg[13] += kd * v3.y;
        accg[14] += kd * v3.z; accg[15] += kd * v3.w;
        if (str) {
            kss += kd;
            accs[0] += kd * v0.x;  accs[1] += kd * v0.y;
            accs[2] += kd * v0.z;  accs[3] += kd * v0.w;
            accs[4] += kd * v1.x;  accs[5] += kd * v1.y;
            accs[6] += kd * v1.z;  accs[7] += kd * v1.w;
            accs[8] += kd * v2.x;  accs[9] += kd * v2.y;
            accs[10] += kd * v2.z; accs[11] += kd * v2.w;
            accs[12] += kd * v3.x; accs[13] += kd * v3.y;
            accs[14] += kd * v3.z; accs[15] += kd * v3.w;
        }
    }
    float* pg = pkv + (size_t)blockIdx.x * 2 * 4096;
#pragma unroll
    for (int i = 0; i < 16; i++) pg[d * 64 + e0 + i] = accg[i];
#pragma unroll
    for (int i = 0; i < 16; i++) pg[4096 + d * 64 + e0 + i] = accs[i];
    if (eg == 0) {
        pks[blockIdx.x * 128 + d] = ksg;
        pks[blockIdx.x * 128 + 64 + d] = kss;
    }
}

// ---------------------------------------------------------------------------
// Kernel 2b: reduce partials + anchor outputs. Grid = 48 bh * 4 e-blocks.
// ---------------------------------------------------------------------------
__global__ __launch_bounds__(256) void band_reduce(const float* __restrict__ pkv,
                                                   const float* __restrict__ pks,
                                                   const float* __restrict__ aq,
                                                   unsigned short* __restrict__ kvsTb,
                                                   unsigned short* __restrict__ ksumsb,
                                                   unsigned short* __restrict__ aoutTb) {
    int bh = blockIdx.x >> 2, eb = blockIdx.x & 3, e0 = eb * 16;
    int h = bh % H_;
    __shared__ float kvgL[64][17];
    __shared__ float ksgL[64];
    __shared__ float anorm[12];
    int tid = threadIdx.x;
    for (int idx = tid; idx < 1024; idx += 256) {
        int d = idx >> 4, j = idx & 15;
        float sg = 0.f, ss = 0.f;
        const float* p = pkv + (size_t)(bh * 16) * 2 * 4096 + d * 64 + e0 + j;
#pragma unroll 4
        for (int c = 0; c < 16; c++) {
            sg += p[0];
            ss += p[4096];
            p += 2 * 4096;
        }
        kvgL[d][j] = sg;
        kvsTb[(size_t)bh * 4096 + (e0 + j) * 64 + d] = f2bu(ss);
    }
    if (tid < 64) {
        float sg = 0.f, ss = 0.f;
#pragma unroll 4
        for (int c = 0; c < 16; c++) {
            sg += pks[(bh * 16 + c) * 128 + tid];
            ss += pks[(bh * 16 + c) * 128 + 64 + tid];
        }
        ksgL[tid] = sg;
        if (eb == 0) ksumsb[bh * 64 + tid] = f2bu(ss);
    }
    __syncthreads();
    if (tid < 12) {
        float nrm = 0.f;
        for (int dd = 0; dd < 64; dd++)
            nrm += fmapf(aq[h * 768 + tid * 64 + dd]) * ksgL[dd];
        anorm[tid] = fmaxf(nrm, 1e-6f);
    }
    __syncthreads();
    if (tid < 192) {
        int a = tid >> 4, j = tid & 15;
        float acc = 0.f;
        for (int dd = 0; dd < 64; dd++)
            acc += fmapf(aq[h * 768 + a * 64 + dd]) * kvgL[dd][j];
        aoutTb[(size_t)bh * 768 + (e0 + j) * 12 + a] = f2bu(acc / anorm[a]);
    }
}

// ---------------------------------------------------------------------------
// Kernel 3: combine v2 — register-direct MFMA fragments (unchanged from r7).
// ---------------------------------------------------------------------------
__global__ __launch_bounds__(256) void combine(const unsigned short* __restrict__ qfb,
                                               const unsigned short* __restrict__ kfb,
                                               const float* __restrict__ vv,
                                               const unsigned short* __restrict__ aqfb_g,
                                               const unsigned short* __restrict__ kvsTb,
                                               const unsigned short* __restrict__ ksumsb,
                                               const unsigned short* __restrict__ aoutTb,
                                               const float* __restrict__ wlp,
                                               const float* __restrict__ wsp,
                                               const float* __restrict__ wgp,
                                               unsigned short* __restrict__ attnb) {
    __shared__ __attribute__((aligned(16))) unsigned short aqfb[16][72];   // anchors + ksum
    __shared__ __attribute__((aligned(16))) unsigned short vtbT[64][104];  // [e][band k], k<96
    __shared__ __attribute__((aligned(16))) unsigned short plb[64][104];   // masked P
    __shared__ __attribute__((aligned(16))) unsigned short qkgb[64][40];   // [token][anchor k]
    __shared__ float nrm[4][3][16];
    int bh = blockIdx.x >> 5, stile = blockIdx.x & 31;
    int b = bh / H_, h = bh % H_;
    int s0 = stile * 64;
    int tid = threadIdx.x, lane = tid & 63, wave = tid >> 6;
    int quad = lane >> 4, l15 = lane & 15;
    const unsigned short* qfp = qfb + (size_t)bh * S_ * HD;
    const unsigned short* kfp = kfb + (size_t)bh * S_ * HD;
    const float* vp = vv + (size_t)bh * S_ * HD;
    float a0 = wlp[0], a1 = wsp[0], a2 = wgp[0];
    float mx = fmaxf(a0, fmaxf(a1, a2));
    float ew0 = __expf(a0 - mx), ew1 = __expf(a1 - mx), ew2 = __expf(a2 - mx);
    float inv = 1.f / (ew0 + ew1 + ew2);
    float wl = ew0 * inv, wsb = ew1 * inv, wg = ew2 * inv;
    // ---- stage: vtbT (fp32 v transpose), aqfb, K-pads ----
    for (int i = tid; i < 96 * 64; i += 256) {
        int k = i >> 6, e = i & 63;
        int gs = s0 + k - 6;
        float v_ = (k < 75 && gs >= 0 && gs < S_) ? vp[(size_t)gs * HD + e] : 0.f;
        vtbT[e][k] = f2bu(v_);
    }
    if (tid < 192) {
        int a = tid >> 4, c = (tid & 15) * 4;
        *(ushort4*)&aqfb[a][c] = *(const ushort4*)&aqfb_g[h * 768 + a * 64 + c];
    }
    if (tid < 64) aqfb[12][tid] = ksumsb[bh * 64 + tid];
    if (tid < 192) aqfb[13 + (tid >> 6)][tid & 63] = 0;
    for (int i = tid; i < 1024; i += 256) {
        plb[i >> 4][80 + (i & 15)] = 0;   // K-pad cols 80..95
        qkgb[i >> 4][16 + (i & 15)] = 0;  // K-pad cols 16..31
    }
    __syncthreads();
    // ---- q A-fragments: per-thread rows, loaded once, reused everywhere ----
    u16x8 qa0, qa1;
    {
        const unsigned short* qr = qfp + (size_t)(s0 + wave * 16 + l15) * HD + quad * 8;
        qa0.u = *(const uint4*)qr;
        qa1.u = *(const uint4*)(qr + 32);
    }
    // ---- phase A: wave w computes P rows w*16..w*16+15 (wave-private) ----
#pragma unroll
    for (int tj = 0; tj < 5; tj++) {
        int row = tj * 16 + l15;
        int gs = s0 + row - 6;
        bool valid = (row < 75) && (gs >= 0) && (gs < S_);
        int gsc = gs < 0 ? 0 : (gs > S_ - 1 ? S_ - 1 : gs);
        const unsigned short* kr = kfp + (size_t)gsc * HD + quad * 8;
        u16x8 b0, b1, ones;
        ones.u = make_uint4(0x3F803F80u, 0x3F803F80u, 0x3F803F80u, 0x3F803F80u);
        b0.u = *(const uint4*)kr;
        b1.u = *(const uint4*)(kr + 32);
        if (!valid) { b0 = ones; b1 = ones; }
        f32x4 c = {0.f, 0.f, 0.f, 0.f};
        c = __builtin_amdgcn_mfma_f32_16x16x32_bf16(qa0.s, b0.s, c, 0, 0, 0);
        c = __builtin_amdgcn_mfma_f32_16x16x32_bf16(qa1.s, b1.s, c, 0, 0, 0);
        int col = tj * 16 + l15;
#pragma unroll
        for (int rr = 0; rr < 4; rr++) {
            int tok = wave * 16 + quad * 4 + rr;
            int which = col - tok;
            plb[tok][col] = (which >= 0 && which < 12) ? f2bu(c[rr]) : (unsigned short)0;
        }
    }
    {
        f32x4 c = {0.f, 0.f, 0.f, 0.f};
        short8 bfr0 = *(short8*)&aqfb[l15][quad * 8];
        short8 bfr1 = *(short8*)&aqfb[l15][32 + quad * 8];
        c = __builtin_amdgcn_mfma_f32_16x16x32_bf16(qa0.s, bfr0, c, 0, 0, 0);
        c = __builtin_amdgcn_mfma_f32_16x16x32_bf16(qa1.s, bfr1, c, 0, 0, 0);
#pragma unroll
        for (int rr = 0; rr < 4; rr++) qkgb[wave * 16 + quad * 4 + rr][l15] = f2bu(c[rr]);
    }
    // ---- per-wave norms -> reciprocal combine weights (lanes 0-15) ----
    if (lane < 16) {
        int t = wave * 16 + lane;
        float sl = 0.f;
#pragma unroll
        for (int j = 0; j < 12; j++) sl += bu2f(plb[t][t + j]);
        float sg = 0.f;
#pragma unroll
        for (int a = 0; a < 12; a++) sg += bu2f(qkgb[t][a]);
        nrm[wave][0][lane] = wl / fmaxf(sl, 1e-6f);
        nrm[wave][1][lane] = wg / fmaxf(sg, 1e-6f);
        nrm[wave][2][lane] = wsb / fmaxf(bu2f(qkgb[t][12]), 1e-6f);
    }
    // ---- phase B: fused MFMA; B-frags for stride/global bands direct ----
#pragma unroll
    for (int j2 = 0; j2 < 4; j2++) {
        int e = j2 * 16 + l15;
        f32x4 cL = {0.f, 0.f, 0.f, 0.f};
        f32x4 cG = {0.f, 0.f, 0.f, 0.f};
        f32x4 cS = {0.f, 0.f, 0.f, 0.f};
#pragma unroll
        for (int kk = 0; kk < 3; kk++) {
            short8 afr = *(short8*)&plb[wave * 16 + l15][kk * 32 + quad * 8];
            short8 bfr = *(short8*)&vtbT[e][kk * 32 + quad * 8];
            cL = __builtin_amdgcn_mfma_f32_16x16x32_bf16(afr, bfr, cL, 0, 0, 0);
        }
        {
            short8 afr = *(short8*)&qkgb[wave * 16 + l15][quad * 8];
            u16x8 bo;
            bo.u = make_uint4(0u, 0u, 0u, 0u);
            const unsigned* ap = (const unsigned*)(aoutTb + (size_t)bh * 768 + e * 12);
            if (quad == 0) {
                bo.u.x = ap[0]; bo.u.y = ap[1]; bo.u.z = ap[2]; bo.u.w = ap[3];
            } else if (quad == 1) {
                bo.u.x = ap[4]; bo.u.y = ap[5];
            }
            cG = __builtin_amdgcn_mfma_f32_16x16x32_bf16(afr, bo.s, cG, 0, 0, 0);
        }
        {
            const unsigned short* kvp = kvsTb + (size_t)bh * 4096 + e * 64 + quad * 8;
            u16x8 bk0, bk1;
            bk0.u = *(const uint4*)kvp;
            bk1.u = *(const uint4*)(kvp + 32);
            cS = __builtin_amdgcn_mfma_f32_16x16x32_bf16(qa0.s, bk0.s, cS, 0, 0, 0);
            cS = __builtin_amdgcn_mfma_f32_16x16x32_bf16(qa1.s, bk1.s, cS, 0, 0, 0);
        }
#pragma unroll
        for (int rr = 0; rr < 4; rr++) {
            int tq = quad * 4 + rr;
            int tok = wave * 16 + tq;
            float res = cL[rr] * nrm[wave][0][tq] + cS[rr] * nrm[wave][2][tq] +
                        cG[rr] * nrm[wave][1][tq];
            attnb[((size_t)(b * S_ + s0 + tok)) * 768 + h * 64 + e] = f2bu(res);
        }
    }
}

// ---------------------------------------------------------------------------
// Kernel 4: out = attn(bf16) @ out_w.T, counted-vmcnt dbuf + XCD swizzle.
// ---------------------------------------------------------------------------
__global__ __launch_bounds__(256) void out_gemm_mfma(const unsigned short* __restrict__ attnb,
                                                     const unsigned short* __restrict__ wb,
                                                     float* __restrict__ out) {
    __shared__ __attribute__((aligned(16))) unsigned short As[2][128 * 32];
    __shared__ __attribute__((aligned(16))) unsigned short Bs[2][128 * 32];
    const int K = 768;
    int orig = blockIdx.x;
    int swz = (orig & 7) * 48 + (orig >> 3);
    int mt = swz / 6, nt = swz - mt * 6;
    int n0 = nt * 128, m0 = mt * 128;
    int tid = threadIdx.x, lane = tid & 63, wave = tid >> 6;
    int wm = (wave & 1) * 64, wn = (wave >> 1) * 64;
    int quad = lane >> 4, l15 = lane & 15;
    f32x4 acc[4][4];
#pragma unroll
    for (int i = 0; i < 4; i++)
#pragma unroll
        for (int j = 0; j < 4; j++) acc[i][j] = 0.f;

    const unsigned short* ga0 = attnb + (size_t)(m0 + (tid >> 2)) * K + (tid & 3) * 8;
    const unsigned short* ga1 = attnb + (size_t)(m0 + 64 + (tid >> 2)) * K + (tid & 3) * 8;
    const unsigned short* gb0 = wb + (size_t)(n0 + (tid >> 2)) * K + (tid & 3) * 8;
    const unsigned short* gb1 = wb + (size_t)(n0 + 64 + (tid >> 2)) * K + (tid & 3) * 8;

    auto stage = [&](int bufi, int kk) {
        gload16(ga0 + kk, &As[bufi][wave * 512]);
        gload16(ga1 + kk, &As[bufi][2048 + wave * 512]);
        gload16(gb0 + kk, &Bs[bufi][wave * 512]);
        gload16(gb1 + kk, &Bs[bufi][2048 + wave * 512]);
    };
    auto compute = [&](int bufi) {
        short8 af[4], bfr[4];
#pragma unroll
        for (int i = 0; i < 4; i++)
            af[i] = *(short8*)&As[bufi][(wm + i * 16 + l15) * 32 + quad * 8];
#pragma unroll
        for (int j = 0; j < 4; j++)
            bfr[j] = *(short8*)&Bs[bufi][(wn + j * 16 + l15) * 32 + quad * 8];
#pragma unroll
        for (int i = 0; i < 4; i++)
#pragma unroll
            for (int j = 0; j < 4; j++)
                acc[i][j] = __builtin_amdgcn_mfma_f32_16x16x32_bf16(af[i], bfr[j], acc[i][j], 0, 0, 0);
    };

    stage(0, 0);
    int buf = 0;
    for (int t = 0; t < 23; t++) {
        stage(buf ^ 1, (t + 1) * 32);
        asm volatile("s_waitcnt vmcnt(4)" ::: "memory");
        __builtin_amdgcn_s_barrier();
        __builtin_amdgcn_sched_barrier(0);
        compute(buf);
        asm volatile("" ::: "memory");
        __builtin_amdgcn_s_barrier();
        buf ^= 1;
    }
    asm volatile("s_waitcnt vmcnt(0)" ::: "memory");
    __builtin_amdgcn_s_barrier();
    __builtin_amdgcn_sched_barrier(0);
    compute(buf);

#pragma unroll
    for (int j = 0; j < 4; j++) {
        int col = n0 + wn + j * 16 + l15;
#pragma unroll
        for (int i = 0; i < 4; i++) {
#pragma unroll
            for (int rr = 0; rr < 4; rr++) {
                int m = m0 + wm + i * 16 + quad * 4 + rr;
                out[(size_t)m * 768 + col] = acc[i][j][rr];
            }
        }
    }
}

extern "C" void kernel_launch(void* const* d_in, const int* in_sizes, int n_in,
                              void* d_out, int out_size, void* d_ws, size_t ws_size,
                              hipStream_t stream) {
    const float* x = (const float*)d_in[0];
    const float* qkvw = (const float*)d_in[1];
    const float* outw = (const float*)d_in[2];
    const float* aq = (const float*)d_in[3];
    const float* wlp = (const float*)d_in[4];
    const float* wsp = (const float*)d_in[5];
    const float* wgp = (const float*)d_in[6];

    float* ws = (float*)d_ws;
    const size_t NBH = (size_t)B_ * H_ * S_ * HD;  // 6,291,456
    unsigned short* qfb = (unsigned short*)ws;
    unsigned short* kfb = (unsigned short*)(ws + NBH / 2);
    float* kf = ws + NBH;
    float* vv = ws + 2 * NBH;
    float* attn_region = ws + 3 * NBH;
    unsigned short* xb = (unsigned short*)attn_region;
    unsigned short* wb = (unsigned short*)(attn_region + 3145728);
    float* pkv = attn_region;
    unsigned short* attnb = (unsigned short*)attn_region;
    unsigned short* kvsTb = (unsigned short*)(attn_region + NBH);   // 48*4096
    unsigned short* ksumsb = kvsTb + 48 * 4096;                     // 48*64
    unsigned short* aoutTb = ksumsb + 48 * 64;                      // 48*768
    unsigned short* aqfb_g = aoutTb + 48 * 768;                     // 9216
    float* pks = attn_region + NBH + 122880;                        // 768*128 floats
    unsigned short* outwb = (unsigned short*)(pks + 768 * 128);

    convert_all<<<8484, 256, 0, stream>>>(x, qkvw, outw, aq, xb, wb, outwb, aqfb_g);
    qkv_gemm_mfma<<<1152, 256, 0, stream>>>(xb, wb, qfb, kf, kfb, vv);
    band_partial<<<48 * 16, 256, 0, stream>>>(kf, vv, pkv, pks);
    band_reduce<<<48 * 4, 256, 0, stream>>>(pkv, pks, aq, kvsTb, ksumsb, aoutTb);
    combine<<<48 * 32, 256, 0, stream>>>(qfb, kfb, vv, aqfb_g, kvsTb, ksumsb, aoutTb,
                                         wlp, wsp, wgp, attnb);
    out_gemm_mfma<<<384, 256, 0, stream>>>(attnb, outwb, (float*)d_out);
}

// Round 9
// 269.474 us; speedup vs baseline: 1.5270x; 1.0112x over previous
//
#include <hip/hip_runtime.h>
#include <hip/hip_bf16.h>

#define B_ 4
#define S_ 2048
#define D_ 768
#define H_ 12
#define HD 64

typedef __attribute__((ext_vector_type(8))) short short8;
typedef __attribute__((ext_vector_type(4))) float f32x4;

__device__ __forceinline__ float fmapf(float x) { return x > 0.f ? x + 1.f : __expf(x); }

// fp32 -> bf16 round-to-nearest-even (finite inputs only)
__device__ __forceinline__ unsigned short f2bu(float f) {
    unsigned u = __float_as_uint(f);
    u += 0x7FFFu + ((u >> 16) & 1u);
    return (unsigned short)(u >> 16);
}
__device__ __forceinline__ float bu2f(unsigned short v) {
    return __uint_as_float((unsigned)v << 16);
}

// async global->LDS direct copy, 16B per lane. lds ptr must be wave-uniform;
// HW writes lane l to ldsbase + l*16 (m97 pattern: linear LDS dest).
__device__ __forceinline__ void gload16(const void* g, void* l) {
    __builtin_amdgcn_global_load_lds((__attribute__((address_space(1))) void*)(size_t)g,
                                     (__attribute__((address_space(3))) void*)l, 16, 0, 0);
}

union u16x8 {
    uint4 u;
    short8 s;
    unsigned short h[8];
};

// ---------------------------------------------------------------------------
// Kernel 0: fused fp32->bf16 converts for x, qkv_w, out_w + fmap(anchor_q).
// ---------------------------------------------------------------------------
__global__ __launch_bounds__(256) void convert_all(const float* __restrict__ x,
                                                   const float* __restrict__ qkvw,
                                                   const float* __restrict__ outw,
                                                   const float* __restrict__ aq,
                                                   unsigned short* __restrict__ xb,
                                                   unsigned short* __restrict__ wb,
                                                   unsigned short* __restrict__ outwb,
                                                   unsigned short* __restrict__ aqfb_g) {
    int gid = blockIdx.x * 256 + threadIdx.x;
    const float* src;
    unsigned short* dst;
    int i4;
    if (gid < 1572864) {
        src = x; dst = xb; i4 = gid;
    } else if (gid < 1572864 + 442368) {
        src = qkvw; dst = wb; i4 = gid - 1572864;
    } else if (gid < 2162688) {
        src = outw; dst = outwb; i4 = gid - (1572864 + 442368);
    } else {
        int i = gid - 2162688;  // < 9216
        aqfb_g[i] = f2bu(fmapf(aq[i]));
        return;
    }
    float4 v = *(const float4*)&src[i4 * 4];
    ushort4 o;
    o.x = f2bu(v.x); o.y = f2bu(v.y); o.z = f2bu(v.z); o.w = f2bu(v.w);
    *(ushort4*)&dst[i4 * 4] = o;
}

// ---------------------------------------------------------------------------
// Kernel 1: qkv = x @ qkv_w.T via bf16 MFMA. dbuf + XCD swizzle + counted
// vmcnt. Epilogue now writes ONLY bf16 q/k/v (37.8 MB vs 75.6 MB) — the
// fp32 copies existed solely for band_partial, which now reads bf16.
// ---------------------------------------------------------------------------
__global__ __launch_bounds__(256) void qkv_gemm_mfma(const unsigned short* __restrict__ xb,
                                                     const unsigned short* __restrict__ wb,
                                                     unsigned short* __restrict__ qfb,
                                                     unsigned short* __restrict__ kfb,
                                                     unsigned short* __restrict__ vvb) {
    __shared__ __attribute__((aligned(16))) unsigned short As[2][128 * 32];
    __shared__ __attribute__((aligned(16))) unsigned short Bs[2][128 * 32];
    const int K = 768;
    int orig = blockIdx.x;
    int swz = (orig & 7) * 144 + (orig >> 3);
    int mt = swz / 18, nt = swz - mt * 18;
    int n0 = nt * 128, m0 = mt * 128;
    int tid = threadIdx.x, lane = tid & 63, wave = tid >> 6;
    int wm = (wave & 1) * 64, wn = (wave >> 1) * 64;
    int quad = lane >> 4, l15 = lane & 15;
    f32x4 acc[4][4];
#pragma unroll
    for (int i = 0; i < 4; i++)
#pragma unroll
        for (int j = 0; j < 4; j++) acc[i][j] = 0.f;

    const unsigned short* ga0 = xb + (size_t)(m0 + (tid >> 2)) * K + (tid & 3) * 8;
    const unsigned short* ga1 = xb + (size_t)(m0 + 64 + (tid >> 2)) * K + (tid & 3) * 8;
    const unsigned short* gb0 = wb + (size_t)(n0 + (tid >> 2)) * K + (tid & 3) * 8;
    const unsigned short* gb1 = wb + (size_t)(n0 + 64 + (tid >> 2)) * K + (tid & 3) * 8;

    auto stage = [&](int bufi, int kk) {
        gload16(ga0 + kk, &As[bufi][wave * 512]);
        gload16(ga1 + kk, &As[bufi][2048 + wave * 512]);
        gload16(gb0 + kk, &Bs[bufi][wave * 512]);
        gload16(gb1 + kk, &Bs[bufi][2048 + wave * 512]);
    };
    auto compute = [&](int bufi) {
        short8 af[4], bfr[4];
#pragma unroll
        for (int i = 0; i < 4; i++)
            af[i] = *(short8*)&As[bufi][(wm + i * 16 + l15) * 32 + quad * 8];
#pragma unroll
        for (int j = 0; j < 4; j++)
            bfr[j] = *(short8*)&Bs[bufi][(wn + j * 16 + l15) * 32 + quad * 8];
#pragma unroll
        for (int i = 0; i < 4; i++)
#pragma unroll
            for (int j = 0; j < 4; j++)
                acc[i][j] = __builtin_amdgcn_mfma_f32_16x16x32_bf16(af[i], bfr[j], acc[i][j], 0, 0, 0);
    };

    stage(0, 0);
    int buf = 0;
    for (int t = 0; t < 23; t++) {
        stage(buf ^ 1, (t + 1) * 32);
        asm volatile("s_waitcnt vmcnt(4)" ::: "memory");
        __builtin_amdgcn_s_barrier();
        __builtin_amdgcn_sched_barrier(0);
        compute(buf);
        asm volatile("" ::: "memory");
        __builtin_amdgcn_s_barrier();
        buf ^= 1;
    }
    asm volatile("s_waitcnt vmcnt(0)" ::: "memory");
    __builtin_amdgcn_s_barrier();
    __builtin_amdgcn_sched_barrier(0);
    compute(buf);

#pragma unroll
    for (int j = 0; j < 4; j++) {
        int col = n0 + wn + j * 16 + l15;
        int t3 = col / 768;
        int r = col - t3 * 768;
        int h = r >> 6, d = r & 63;
#pragma unroll
        for (int i = 0; i < 4; i++) {
#pragma unroll
            for (int rr = 0; rr < 4; rr++) {
                int m = m0 + wm + i * 16 + quad * 4 + rr;
                int b = m >> 11, s = m & 2047;
                size_t dst = (((size_t)(b * H_ + h) * S_) + s) * HD + d;
                float val = acc[i][j][rr];
                if (t3 == 0)
                    qfb[dst] = f2bu(fmapf(val));
                else if (t3 == 1)
                    kfb[dst] = f2bu(fmapf(val));
                else
                    vvb[dst] = f2bu(val);
            }
        }
    }
}

// ---------------------------------------------------------------------------
// Kernel 2a: partial kv states — pure streaming, bf16 inputs (exact
// bf16->fp32 converts; accumulation order unchanged). Grid = 48*16.
// ---------------------------------------------------------------------------
__global__ __launch_bounds__(256) void band_partial(const unsigned short* __restrict__ kfb,
                                                    const unsigned short* __restrict__ vvb,
                                                    float* __restrict__ pkv,
                                                    float* __restrict__ pks) {
    int bh = blockIdx.x >> 4, chunk = blockIdx.x & 15;
    int sbase = chunk * 128;
    const unsigned short* kfp = kfb + (size_t)bh * S_ * HD + (size_t)sbase * HD;
    const unsigned short* vp = vvb + (size_t)bh * S_ * HD + (size_t)sbase * HD;
    int tid = threadIdx.x;
    int d = tid & 63, eg = tid >> 6, e0 = eg * 16;
    float accg[16], accs[16];
#pragma unroll
    for (int i = 0; i < 16; i++) { accg[i] = 0.f; accs[i] = 0.f; }
    float ksg = 0.f, kss = 0.f;
#pragma unroll 4
    for (int s = 0; s < 128; s++) {
        float kd = bu2f(kfp[(size_t)s * HD + d]);
        bool str = ((sbase + s) % 3) == 0;
        ksg += kd;
        u16x8 va, vb2;
        va.u = *(const uint4*)&vp[(size_t)s * HD + e0];
        vb2.u = *(const uint4*)&vp[(size_t)s * HD + e0 + 8];
        float vf[16];
#pragma unroll
        for (int i = 0; i < 8; i++) vf[i] = bu2f(va.h[i]);
#pragma unroll
        for (int i = 0; i < 8; i++) vf[8 + i] = bu2f(vb2.h[i]);
#pragma unroll
        for (int i = 0; i < 16; i++) accg[i] += kd * vf[i];
        if (str) {
            kss += kd;
#pragma unroll
            for (int i = 0; i < 16; i++) accs[i] += kd * vf[i];
        }
    }
    float* pg = pkv + (size_t)blockIdx.x * 2 * 4096;
#pragma unroll
    for (int i = 0; i < 16; i++) pg[d * 64 + e0 + i] = accg[i];
#pragma unroll
    for (int i = 0; i < 16; i++) pg[4096 + d * 64 + e0 + i] = accs[i];
    if (eg == 0) {
        pks[blockIdx.x * 128 + d] = ksg;
        pks[blockIdx.x * 128 + 64 + d] = kss;
    }
}

// ---------------------------------------------------------------------------
// Kernel 2b: reduce partials + anchor outputs. Grid = 48 bh * 4 e-blocks.
// ---------------------------------------------------------------------------
__global__ __launch_bounds__(256) void band_reduce(const float* __restrict__ pkv,
                                                   const float* __restrict__ pks,
                                                   const float* __restrict__ aq,
                                                   unsigned short* __restrict__ kvsTb,
                                                   unsigned short* __restrict__ ksumsb,
                                                   unsigned short* __restrict__ aoutTb) {
    int bh = blockIdx.x >> 2, eb = blockIdx.x & 3, e0 = eb * 16;
    int h = bh % H_;
    __shared__ float kvgL[64][17];
    __shared__ float ksgL[64];
    __shared__ float anorm[12];
    int tid = threadIdx.x;
    for (int idx = tid; idx < 1024; idx += 256) {
        int d = idx >> 4, j = idx & 15;
        float sg = 0.f, ss = 0.f;
        const float* p = pkv + (size_t)(bh * 16) * 2 * 4096 + d * 64 + e0 + j;
#pragma unroll 4
        for (int c = 0; c < 16; c++) {
            sg += p[0];
            ss += p[4096];
            p += 2 * 4096;
        }
        kvgL[d][j] = sg;
        kvsTb[(size_t)bh * 4096 + (e0 + j) * 64 + d] = f2bu(ss);
    }
    if (tid < 64) {
        float sg = 0.f, ss = 0.f;
#pragma unroll 4
        for (int c = 0; c < 16; c++) {
            sg += pks[(bh * 16 + c) * 128 + tid];
            ss += pks[(bh * 16 + c) * 128 + 64 + tid];
        }
        ksgL[tid] = sg;
        if (eb == 0) ksumsb[bh * 64 + tid] = f2bu(ss);
    }
    __syncthreads();
    if (tid < 12) {
        float nrm = 0.f;
        for (int dd = 0; dd < 64; dd++)
            nrm += fmapf(aq[h * 768 + tid * 64 + dd]) * ksgL[dd];
        anorm[tid] = fmaxf(nrm, 1e-6f);
    }
    __syncthreads();
    if (tid < 192) {
        int a = tid >> 4, j = tid & 15;
        float acc = 0.f;
        for (int dd = 0; dd < 64; dd++)
            acc += fmapf(aq[h * 768 + a * 64 + dd]) * kvgL[dd][j];
        aoutTb[(size_t)bh * 768 + (e0 + j) * 12 + a] = f2bu(acc / anorm[a]);
    }
}

// ---------------------------------------------------------------------------
// Kernel 3: combine — register-direct MFMA fragments. vtbT now stages
// straight bf16 copies from vvb (same values as f2bu(fp32 v) — the local
// band remains bit-identical).
// ---------------------------------------------------------------------------
__global__ __launch_bounds__(256) void combine(const unsigned short* __restrict__ qfb,
                                               const unsigned short* __restrict__ kfb,
                                               const unsigned short* __restrict__ vvb,
                                               const unsigned short* __restrict__ aqfb_g,
                                               const unsigned short* __restrict__ kvsTb,
                                               const unsigned short* __restrict__ ksumsb,
                                               const unsigned short* __restrict__ aoutTb,
                                               const float* __restrict__ wlp,
                                               const float* __restrict__ wsp,
                                               const float* __restrict__ wgp,
                                               unsigned short* __restrict__ attnb) {
    __shared__ __attribute__((aligned(16))) unsigned short aqfb[16][72];   // anchors + ksum
    __shared__ __attribute__((aligned(16))) unsigned short vtbT[64][104];  // [e][band k], k<96
    __shared__ __attribute__((aligned(16))) unsigned short plb[64][104];   // masked P
    __shared__ __attribute__((aligned(16))) unsigned short qkgb[64][40];   // [token][anchor k]
    __shared__ float nrm[4][3][16];
    int bh = blockIdx.x >> 5, stile = blockIdx.x & 31;
    int b = bh / H_, h = bh % H_;
    int s0 = stile * 64;
    int tid = threadIdx.x, lane = tid & 63, wave = tid >> 6;
    int quad = lane >> 4, l15 = lane & 15;
    const unsigned short* qfp = qfb + (size_t)bh * S_ * HD;
    const unsigned short* kfp = kfb + (size_t)bh * S_ * HD;
    const unsigned short* vp = vvb + (size_t)bh * S_ * HD;
    float a0 = wlp[0], a1 = wsp[0], a2 = wgp[0];
    float mx = fmaxf(a0, fmaxf(a1, a2));
    float ew0 = __expf(a0 - mx), ew1 = __expf(a1 - mx), ew2 = __expf(a2 - mx);
    float inv = 1.f / (ew0 + ew1 + ew2);
    float wl = ew0 * inv, wsb = ew1 * inv, wg = ew2 * inv;
    // ---- stage: vtbT (bf16 copy transpose), aqfb, K-pads ----
    for (int i = tid; i < 96 * 64; i += 256) {
        int k = i >> 6, e = i & 63;
        int gs = s0 + k - 6;
        unsigned short v_ = (k < 75 && gs >= 0 && gs < S_) ? vp[(size_t)gs * HD + e]
                                                           : (unsigned short)0;
        vtbT[e][k] = v_;
    }
    if (tid < 192) {
        int a = tid >> 4, c = (tid & 15) * 4;
        *(ushort4*)&aqfb[a][c] = *(const ushort4*)&aqfb_g[h * 768 + a * 64 + c];
    }
    if (tid < 64) aqfb[12][tid] = ksumsb[bh * 64 + tid];
    if (tid < 192) aqfb[13 + (tid >> 6)][tid & 63] = 0;
    for (int i = tid; i < 1024; i += 256) {
        plb[i >> 4][80 + (i & 15)] = 0;   // K-pad cols 80..95
        qkgb[i >> 4][16 + (i & 15)] = 0;  // K-pad cols 16..31
    }
    __syncthreads();
    // ---- q A-fragments: per-thread rows, loaded once, reused everywhere ----
    u16x8 qa0, qa1;
    {
        const unsigned short* qr = qfp + (size_t)(s0 + wave * 16 + l15) * HD + quad * 8;
        qa0.u = *(const uint4*)qr;
        qa1.u = *(const uint4*)(qr + 32);
    }
    // ---- phase A: wave w computes P rows w*16..w*16+15 (wave-private) ----
#pragma unroll
    for (int tj = 0; tj < 5; tj++) {
        int row = tj * 16 + l15;
        int gs = s0 + row - 6;
        bool valid = (row < 75) && (gs >= 0) && (gs < S_);
        int gsc = gs < 0 ? 0 : (gs > S_ - 1 ? S_ - 1 : gs);
        const unsigned short* kr = kfp + (size_t)gsc * HD + quad * 8;
        u16x8 b0, b1, ones;
        ones.u = make_uint4(0x3F803F80u, 0x3F803F80u, 0x3F803F80u, 0x3F803F80u);
        b0.u = *(const uint4*)kr;
        b1.u = *(const uint4*)(kr + 32);
        if (!valid) { b0 = ones; b1 = ones; }
        f32x4 c = {0.f, 0.f, 0.f, 0.f};
        c = __builtin_amdgcn_mfma_f32_16x16x32_bf16(qa0.s, b0.s, c, 0, 0, 0);
        c = __builtin_amdgcn_mfma_f32_16x16x32_bf16(qa1.s, b1.s, c, 0, 0, 0);
        int col = tj * 16 + l15;
#pragma unroll
        for (int rr = 0; rr < 4; rr++) {
            int tok = wave * 16 + quad * 4 + rr;
            int which = col - tok;
            plb[tok][col] = (which >= 0 && which < 12) ? f2bu(c[rr]) : (unsigned short)0;
        }
    }
    {
        f32x4 c = {0.f, 0.f, 0.f, 0.f};
        short8 bfr0 = *(short8*)&aqfb[l15][quad * 8];
        short8 bfr1 = *(short8*)&aqfb[l15][32 + quad * 8];
        c = __builtin_amdgcn_mfma_f32_16x16x32_bf16(qa0.s, bfr0, c, 0, 0, 0);
        c = __builtin_amdgcn_mfma_f32_16x16x32_bf16(qa1.s, bfr1, c, 0, 0, 0);
#pragma unroll
        for (int rr = 0; rr < 4; rr++) qkgb[wave * 16 + quad * 4 + rr][l15] = f2bu(c[rr]);
    }
    // ---- per-wave norms -> reciprocal combine weights (lanes 0-15) ----
    if (lane < 16) {
        int t = wave * 16 + lane;
        float sl = 0.f;
#pragma unroll
        for (int j = 0; j < 12; j++) sl += bu2f(plb[t][t + j]);
        float sg = 0.f;
#pragma unroll
        for (int a = 0; a < 12; a++) sg += bu2f(qkgb[t][a]);
        nrm[wave][0][lane] = wl / fmaxf(sl, 1e-6f);
        nrm[wave][1][lane] = wg / fmaxf(sg, 1e-6f);
        nrm[wave][2][lane] = wsb / fmaxf(bu2f(qkgb[t][12]), 1e-6f);
    }
    // ---- phase B: fused MFMA; B-frags for stride/global bands direct ----
#pragma unroll
    for (int j2 = 0; j2 < 4; j2++) {
        int e = j2 * 16 + l15;
        f32x4 cL = {0.f, 0.f, 0.f, 0.f};
        f32x4 cG = {0.f, 0.f, 0.f, 0.f};
        f32x4 cS = {0.f, 0.f, 0.f, 0.f};
#pragma unroll
        for (int kk = 0; kk < 3; kk++) {
            short8 afr = *(short8*)&plb[wave * 16 + l15][kk * 32 + quad * 8];
            short8 bfr = *(short8*)&vtbT[e][kk * 32 + quad * 8];
            cL = __builtin_amdgcn_mfma_f32_16x16x32_bf16(afr, bfr, cL, 0, 0, 0);
        }
        {
            short8 afr = *(short8*)&qkgb[wave * 16 + l15][quad * 8];
            u16x8 bo;
            bo.u = make_uint4(0u, 0u, 0u, 0u);
            const unsigned* ap = (const unsigned*)(aoutTb + (size_t)bh * 768 + e * 12);
            if (quad == 0) {
                bo.u.x = ap[0]; bo.u.y = ap[1]; bo.u.z = ap[2]; bo.u.w = ap[3];
            } else if (quad == 1) {
                bo.u.x = ap[4]; bo.u.y = ap[5];
            }
            cG = __builtin_amdgcn_mfma_f32_16x16x32_bf16(afr, bo.s, cG, 0, 0, 0);
        }
        {
            const unsigned short* kvp = kvsTb + (size_t)bh * 4096 + e * 64 + quad * 8;
            u16x8 bk0, bk1;
            bk0.u = *(const uint4*)kvp;
            bk1.u = *(const uint4*)(kvp + 32);
            cS = __builtin_amdgcn_mfma_f32_16x16x32_bf16(qa0.s, bk0.s, cS, 0, 0, 0);
            cS = __builtin_amdgcn_mfma_f32_16x16x32_bf16(qa1.s, bk1.s, cS, 0, 0, 0);
        }
#pragma unroll
        for (int rr = 0; rr < 4; rr++) {
            int tq = quad * 4 + rr;
            int tok = wave * 16 + tq;
            float res = cL[rr] * nrm[wave][0][tq] + cS[rr] * nrm[wave][2][tq] +
                        cG[rr] * nrm[wave][1][tq];
            attnb[((size_t)(b * S_ + s0 + tok)) * 768 + h * 64 + e] = f2bu(res);
        }
    }
}

// ---------------------------------------------------------------------------
// Kernel 4: out = attn(bf16) @ out_w.T, counted-vmcnt dbuf + XCD swizzle.
// ---------------------------------------------------------------------------
__global__ __launch_bounds__(256) void out_gemm_mfma(const unsigned short* __restrict__ attnb,
                                                     const unsigned short* __restrict__ wb,
                                                     float* __restrict__ out) {
    __shared__ __attribute__((aligned(16))) unsigned short As[2][128 * 32];
    __shared__ __attribute__((aligned(16))) unsigned short Bs[2][128 * 32];
    const int K = 768;
    int orig = blockIdx.x;
    int swz = (orig & 7) * 48 + (orig >> 3);
    int mt = swz / 6, nt = swz - mt * 6;
    int n0 = nt * 128, m0 = mt * 128;
    int tid = threadIdx.x, lane = tid & 63, wave = tid >> 6;
    int wm = (wave & 1) * 64, wn = (wave >> 1) * 64;
    int quad = lane >> 4, l15 = lane & 15;
    f32x4 acc[4][4];
#pragma unroll
    for (int i = 0; i < 4; i++)
#pragma unroll
        for (int j = 0; j < 4; j++) acc[i][j] = 0.f;

    const unsigned short* ga0 = attnb + (size_t)(m0 + (tid >> 2)) * K + (tid & 3) * 8;
    const unsigned short* ga1 = attnb + (size_t)(m0 + 64 + (tid >> 2)) * K + (tid & 3) * 8;
    const unsigned short* gb0 = wb + (size_t)(n0 + (tid >> 2)) * K + (tid & 3) * 8;
    const unsigned short* gb1 = wb + (size_t)(n0 + 64 + (tid >> 2)) * K + (tid & 3) * 8;

    auto stage = [&](int bufi, int kk) {
        gload16(ga0 + kk, &As[bufi][wave * 512]);
        gload16(ga1 + kk, &As[bufi][2048 + wave * 512]);
        gload16(gb0 + kk, &Bs[bufi][wave * 512]);
        gload16(gb1 + kk, &Bs[bufi][2048 + wave * 512]);
    };
    auto compute = [&](int bufi) {
        short8 af[4], bfr[4];
#pragma unroll
        for (int i = 0; i < 4; i++)
            af[i] = *(short8*)&As[bufi][(wm + i * 16 + l15) * 32 + quad * 8];
#pragma unroll
        for (int j = 0; j < 4; j++)
            bfr[j] = *(short8*)&Bs[bufi][(wn + j * 16 + l15) * 32 + quad * 8];
#pragma unroll
        for (int i = 0; i < 4; i++)
#pragma unroll
            for (int j = 0; j < 4; j++)
                acc[i][j] = __builtin_amdgcn_mfma_f32_16x16x32_bf16(af[i], bfr[j], acc[i][j], 0, 0, 0);
    };

    stage(0, 0);
    int buf = 0;
    for (int t = 0; t < 23; t++) {
        stage(buf ^ 1, (t + 1) * 32);
        asm volatile("s_waitcnt vmcnt(4)" ::: "memory");
        __builtin_amdgcn_s_barrier();
        __builtin_amdgcn_sched_barrier(0);
        compute(buf);
        asm volatile("" ::: "memory");
        __builtin_amdgcn_s_barrier();
        buf ^= 1;
    }
    asm volatile("s_waitcnt vmcnt(0)" ::: "memory");
    __builtin_amdgcn_s_barrier();
    __builtin_amdgcn_sched_barrier(0);
    compute(buf);

#pragma unroll
    for (int j = 0; j < 4; j++) {
        int col = n0 + wn + j * 16 + l15;
#pragma unroll
        for (int i = 0; i < 4; i++) {
#pragma unroll
            for (int rr = 0; rr < 4; rr++) {
                int m = m0 + wm + i * 16 + quad * 4 + rr;
                out[(size_t)m * 768 + col] = acc[i][j][rr];
            }
        }
    }
}

extern "C" void kernel_launch(void* const* d_in, const int* in_sizes, int n_in,
                              void* d_out, int out_size, void* d_ws, size_t ws_size,
                              hipStream_t stream) {
    const float* x = (const float*)d_in[0];
    const float* qkvw = (const float*)d_in[1];
    const float* outw = (const float*)d_in[2];
    const float* aq = (const float*)d_in[3];
    const float* wlp = (const float*)d_in[4];
    const float* wsp = (const float*)d_in[5];
    const float* wgp = (const float*)d_in[6];

    float* ws = (float*)d_ws;
    const size_t NBH = (size_t)B_ * H_ * S_ * HD;  // 6,291,456
    // [0, 1.5*NBH floats): bf16 qfb / kfb / vvb (NBH ushorts each)
    unsigned short* qfb = (unsigned short*)ws;
    unsigned short* kfb = (unsigned short*)(ws + NBH / 2);
    unsigned short* vvb = (unsigned short*)(ws + NBH);
    float* attn_region = ws + 2 * NBH;  // NBH floats; multi-use scratch
    //  [0, 3145728)  xb (bf16 x)      : convert .. qkv_gemm
    //  [3145728, 4030464) wb (bf16 qkv_w): convert .. qkv_gemm
    //  [0, NBH)      pkv              : band_partial .. band_reduce
    //  [0, 3145728)  attnb (bf16 attn): combine .. out_gemm
    unsigned short* xb = (unsigned short*)attn_region;
    unsigned short* wb = (unsigned short*)(attn_region + 3145728);
    float* pkv = attn_region;
    unsigned short* attnb = (unsigned short*)attn_region;
    unsigned short* kvsTb = (unsigned short*)(attn_region + NBH);   // 48*4096
    unsigned short* ksumsb = kvsTb + 48 * 4096;                     // 48*64
    unsigned short* aoutTb = ksumsb + 48 * 64;                      // 48*768
    unsigned short* aqfb_g = aoutTb + 48 * 768;                     // 9216
    float* pks = attn_region + NBH + 122880;                        // 768*128 floats
    unsigned short* outwb = (unsigned short*)(pks + 768 * 128);

    convert_all<<<8484, 256, 0, stream>>>(x, qkvw, outw, aq, xb, wb, outwb, aqfb_g);
    qkv_gemm_mfma<<<1152, 256, 0, stream>>>(xb, wb, qfb, kfb, vvb);
    band_partial<<<48 * 16, 256, 0, stream>>>(kfb, vvb, pkv, pks);
    band_reduce<<<48 * 4, 256, 0, stream>>>(pkv, pks, aq, kvsTb, ksumsb, aoutTb);
    combine<<<48 * 32, 256, 0, stream>>>(qfb, kfb, vvb, aqfb_g, kvsTb, ksumsb, aoutTb,
                                         wlp, wsp, wgp, attnb);
    out_gemm_mfma<<<384, 256, 0, stream>>>(attnb, outwb, (float*)d_out);
}

// Round 10
// 257.787 us; speedup vs baseline: 1.5962x; 1.0453x over previous
//
#include <hip/hip_runtime.h>
#include <hip/hip_bf16.h>

#define B_ 4
#define S_ 2048
#define D_ 768
#define H_ 12
#define HD 64

typedef __attribute__((ext_vector_type(8))) short short8;
typedef __attribute__((ext_vector_type(4))) float f32x4;

__device__ __forceinline__ float fmapf(float x) { return x > 0.f ? x + 1.f : __expf(x); }

// fp32 -> bf16 round-to-nearest-even (finite inputs only)
__device__ __forceinline__ unsigned short f2bu(float f) {
    unsigned u = __float_as_uint(f);
    u += 0x7FFFu + ((u >> 16) & 1u);
    return (unsigned short)(u >> 16);
}
__device__ __forceinline__ float bu2f(unsigned short v) {
    return __uint_as_float((unsigned)v << 16);
}

// async global->LDS direct copy, 16B per lane. lds ptr must be wave-uniform;
// HW writes lane l to ldsbase + l*16 (m97 pattern: linear LDS dest).
__device__ __forceinline__ void gload16(const void* g, void* l) {
    __builtin_amdgcn_global_load_lds((__attribute__((address_space(1))) void*)(size_t)g,
                                     (__attribute__((address_space(3))) void*)l, 16, 0, 0);
}

union u16x8 {
    uint4 u;
    short8 s;
    unsigned short h[8];
};

// ---------------------------------------------------------------------------
// Kernel 0: fused fp32->bf16 converts for x, qkv_w, out_w + fmap(anchor_q).
// ---------------------------------------------------------------------------
__global__ __launch_bounds__(256) void convert_all(const float* __restrict__ x,
                                                   const float* __restrict__ qkvw,
                                                   const float* __restrict__ outw,
                                                   const float* __restrict__ aq,
                                                   unsigned short* __restrict__ xb,
                                                   unsigned short* __restrict__ wb,
                                                   unsigned short* __restrict__ outwb,
                                                   unsigned short* __restrict__ aqfb_g) {
    int gid = blockIdx.x * 256 + threadIdx.x;
    const float* src;
    unsigned short* dst;
    int i4;
    if (gid < 1572864) {
        src = x; dst = xb; i4 = gid;
    } else if (gid < 1572864 + 442368) {
        src = qkvw; dst = wb; i4 = gid - 1572864;
    } else if (gid < 2162688) {
        src = outw; dst = outwb; i4 = gid - (1572864 + 442368);
    } else {
        int i = gid - 2162688;  // < 9216
        aqfb_g[i] = f2bu(fmapf(aq[i]));
        return;
    }
    float4 v = *(const float4*)&src[i4 * 4];
    ushort4 o;
    o.x = f2bu(v.x); o.y = f2bu(v.y); o.z = f2bu(v.z); o.w = f2bu(v.w);
    *(ushort4*)&dst[i4 * 4] = o;
}

// ---------------------------------------------------------------------------
// Kernel 1: qkv = x @ qkv_w.T via bf16 MFMA. dbuf + XCD swizzle + counted
// vmcnt. Epilogue v2: per-wave C-tile (64 tokens x 64 d, t3/h wave-uniform
// since 64-aligned 64-wide col range never crosses a 768 boundary) staged
// in LDS [64][72] bf16 then stored as 8x coalesced 1KB dwordx4 bursts —
// full 64B lines, no write amplification. Values bit-identical.
// ---------------------------------------------------------------------------
__global__ __launch_bounds__(256) void qkv_gemm_mfma(const unsigned short* __restrict__ xb,
                                                     const unsigned short* __restrict__ wb,
                                                     unsigned short* __restrict__ qfb,
                                                     unsigned short* __restrict__ kfb,
                                                     unsigned short* __restrict__ vvb) {
    // shmem layout: As[bufi] = [bufi*4096, +4096) shorts,
    //               Bs[bufi] = [8192 + bufi*4096, +4096) shorts  (32 KB)
    // epilogue: wave w C-tile = [w*4608, +4608) shorts ([64][72], 36 KB)
    __shared__ __attribute__((aligned(16))) unsigned short shmem[18432];
    const int K = 768;
    int orig = blockIdx.x;
    int swz = (orig & 7) * 144 + (orig >> 3);
    int mt = swz / 18, nt = swz - mt * 18;
    int n0 = nt * 128, m0 = mt * 128;
    int tid = threadIdx.x, lane = tid & 63, wave = tid >> 6;
    int wm = (wave & 1) * 64, wn = (wave >> 1) * 64;
    int quad = lane >> 4, l15 = lane & 15;
    f32x4 acc[4][4];
#pragma unroll
    for (int i = 0; i < 4; i++)
#pragma unroll
        for (int j = 0; j < 4; j++) acc[i][j] = 0.f;

    const unsigned short* ga0 = xb + (size_t)(m0 + (tid >> 2)) * K + (tid & 3) * 8;
    const unsigned short* ga1 = xb + (size_t)(m0 + 64 + (tid >> 2)) * K + (tid & 3) * 8;
    const unsigned short* gb0 = wb + (size_t)(n0 + (tid >> 2)) * K + (tid & 3) * 8;
    const unsigned short* gb1 = wb + (size_t)(n0 + 64 + (tid >> 2)) * K + (tid & 3) * 8;

    auto stage = [&](int bufi, int kk) {
        gload16(ga0 + kk, shmem + bufi * 4096 + wave * 512);
        gload16(ga1 + kk, shmem + bufi * 4096 + 2048 + wave * 512);
        gload16(gb0 + kk, shmem + 8192 + bufi * 4096 + wave * 512);
        gload16(gb1 + kk, shmem + 8192 + bufi * 4096 + 2048 + wave * 512);
    };
    auto compute = [&](int bufi) {
        short8 af[4], bfr[4];
#pragma unroll
        for (int i = 0; i < 4; i++)
            af[i] = *(short8*)&shmem[bufi * 4096 + (wm + i * 16 + l15) * 32 + quad * 8];
#pragma unroll
        for (int j = 0; j < 4; j++)
            bfr[j] = *(short8*)&shmem[8192 + bufi * 4096 + (wn + j * 16 + l15) * 32 + quad * 8];
#pragma unroll
        for (int i = 0; i < 4; i++)
#pragma unroll
            for (int j = 0; j < 4; j++)
                acc[i][j] = __builtin_amdgcn_mfma_f32_16x16x32_bf16(af[i], bfr[j], acc[i][j], 0, 0, 0);
    };

    stage(0, 0);
    int buf = 0;
    for (int t = 0; t < 23; t++) {
        stage(buf ^ 1, (t + 1) * 32);
        asm volatile("s_waitcnt vmcnt(4)" ::: "memory");
        __builtin_amdgcn_s_barrier();
        __builtin_amdgcn_sched_barrier(0);
        compute(buf);
        asm volatile("" ::: "memory");
        __builtin_amdgcn_s_barrier();
        buf ^= 1;
    }
    asm volatile("s_waitcnt vmcnt(0)" ::: "memory");
    __builtin_amdgcn_s_barrier();
    __builtin_amdgcn_sched_barrier(0);
    compute(buf);

    // ---- epilogue: LDS-transposed coalesced store ----
    __syncthreads();  // all waves done reading staging buffers
    {
        int colbase = n0 + wn;            // 64-aligned -> t3, h wave-uniform
        int t3 = colbase / 768;
        int r = colbase - t3 * 768;
        int h = r >> 6;
        int mstart = m0 + wm;
        int bb = mstart >> 11, sstart = mstart & 2047;
        unsigned short* ldsw = shmem + wave * 4608;  // [64 tok][72]
#pragma unroll
        for (int j = 0; j < 4; j++)
#pragma unroll
            for (int i = 0; i < 4; i++)
#pragma unroll
                for (int rr = 0; rr < 4; rr++) {
                    float val = acc[i][j][rr];
                    unsigned short o = (t3 == 2) ? f2bu(val) : f2bu(fmapf(val));
                    ldsw[(i * 16 + quad * 4 + rr) * 72 + j * 16 + l15] = o;
                }
        unsigned short* gb = (t3 == 0 ? qfb : (t3 == 1 ? kfb : vvb)) +
                             (((size_t)(bb * H_ + h) * S_) + sstart) * (size_t)HD;
        // 64 tokens x 128B contiguous; lane l -> tok c*8+(l>>3), chunk (l&7)*16B
#pragma unroll
        for (int c = 0; c < 8; c++) {
            int tok = c * 8 + (lane >> 3);
            uint4 vd = *(uint4*)&ldsw[tok * 72 + (lane & 7) * 8];
            *(uint4*)&gb[(size_t)tok * 64 + (lane & 7) * 8] = vd;
        }
    }
}

// ---------------------------------------------------------------------------
// Kernel 2a: partial kv states — pure streaming, bf16 inputs (exact
// bf16->fp32 converts; accumulation order unchanged). Grid = 48*16.
// ---------------------------------------------------------------------------
__global__ __launch_bounds__(256) void band_partial(const unsigned short* __restrict__ kfb,
                                                    const unsigned short* __restrict__ vvb,
                                                    float* __restrict__ pkv,
                                                    float* __restrict__ pks) {
    int bh = blockIdx.x >> 4, chunk = blockIdx.x & 15;
    int sbase = chunk * 128;
    const unsigned short* kfp = kfb + (size_t)bh * S_ * HD + (size_t)sbase * HD;
    const unsigned short* vp = vvb + (size_t)bh * S_ * HD + (size_t)sbase * HD;
    int tid = threadIdx.x;
    int d = tid & 63, eg = tid >> 6, e0 = eg * 16;
    float accg[16], accs[16];
#pragma unroll
    for (int i = 0; i < 16; i++) { accg[i] = 0.f; accs[i] = 0.f; }
    float ksg = 0.f, kss = 0.f;
#pragma unroll 4
    for (int s = 0; s < 128; s++) {
        float kd = bu2f(kfp[(size_t)s * HD + d]);
        bool str = ((sbase + s) % 3) == 0;
        ksg += kd;
        u16x8 va, vb2;
        va.u = *(const uint4*)&vp[(size_t)s * HD + e0];
        vb2.u = *(const uint4*)&vp[(size_t)s * HD + e0 + 8];
        float vf[16];
#pragma unroll
        for (int i = 0; i < 8; i++) vf[i] = bu2f(va.h[i]);
#pragma unroll
        for (int i = 0; i < 8; i++) vf[8 + i] = bu2f(vb2.h[i]);
#pragma unroll
        for (int i = 0; i < 16; i++) accg[i] += kd * vf[i];
        if (str) {
            kss += kd;
#pragma unroll
            for (int i = 0; i < 16; i++) accs[i] += kd * vf[i];
        }
    }
    float* pg = pkv + (size_t)blockIdx.x * 2 * 4096;
#pragma unroll
    for (int i = 0; i < 16; i++) pg[d * 64 + e0 + i] = accg[i];
#pragma unroll
    for (int i = 0; i < 16; i++) pg[4096 + d * 64 + e0 + i] = accs[i];
    if (eg == 0) {
        pks[blockIdx.x * 128 + d] = ksg;
        pks[blockIdx.x * 128 + 64 + d] = kss;
    }
}

// ---------------------------------------------------------------------------
// Kernel 2b: reduce partials + anchor outputs. Grid = 48 bh * 4 e-blocks.
// ---------------------------------------------------------------------------
__global__ __launch_bounds__(256) void band_reduce(const float* __restrict__ pkv,
                                                   const float* __restrict__ pks,
                                                   const float* __restrict__ aq,
                                                   unsigned short* __restrict__ kvsTb,
                                                   unsigned short* __restrict__ ksumsb,
                                                   unsigned short* __restrict__ aoutTb) {
    int bh = blockIdx.x >> 2, eb = blockIdx.x & 3, e0 = eb * 16;
    int h = bh % H_;
    __shared__ float kvgL[64][17];
    __shared__ float ksgL[64];
    __shared__ float anorm[12];
    int tid = threadIdx.x;
    for (int idx = tid; idx < 1024; idx += 256) {
        int d = idx >> 4, j = idx & 15;
        float sg = 0.f, ss = 0.f;
        const float* p = pkv + (size_t)(bh * 16) * 2 * 4096 + d * 64 + e0 + j;
#pragma unroll 4
        for (int c = 0; c < 16; c++) {
            sg += p[0];
            ss += p[4096];
            p += 2 * 4096;
        }
        kvgL[d][j] = sg;
        kvsTb[(size_t)bh * 4096 + (e0 + j) * 64 + d] = f2bu(ss);
    }
    if (tid < 64) {
        float sg = 0.f, ss = 0.f;
#pragma unroll 4
        for (int c = 0; c < 16; c++) {
            sg += pks[(bh * 16 + c) * 128 + tid];
            ss += pks[(bh * 16 + c) * 128 + 64 + tid];
        }
        ksgL[tid] = sg;
        if (eb == 0) ksumsb[bh * 64 + tid] = f2bu(ss);
    }
    __syncthreads();
    if (tid < 12) {
        float nrm = 0.f;
        for (int dd = 0; dd < 64; dd++)
            nrm += fmapf(aq[h * 768 + tid * 64 + dd]) * ksgL[dd];
        anorm[tid] = fmaxf(nrm, 1e-6f);
    }
    __syncthreads();
    if (tid < 192) {
        int a = tid >> 4, j = tid & 15;
        float acc = 0.f;
        for (int dd = 0; dd < 64; dd++)
            acc += fmapf(aq[h * 768 + a * 64 + dd]) * kvgL[dd][j];
        aoutTb[(size_t)bh * 768 + (e0 + j) * 12 + a] = f2bu(acc / anorm[a]);
    }
}

// ---------------------------------------------------------------------------
// Kernel 3: combine — register-direct MFMA fragments (unchanged from r9).
// ---------------------------------------------------------------------------
__global__ __launch_bounds__(256) void combine(const unsigned short* __restrict__ qfb,
                                               const unsigned short* __restrict__ kfb,
                                               const unsigned short* __restrict__ vvb,
                                               const unsigned short* __restrict__ aqfb_g,
                                               const unsigned short* __restrict__ kvsTb,
                                               const unsigned short* __restrict__ ksumsb,
                                               const unsigned short* __restrict__ aoutTb,
                                               const float* __restrict__ wlp,
                                               const float* __restrict__ wsp,
                                               const float* __restrict__ wgp,
                                               unsigned short* __restrict__ attnb) {
    __shared__ __attribute__((aligned(16))) unsigned short aqfb[16][72];   // anchors + ksum
    __shared__ __attribute__((aligned(16))) unsigned short vtbT[64][104];  // [e][band k], k<96
    __shared__ __attribute__((aligned(16))) unsigned short plb[64][104];   // masked P
    __shared__ __attribute__((aligned(16))) unsigned short qkgb[64][40];   // [token][anchor k]
    __shared__ float nrm[4][3][16];
    int bh = blockIdx.x >> 5, stile = blockIdx.x & 31;
    int b = bh / H_, h = bh % H_;
    int s0 = stile * 64;
    int tid = threadIdx.x, lane = tid & 63, wave = tid >> 6;
    int quad = lane >> 4, l15 = lane & 15;
    const unsigned short* qfp = qfb + (size_t)bh * S_ * HD;
    const unsigned short* kfp = kfb + (size_t)bh * S_ * HD;
    const unsigned short* vp = vvb + (size_t)bh * S_ * HD;
    float a0 = wlp[0], a1 = wsp[0], a2 = wgp[0];
    float mx = fmaxf(a0, fmaxf(a1, a2));
    float ew0 = __expf(a0 - mx), ew1 = __expf(a1 - mx), ew2 = __expf(a2 - mx);
    float inv = 1.f / (ew0 + ew1 + ew2);
    float wl = ew0 * inv, wsb = ew1 * inv, wg = ew2 * inv;
    // ---- stage: vtbT (bf16 copy transpose), aqfb, K-pads ----
    for (int i = tid; i < 96 * 64; i += 256) {
        int k = i >> 6, e = i & 63;
        int gs = s0 + k - 6;
        unsigned short v_ = (k < 75 && gs >= 0 && gs < S_) ? vp[(size_t)gs * HD + e]
                                                           : (unsigned short)0;
        vtbT[e][k] = v_;
    }
    if (tid < 192) {
        int a = tid >> 4, c = (tid & 15) * 4;
        *(ushort4*)&aqfb[a][c] = *(const ushort4*)&aqfb_g[h * 768 + a * 64 + c];
    }
    if (tid < 64) aqfb[12][tid] = ksumsb[bh * 64 + tid];
    if (tid < 192) aqfb[13 + (tid >> 6)][tid & 63] = 0;
    for (int i = tid; i < 1024; i += 256) {
        plb[i >> 4][80 + (i & 15)] = 0;   // K-pad cols 80..95
        qkgb[i >> 4][16 + (i & 15)] = 0;  // K-pad cols 16..31
    }
    __syncthreads();
    // ---- q A-fragments: per-thread rows, loaded once, reused everywhere ----
    u16x8 qa0, qa1;
    {
        const unsigned short* qr = qfp + (size_t)(s0 + wave * 16 + l15) * HD + quad * 8;
        qa0.u = *(const uint4*)qr;
        qa1.u = *(const uint4*)(qr + 32);
    }
    // ---- phase A: wave w computes P rows w*16..w*16+15 (wave-private) ----
#pragma unroll
    for (int tj = 0; tj < 5; tj++) {
        int row = tj * 16 + l15;
        int gs = s0 + row - 6;
        bool valid = (row < 75) && (gs >= 0) && (gs < S_);
        int gsc = gs < 0 ? 0 : (gs > S_ - 1 ? S_ - 1 : gs);
        const unsigned short* kr = kfp + (size_t)gsc * HD + quad * 8;
        u16x8 b0, b1, ones;
        ones.u = make_uint4(0x3F803F80u, 0x3F803F80u, 0x3F803F80u, 0x3F803F80u);
        b0.u = *(const uint4*)kr;
        b1.u = *(const uint4*)(kr + 32);
        if (!valid) { b0 = ones; b1 = ones; }
        f32x4 c = {0.f, 0.f, 0.f, 0.f};
        c = __builtin_amdgcn_mfma_f32_16x16x32_bf16(qa0.s, b0.s, c, 0, 0, 0);
        c = __builtin_amdgcn_mfma_f32_16x16x32_bf16(qa1.s, b1.s, c, 0, 0, 0);
        int col = tj * 16 + l15;
#pragma unroll
        for (int rr = 0; rr < 4; rr++) {
            int tok = wave * 16 + quad * 4 + rr;
            int which = col - tok;
            plb[tok][col] = (which >= 0 && which < 12) ? f2bu(c[rr]) : (unsigned short)0;
        }
    }
    {
        f32x4 c = {0.f, 0.f, 0.f, 0.f};
        short8 bfr0 = *(short8*)&aqfb[l15][quad * 8];
        short8 bfr1 = *(short8*)&aqfb[l15][32 + quad * 8];
        c = __builtin_amdgcn_mfma_f32_16x16x32_bf16(qa0.s, bfr0, c, 0, 0, 0);
        c = __builtin_amdgcn_mfma_f32_16x16x32_bf16(qa1.s, bfr1, c, 0, 0, 0);
#pragma unroll
        for (int rr = 0; rr < 4; rr++) qkgb[wave * 16 + quad * 4 + rr][l15] = f2bu(c[rr]);
    }
    // ---- per-wave norms -> reciprocal combine weights (lanes 0-15) ----
    if (lane < 16) {
        int t = wave * 16 + lane;
        float sl = 0.f;
#pragma unroll
        for (int j = 0; j < 12; j++) sl += bu2f(plb[t][t + j]);
        float sg = 0.f;
#pragma unroll
        for (int a = 0; a < 12; a++) sg += bu2f(qkgb[t][a]);
        nrm[wave][0][lane] = wl / fmaxf(sl, 1e-6f);
        nrm[wave][1][lane] = wg / fmaxf(sg, 1e-6f);
        nrm[wave][2][lane] = wsb / fmaxf(bu2f(qkgb[t][12]), 1e-6f);
    }
    // ---- phase B: fused MFMA; B-frags for stride/global bands direct ----
#pragma unroll
    for (int j2 = 0; j2 < 4; j2++) {
        int e = j2 * 16 + l15;
        f32x4 cL = {0.f, 0.f, 0.f, 0.f};
        f32x4 cG = {0.f, 0.f, 0.f, 0.f};
        f32x4 cS = {0.f, 0.f, 0.f, 0.f};
#pragma unroll
        for (int kk = 0; kk < 3; kk++) {
            short8 afr = *(short8*)&plb[wave * 16 + l15][kk * 32 + quad * 8];
            short8 bfr = *(short8*)&vtbT[e][kk * 32 + quad * 8];
            cL = __builtin_amdgcn_mfma_f32_16x16x32_bf16(afr, bfr, cL, 0, 0, 0);
        }
        {
            short8 afr = *(short8*)&qkgb[wave * 16 + l15][quad * 8];
            u16x8 bo;
            bo.u = make_uint4(0u, 0u, 0u, 0u);
            const unsigned* ap = (const unsigned*)(aoutTb + (size_t)bh * 768 + e * 12);
            if (quad == 0) {
                bo.u.x = ap[0]; bo.u.y = ap[1]; bo.u.z = ap[2]; bo.u.w = ap[3];
            } else if (quad == 1) {
                bo.u.x = ap[4]; bo.u.y = ap[5];
            }
            cG = __builtin_amdgcn_mfma_f32_16x16x32_bf16(afr, bo.s, cG, 0, 0, 0);
        }
        {
            const unsigned short* kvp = kvsTb + (size_t)bh * 4096 + e * 64 + quad * 8;
            u16x8 bk0, bk1;
            bk0.u = *(const uint4*)kvp;
            bk1.u = *(const uint4*)(kvp + 32);
            cS = __builtin_amdgcn_mfma_f32_16x16x32_bf16(qa0.s, bk0.s, cS, 0, 0, 0);
            cS = __builtin_amdgcn_mfma_f32_16x16x32_bf16(qa1.s, bk1.s, cS, 0, 0, 0);
        }
#pragma unroll
        for (int rr = 0; rr < 4; rr++) {
            int tq = quad * 4 + rr;
            int tok = wave * 16 + tq;
            float res = cL[rr] * nrm[wave][0][tq] + cS[rr] * nrm[wave][2][tq] +
                        cG[rr] * nrm[wave][1][tq];
            attnb[((size_t)(b * S_ + s0 + tok)) * 768 + h * 64 + e] = f2bu(res);
        }
    }
}

// ---------------------------------------------------------------------------
// Kernel 4: out = attn(bf16) @ out_w.T, counted-vmcnt dbuf + XCD swizzle.
// (fp32 stores are already full 64B lines — no epilogue change needed.)
// ---------------------------------------------------------------------------
__global__ __launch_bounds__(256) void out_gemm_mfma(const unsigned short* __restrict__ attnb,
                                                     const unsigned short* __restrict__ wb,
                                                     float* __restrict__ out) {
    __shared__ __attribute__((aligned(16))) unsigned short As[2][128 * 32];
    __shared__ __attribute__((aligned(16))) unsigned short Bs[2][128 * 32];
    const int K = 768;
    int orig = blockIdx.x;
    int swz = (orig & 7) * 48 + (orig >> 3);
    int mt = swz / 6, nt = swz - mt * 6;
    int n0 = nt * 128, m0 = mt * 128;
    int tid = threadIdx.x, lane = tid & 63, wave = tid >> 6;
    int wm = (wave & 1) * 64, wn = (wave >> 1) * 64;
    int quad = lane >> 4, l15 = lane & 15;
    f32x4 acc[4][4];
#pragma unroll
    for (int i = 0; i < 4; i++)
#pragma unroll
        for (int j = 0; j < 4; j++) acc[i][j] = 0.f;

    const unsigned short* ga0 = attnb + (size_t)(m0 + (tid >> 2)) * K + (tid & 3) * 8;
    const unsigned short* ga1 = attnb + (size_t)(m0 + 64 + (tid >> 2)) * K + (tid & 3) * 8;
    const unsigned short* gb0 = wb + (size_t)(n0 + (tid >> 2)) * K + (tid & 3) * 8;
    const unsigned short* gb1 = wb + (size_t)(n0 + 64 + (tid >> 2)) * K + (tid & 3) * 8;

    auto stage = [&](int bufi, int kk) {
        gload16(ga0 + kk, &As[bufi][wave * 512]);
        gload16(ga1 + kk, &As[bufi][2048 + wave * 512]);
        gload16(gb0 + kk, &Bs[bufi][wave * 512]);
        gload16(gb1 + kk, &Bs[bufi][2048 + wave * 512]);
    };
    auto compute = [&](int bufi) {
        short8 af[4], bfr[4];
#pragma unroll
        for (int i = 0; i < 4; i++)
            af[i] = *(short8*)&As[bufi][(wm + i * 16 + l15) * 32 + quad * 8];
#pragma unroll
        for (int j = 0; j < 4; j++)
            bfr[j] = *(short8*)&Bs[bufi][(wn + j * 16 + l15) * 32 + quad * 8];
#pragma unroll
        for (int i = 0; i < 4; i++)
#pragma unroll
            for (int j = 0; j < 4; j++)
                acc[i][j] = __builtin_amdgcn_mfma_f32_16x16x32_bf16(af[i], bfr[j], acc[i][j], 0, 0, 0);
    };

    stage(0, 0);
    int buf = 0;
    for (int t = 0; t < 23; t++) {
        stage(buf ^ 1, (t + 1) * 32);
        asm volatile("s_waitcnt vmcnt(4)" ::: "memory");
        __builtin_amdgcn_s_barrier();
        __builtin_amdgcn_sched_barrier(0);
        compute(buf);
        asm volatile("" ::: "memory");
        __builtin_amdgcn_s_barrier();
        buf ^= 1;
    }
    asm volatile("s_waitcnt vmcnt(0)" ::: "memory");
    __builtin_amdgcn_s_barrier();
    __builtin_amdgcn_sched_barrier(0);
    compute(buf);

#pragma unroll
    for (int j = 0; j < 4; j++) {
        int col = n0 + wn + j * 16 + l15;
#pragma unroll
        for (int i = 0; i < 4; i++) {
#pragma unroll
            for (int rr = 0; rr < 4; rr++) {
                int m = m0 + wm + i * 16 + quad * 4 + rr;
                out[(size_t)m * 768 + col] = acc[i][j][rr];
            }
        }
    }
}

extern "C" void kernel_launch(void* const* d_in, const int* in_sizes, int n_in,
                              void* d_out, int out_size, void* d_ws, size_t ws_size,
                              hipStream_t stream) {
    const float* x = (const float*)d_in[0];
    const float* qkvw = (const float*)d_in[1];
    const float* outw = (const float*)d_in[2];
    const float* aq = (const float*)d_in[3];
    const float* wlp = (const float*)d_in[4];
    const float* wsp = (const float*)d_in[5];
    const float* wgp = (const float*)d_in[6];

    float* ws = (float*)d_ws;
    const size_t NBH = (size_t)B_ * H_ * S_ * HD;  // 6,291,456
    // [0, 1.5*NBH floats): bf16 qfb / kfb / vvb (NBH ushorts each)
    unsigned short* qfb = (unsigned short*)ws;
    unsigned short* kfb = (unsigned short*)(ws + NBH / 2);
    unsigned short* vvb = (unsigned short*)(ws + NBH);
    float* attn_region = ws + 2 * NBH;  // NBH floats; multi-use scratch
    unsigned short* xb = (unsigned short*)attn_region;
    unsigned short* wb = (unsigned short*)(attn_region + 3145728);
    float* pkv = attn_region;
    unsigned short* attnb = (unsigned short*)attn_region;
    unsigned short* kvsTb = (unsigned short*)(attn_region + NBH);   // 48*4096
    unsigned short* ksumsb = kvsTb + 48 * 4096;                     // 48*64
    unsigned short* aoutTb = ksumsb + 48 * 64;                      // 48*768
    unsigned short* aqfb_g = aoutTb + 48 * 768;                     // 9216
    float* pks = attn_region + NBH + 122880;                        // 768*128 floats
    unsigned short* outwb = (unsigned short*)(pks + 768 * 128);

    convert_all<<<8484, 256, 0, stream>>>(x, qkvw, outw, aq, xb, wb, outwb, aqfb_g);
    qkv_gemm_mfma<<<1152, 256, 0, stream>>>(xb, wb, qfb, kfb, vvb);
    band_partial<<<48 * 16, 256, 0, stream>>>(kfb, vvb, pkv, pks);
    band_reduce<<<48 * 4, 256, 0, stream>>>(pkv, pks, aq, kvsTb, ksumsb, aoutTb);
    combine<<<48 * 32, 256, 0, stream>>>(qfb, kfb, vvb, aqfb_g, kvsTb, ksumsb, aoutTb,
                                         wlp, wsp, wgp, attnb);
    out_gemm_mfma<<<384, 256, 0, stream>>>(attnb, outwb, (float*)d_out);
}